// Round 1
// baseline (2613.298 us; speedup 1.0000x reference)
//
#include <hip/hip_runtime.h>
#include <math.h>

#define BATCH   8
#define NTOK    10150
#define DIMC    768
#define INNERC  300
#define HEADS   6
#define DHEAD   50
#define NQ      100
#define NBH     48          // BATCH*HEADS
#define NSPLIT  16
#define CHUNK   640         // 16*640 = 10240 >= 10150; all splits non-empty
#define SCALE   0.14142135623730951f   // 50^-0.5
#define MTOT    (BATCH*NTOK)           // 81200

// ---------------------------------------------------------------------------
// Generic fp32 GEMM (NT): C[m][n] = sum_k A[m][k]*B[n][k] (+ bias[n])
// 64x64 tile, BK=16, 256 threads, 4x4 microtile.
// grid = (ceil(N/64), ceil(M/64))  -- N fastest so same-M blocks are adjacent
// ---------------------------------------------------------------------------
__global__ __launch_bounds__(256) void gemm_nt(
    const float* __restrict__ A, const float* __restrict__ Bm,
    float* __restrict__ Cm, const float* __restrict__ bias,
    int M, int Nn, int K) {
  __shared__ float As[16][68];
  __shared__ float Bs[16][68];
  const int t  = threadIdx.x;
  const int tx = t & 15, ty = t >> 4;
  const int n0 = blockIdx.x * 64;
  const int m0 = blockIdx.y * 64;
  const int lr = t >> 2;          // 0..63
  const int lk = (t & 3) * 4;     // 0,4,8,12

  float c[4][4];
#pragma unroll
  for (int i = 0; i < 4; ++i)
#pragma unroll
    for (int j = 0; j < 4; ++j) c[i][j] = 0.f;

  for (int k0 = 0; k0 < K; k0 += 16) {
    float4 av = make_float4(0.f, 0.f, 0.f, 0.f);
    if (m0 + lr < M && k0 + lk < K) {
      const float* p = &A[(size_t)(m0 + lr) * K];
      if (k0 + lk + 3 < K) av = *(const float4*)&p[k0 + lk];
      else {
        av.x = p[k0 + lk];
        if (k0 + lk + 1 < K) av.y = p[k0 + lk + 1];
        if (k0 + lk + 2 < K) av.z = p[k0 + lk + 2];
      }
    }
    As[lk + 0][lr] = av.x; As[lk + 1][lr] = av.y;
    As[lk + 2][lr] = av.z; As[lk + 3][lr] = av.w;

    float4 bv = make_float4(0.f, 0.f, 0.f, 0.f);
    if (n0 + lr < Nn && k0 + lk < K) {
      const float* p = &Bm[(size_t)(n0 + lr) * K];
      if (k0 + lk + 3 < K) bv = *(const float4*)&p[k0 + lk];
      else {
        bv.x = p[k0 + lk];
        if (k0 + lk + 1 < K) bv.y = p[k0 + lk + 1];
        if (k0 + lk + 2 < K) bv.z = p[k0 + lk + 2];
      }
    }
    Bs[lk + 0][lr] = bv.x; Bs[lk + 1][lr] = bv.y;
    Bs[lk + 2][lr] = bv.z; Bs[lk + 3][lr] = bv.w;

    __syncthreads();
#pragma unroll
    for (int kk = 0; kk < 16; ++kk) {
      float4 a4 = *(const float4*)&As[kk][ty * 4];
      float4 b4 = *(const float4*)&Bs[kk][tx * 4];
      float a[4] = {a4.x, a4.y, a4.z, a4.w};
      float b[4] = {b4.x, b4.y, b4.z, b4.w};
#pragma unroll
      for (int i = 0; i < 4; ++i)
#pragma unroll
        for (int j = 0; j < 4; ++j) c[i][j] += a[i] * b[j];
    }
    __syncthreads();
  }

#pragma unroll
  for (int i = 0; i < 4; ++i) {
    int m = m0 + ty * 4 + i;
    if (m >= M) continue;
#pragma unroll
    for (int j = 0; j < 4; ++j) {
      int n = n0 + tx * 4 + j;
      if (n < Nn) Cm[(size_t)m * Nn + n] = c[i][j] + (bias ? bias[n] : 0.f);
    }
  }
}

// ---------------------------------------------------------------------------
// Adaptive avg-pool of spatial tokens -> rep[b][h][q][d]   (q = pr*10+pc)
// grid (NQ, BATCH), block 320
// ---------------------------------------------------------------------------
__global__ void pool_kernel(const float* __restrict__ w, float* __restrict__ rep) {
  int q = blockIdx.x, b = blockIdx.y;
  int i = threadIdx.x;
  if (i >= INNERC) return;
  int pr = q / 10, pc = q % 10;
  float s = 0.f;
  for (int kr = 0; kr < 10; ++kr)
    for (int kc = 0; kc < 10; ++kc) {
      int tok = (pr * 10 + kr) * 100 + (pc * 10 + kc);
      s += w[((size_t)b * NTOK + tok) * INNERC + i];
    }
  s *= 0.01f;
  int h = i / DHEAD, d = i % DHEAD;
  rep[(((size_t)b * HEADS + h) * NQ + q) * DHEAD + d] = s;
}

// ---------------------------------------------------------------------------
// Stage-1 attention, split-flash partials.
// grid (NBH, NSPLIT), block 256.  thread t -> q = t>>1 (q<100), dt = t&1 (d half)
// ---------------------------------------------------------------------------
__global__ __launch_bounds__(256) void attn1_partial(
    const float* __restrict__ w, const float* __restrict__ rep,
    float* __restrict__ m_part, float* __restrict__ l_part,
    float* __restrict__ delta_part) {
  int bh = blockIdx.x, s = blockIdx.y;
  int b = bh / HEADS, h = bh % HEADS;
  int t = threadIdx.x;
  int q = t >> 1, dt = t & 1;
  bool active = (q < NQ);

  __shared__ float kv[16 * DHEAD];

  float Q[DHEAD];
  if (active) {
    const float* qp = &rep[((size_t)bh * NQ + q) * DHEAD];
#pragma unroll
    for (int k = 0; k < DHEAD; ++k) Q[k] = qp[k] * SCALE;
  }
  float mval = -INFINITY, lval = 0.f;
  float acc[25];
#pragma unroll
  for (int dd = 0; dd < 25; ++dd) acc[dd] = 0.f;

  int n0 = s * CHUNK;
  int n1 = min(NTOK, n0 + CHUNK);

  for (int nt = n0; nt < n1; nt += 16) {
    int jn = min(16, n1 - nt);
    __syncthreads();
    for (int idx = t; idx < 16 * DHEAD; idx += 256) {
      int j = idx / DHEAD, k = idx % DHEAD;
      kv[idx] = (nt + j < n1) ? w[((size_t)b * NTOK + nt + j) * INNERC + h * DHEAD + k] : 0.f;
    }
    __syncthreads();
    if (active) {
      float dots[16];
      float tmax = -INFINITY;
#pragma unroll
      for (int j = 0; j < 16; ++j) {
        float dsum = 0.f;
#pragma unroll
        for (int k = 0; k < DHEAD; ++k) dsum += Q[k] * kv[j * DHEAD + k];
        dots[j] = (j < jn) ? dsum : -INFINITY;
        tmax = fmaxf(tmax, dots[j]);
      }
      float m_new = fmaxf(mval, tmax);
      float sc = __expf(mval - m_new);
      lval *= sc;
#pragma unroll
      for (int dd = 0; dd < 25; ++dd) acc[dd] *= sc;
#pragma unroll
      for (int j = 0; j < 16; ++j) {
        float p = __expf(dots[j] - m_new);
        lval += p;
#pragma unroll
        for (int dd = 0; dd < 25; ++dd) acc[dd] += p * kv[j * DHEAD + dt * 25 + dd];
      }
      mval = m_new;
    }
  }

  if (active) {
    size_t base = ((size_t)bh * NSPLIT + s) * NQ + q;
    if (dt == 0) { m_part[base] = mval; l_part[base] = lval; }
#pragma unroll
    for (int dd = 0; dd < 25; ++dd)
      delta_part[base * DHEAD + dt * 25 + dd] = acc[dd];
  }
}

// ---------------------------------------------------------------------------
// Combine split partials -> reph2 (updated rep), final m,l per (bh,q)
// grid (NBH), block 256
// ---------------------------------------------------------------------------
__global__ __launch_bounds__(256) void attn1_combine(
    const float* __restrict__ rep, const float* __restrict__ m_part,
    const float* __restrict__ l_part, const float* __restrict__ delta_part,
    const float* __restrict__ step_rep,
    float* __restrict__ reph2, float* __restrict__ m_fin, float* __restrict__ l_fin) {
  int bh = blockIdx.x;
  int h = bh % HEADS;
  int t = threadIdx.x;
  __shared__ float Mf[NQ], Lf[NQ];
  if (t < NQ) {
    int q = t;
    float M = -INFINITY;
#pragma unroll
    for (int s2 = 0; s2 < NSPLIT; ++s2)
      M = fmaxf(M, m_part[((size_t)bh * NSPLIT + s2) * NQ + q]);
    float L = 0.f;
#pragma unroll
    for (int s2 = 0; s2 < NSPLIT; ++s2)
      L += l_part[((size_t)bh * NSPLIT + s2) * NQ + q] *
           __expf(m_part[((size_t)bh * NSPLIT + s2) * NQ + q] - M);
    Mf[q] = M; Lf[q] = L;
    m_fin[(size_t)bh * NQ + q] = M;
    l_fin[(size_t)bh * NQ + q] = L;
  }
  __syncthreads();
  float sr = step_rep[h];
  for (int idx = t; idx < NQ * DHEAD; idx += 256) {
    int q = idx / DHEAD, d = idx % DHEAD;
    float sum = 0.f;
#pragma unroll
    for (int s2 = 0; s2 < NSPLIT; ++s2) {
      size_t pb = ((size_t)bh * NSPLIT + s2) * NQ + q;
      sum += __expf(m_part[pb] - Mf[q]) * delta_part[pb * DHEAD + d];
    }
    float rd = sum / Lf[q];
    reph2[(size_t)bh * NQ * DHEAD + idx] =
        rep[(size_t)bh * NQ * DHEAD + idx] + sr * rd;
  }
}

// ---------------------------------------------------------------------------
// Stage-2 self attention on reph2 -> xq = step_x[h] * (softmax(r2 r2^T s) r2)
// grid (NBH), block 256
// ---------------------------------------------------------------------------
__global__ __launch_bounds__(256) void attn2_kernel(
    const float* __restrict__ reph2, const float* __restrict__ step_x,
    float* __restrict__ xq) {
  int bh = blockIdx.x;
  int h = bh % HEADS;
  int t = threadIdx.x;
  __shared__ float r2[NQ * DHEAD];
  __shared__ float att[NQ * NQ];

  for (int idx = t; idx < NQ * DHEAD; idx += 256)
    r2[idx] = reph2[(size_t)bh * NQ * DHEAD + idx];
  __syncthreads();

  for (int idx = t; idx < NQ * NQ; idx += 256) {
    int qq = idx / NQ, jj = idx % NQ;
    float s = 0.f;
#pragma unroll
    for (int k = 0; k < DHEAD; ++k) s += r2[qq * DHEAD + k] * r2[jj * DHEAD + k];
    att[idx] = s * SCALE;
  }
  __syncthreads();
  if (t < NQ) {
    float M = -INFINITY;
    for (int j = 0; j < NQ; ++j) M = fmaxf(M, att[t * NQ + j]);
    float L = 0.f;
    for (int j = 0; j < NQ; ++j) { float e = __expf(att[t * NQ + j] - M); att[t * NQ + j] = e; L += e; }
    float inv = 1.f / L;
    for (int j = 0; j < NQ; ++j) att[t * NQ + j] *= inv;
  }
  __syncthreads();
  float sx = step_x[h];
  for (int idx = t; idx < NQ * DHEAD; idx += 256) {
    int qd_q = idx / DHEAD, d = idx % DHEAD;
    float v = 0.f;
#pragma unroll
    for (int j = 0; j < NQ; ++j) v += att[qd_q * NQ + j] * r2[j * DHEAD + d];
    xq[(size_t)bh * NQ * DHEAD + idx] = sx * v;
  }
}

// ---------------------------------------------------------------------------
// Pass 2: recompute attn from (m,l), xd[b][n][h*50+d] = sum_q attn[q,n]*xq[q,d]
// grid (ceil(NTOK/32), BATCH), block 256
// ---------------------------------------------------------------------------
#define TTOK 32
__global__ __launch_bounds__(256) void bcast_kernel(
    const float* __restrict__ w, const float* __restrict__ rep,
    const float* __restrict__ xq, const float* __restrict__ m_fin,
    const float* __restrict__ l_fin, float* __restrict__ xd) {
  int tile = blockIdx.x, b = blockIdx.y;
  int tok0 = tile * TTOK;
  int t = threadIdx.x;
  __shared__ float wT[INNERC * 33];      // wT[c*33 + tok], +1 pad kills conflicts
  __shared__ float p[NQ * TTOK];

  for (int idx = t; idx < TTOK * INNERC; idx += 256) {
    int tok = idx / INNERC, c = idx % INNERC;
    float v = (tok0 + tok < NTOK) ? w[((size_t)b * NTOK + tok0 + tok) * INNERC + c] : 0.f;
    wT[c * 33 + tok] = v;
  }
  __syncthreads();

  for (int h = 0; h < HEADS; ++h) {
    int bh = b * HEADS + h;
    for (int idx = t; idx < NQ * TTOK; idx += 256) {
      int q = idx >> 5, tok = idx & 31;
      const float* qp = &rep[((size_t)bh * NQ + q) * DHEAD];
      float dsum = 0.f;
#pragma unroll
      for (int k = 0; k < DHEAD; ++k) dsum += qp[k] * wT[(h * DHEAD + k) * 33 + tok];
      p[idx] = __expf(dsum * SCALE - m_fin[(size_t)bh * NQ + q]) / l_fin[(size_t)bh * NQ + q];
    }
    __syncthreads();
    for (int idx = t; idx < TTOK * DHEAD; idx += 256) {
      int tok = idx / DHEAD, d = idx % DHEAD;
      float v = 0.f;
#pragma unroll
      for (int q = 0; q < NQ; ++q)
        v += p[q * TTOK + tok] * xq[((size_t)bh * NQ + q) * DHEAD + d];
      if (tok0 + tok < NTOK)
        xd[((size_t)b * NTOK + tok0 + tok) * INNERC + h * DHEAD + d] = v;
    }
    __syncthreads();
  }
}

// ---------------------------------------------------------------------------
extern "C" void kernel_launch(void* const* d_in, const int* in_sizes, int n_in,
                              void* d_out, int out_size, void* d_ws, size_t ws_size,
                              hipStream_t stream) {
  const float* x        = (const float*)d_in[0];
  const float* proj_w   = (const float*)d_in[1];
  const float* step_x   = (const float*)d_in[2];
  const float* step_rep = (const float*)d_in[3];
  const float* out_w    = (const float*)d_in[4];
  const float* out_b    = (const float*)d_in[5];
  float* out = (float*)d_out;

  float* ws = (float*)d_ws;
  float* w      = ws;                       // 24,360,000
  float* rep    = w      + 24360000;        //    240,000
  float* reph2  = rep    + 240000;          //    240,000
  float* xq     = reph2  + 240000;          //    240,000
  float* m_part = xq     + 240000;          //     76,800
  float* l_part = m_part + 76800;           //     76,800
  float* m_fin  = l_part + 76800;           //      4,800
  float* l_fin  = m_fin  + 4800;            //      4,800
  float* delta  = l_fin  + 4800;            //  3,840,000
  float* xd     = delta  + 3840000;         // 24,360,000
  // total 53,443,200 floats = 213.8 MB

  // 1. w = x @ proj_w^T   [81200 x 300], K=768
  gemm_nt<<<dim3(5, 1269), 256, 0, stream>>>(x, proj_w, w, nullptr, MTOT, INNERC, DIMC);
  // 2. pooling -> rep[b][h][q][d]
  pool_kernel<<<dim3(NQ, BATCH), 320, 0, stream>>>(w, rep);
  // 3. stage-1 attention (split flash) + combine
  attn1_partial<<<dim3(NBH, NSPLIT), 256, 0, stream>>>(w, rep, m_part, l_part, delta);
  attn1_combine<<<NBH, 256, 0, stream>>>(rep, m_part, l_part, delta, step_rep,
                                         reph2, m_fin, l_fin);
  // 4. stage-2 self-attention -> xq (pre-scaled by step_x)
  attn2_kernel<<<NBH, 256, 0, stream>>>(reph2, step_x, xq);
  // 5. broadcast back through attn^T -> xd[b][n][300]
  bcast_kernel<<<dim3((NTOK + TTOK - 1) / TTOK, BATCH), 256, 0, stream>>>(
      w, rep, xq, m_fin, l_fin, xd);
  // 6. out = xd @ out_w^T + out_b   [81200 x 768], K=300
  gemm_nt<<<dim3(12, 1269), 256, 0, stream>>>(xd, out_w, out, out_b, MTOT, DIMC, INNERC);
}

// Round 2
// 2261.870 us; speedup vs baseline: 1.1554x; 1.1554x over previous
//
#include <hip/hip_runtime.h>
#include <math.h>

#define BATCH   8
#define NTOK    10150
#define DIMC    768
#define INNERC  300
#define HEADS   6
#define DHEAD   50
#define NQ      100
#define NBH     48          // BATCH*HEADS
#define NSPLIT  16
#define CHUNK   640         // 16*640 = 10240 >= 10150; all splits non-empty
#define SCALE   0.14142135623730951f   // 50^-0.5
#define MTOT    (BATCH*NTOK)           // 81200

// ---------------------------------------------------------------------------
// Generic fp32 GEMM (NT): C[m][n] = sum_k A[m][k]*B[n][k] (+ bias[n])
// 64x64 tile, BK=16, 256 threads, 4x4 microtile.
// ---------------------------------------------------------------------------
__global__ __launch_bounds__(256) void gemm_nt(
    const float* __restrict__ A, const float* __restrict__ Bm,
    float* __restrict__ Cm, const float* __restrict__ bias,
    int M, int Nn, int K) {
  __shared__ float As[16][68];
  __shared__ float Bs[16][68];
  const int t  = threadIdx.x;
  const int tx = t & 15, ty = t >> 4;
  const int n0 = blockIdx.x * 64;
  const int m0 = blockIdx.y * 64;
  const int lr = t >> 2;          // 0..63
  const int lk = (t & 3) * 4;     // 0,4,8,12

  float c[4][4];
#pragma unroll
  for (int i = 0; i < 4; ++i)
#pragma unroll
    for (int j = 0; j < 4; ++j) c[i][j] = 0.f;

  for (int k0 = 0; k0 < K; k0 += 16) {
    float4 av = make_float4(0.f, 0.f, 0.f, 0.f);
    if (m0 + lr < M && k0 + lk < K) {
      const float* p = &A[(size_t)(m0 + lr) * K];
      if (k0 + lk + 3 < K) av = *(const float4*)&p[k0 + lk];
      else {
        av.x = p[k0 + lk];
        if (k0 + lk + 1 < K) av.y = p[k0 + lk + 1];
        if (k0 + lk + 2 < K) av.z = p[k0 + lk + 2];
      }
    }
    As[lk + 0][lr] = av.x; As[lk + 1][lr] = av.y;
    As[lk + 2][lr] = av.z; As[lk + 3][lr] = av.w;

    float4 bv = make_float4(0.f, 0.f, 0.f, 0.f);
    if (n0 + lr < Nn && k0 + lk < K) {
      const float* p = &Bm[(size_t)(n0 + lr) * K];
      if (k0 + lk + 3 < K) bv = *(const float4*)&p[k0 + lk];
      else {
        bv.x = p[k0 + lk];
        if (k0 + lk + 1 < K) bv.y = p[k0 + lk + 1];
        if (k0 + lk + 2 < K) bv.z = p[k0 + lk + 2];
      }
    }
    Bs[lk + 0][lr] = bv.x; Bs[lk + 1][lr] = bv.y;
    Bs[lk + 2][lr] = bv.z; Bs[lk + 3][lr] = bv.w;

    __syncthreads();
#pragma unroll
    for (int kk = 0; kk < 16; ++kk) {
      float4 a4 = *(const float4*)&As[kk][ty * 4];
      float4 b4 = *(const float4*)&Bs[kk][tx * 4];
      float a[4] = {a4.x, a4.y, a4.z, a4.w};
      float b[4] = {b4.x, b4.y, b4.z, b4.w};
#pragma unroll
      for (int i = 0; i < 4; ++i)
#pragma unroll
        for (int j = 0; j < 4; ++j) c[i][j] += a[i] * b[j];
    }
    __syncthreads();
  }

#pragma unroll
  for (int i = 0; i < 4; ++i) {
    int m = m0 + ty * 4 + i;
    if (m >= M) continue;
#pragma unroll
    for (int j = 0; j < 4; ++j) {
      int n = n0 + tx * 4 + j;
      if (n < Nn) Cm[(size_t)m * Nn + n] = c[i][j] + (bias ? bias[n] : 0.f);
    }
  }
}

// ---------------------------------------------------------------------------
// Adaptive avg-pool of spatial tokens -> rep[b][h][q][d]   (q = pr*10+pc)
// ---------------------------------------------------------------------------
__global__ void pool_kernel(const float* __restrict__ w, float* __restrict__ rep) {
  int q = blockIdx.x, b = blockIdx.y;
  int i = threadIdx.x;
  if (i >= INNERC) return;
  int pr = q / 10, pc = q % 10;
  float s = 0.f;
  for (int kr = 0; kr < 10; ++kr)
    for (int kc = 0; kc < 10; ++kc) {
      int tok = (pr * 10 + kr) * 100 + (pc * 10 + kc);
      s += w[((size_t)b * NTOK + tok) * INNERC + i];
    }
  s *= 0.01f;
  int h = i / DHEAD, d = i % DHEAD;
  rep[(((size_t)b * HEADS + h) * NQ + q) * DHEAD + d] = s;
}

// ---------------------------------------------------------------------------
// Stage-1 attention, split-flash partials.
// grid (NBH, NSPLIT), block 256.  thread t -> q = t>>1 (q<100), dt = t&1
// ---------------------------------------------------------------------------
__global__ __launch_bounds__(256) void attn1_partial(
    const float* __restrict__ w, const float* __restrict__ rep,
    float* __restrict__ m_part, float* __restrict__ l_part,
    float* __restrict__ delta_part) {
  int bh = blockIdx.x, s = blockIdx.y;
  int b = bh / HEADS, h = bh % HEADS;
  int t = threadIdx.x;
  int q = t >> 1, dt = t & 1;
  bool active = (q < NQ);

  __shared__ float kv[16 * DHEAD];

  float Q[DHEAD];
  if (active) {
    const float* qp = &rep[((size_t)bh * NQ + q) * DHEAD];
#pragma unroll
    for (int k = 0; k < DHEAD; ++k) Q[k] = qp[k] * SCALE;
  }
  float mval = -INFINITY, lval = 0.f;
  float acc[25];
#pragma unroll
  for (int dd = 0; dd < 25; ++dd) acc[dd] = 0.f;

  int n0 = s * CHUNK;
  int n1 = min(NTOK, n0 + CHUNK);

  for (int nt = n0; nt < n1; nt += 16) {
    int jn = min(16, n1 - nt);
    __syncthreads();
    for (int idx = t; idx < 16 * DHEAD; idx += 256) {
      int j = idx / DHEAD, k = idx % DHEAD;
      kv[idx] = (nt + j < n1) ? w[((size_t)b * NTOK + nt + j) * INNERC + h * DHEAD + k] : 0.f;
    }
    __syncthreads();
    if (active) {
      float dots[16];
      float tmax = -INFINITY;
#pragma unroll
      for (int j = 0; j < 16; ++j) {
        float dsum = 0.f;
#pragma unroll
        for (int k = 0; k < DHEAD; ++k) dsum += Q[k] * kv[j * DHEAD + k];
        dots[j] = (j < jn) ? dsum : -INFINITY;
        tmax = fmaxf(tmax, dots[j]);
      }
      float m_new = fmaxf(mval, tmax);
      float sc = __expf(mval - m_new);
      lval *= sc;
#pragma unroll
      for (int dd = 0; dd < 25; ++dd) acc[dd] *= sc;
#pragma unroll
      for (int j = 0; j < 16; ++j) {
        float p = __expf(dots[j] - m_new);
        lval += p;
#pragma unroll
        for (int dd = 0; dd < 25; ++dd) acc[dd] += p * kv[j * DHEAD + dt * 25 + dd];
      }
      mval = m_new;
    }
  }

  if (active) {
    size_t base = ((size_t)bh * NSPLIT + s) * NQ + q;
    if (dt == 0) { m_part[base] = mval; l_part[base] = lval; }
#pragma unroll
    for (int dd = 0; dd < 25; ++dd)
      delta_part[base * DHEAD + dt * 25 + dd] = acc[dd];
  }
}

// ---------------------------------------------------------------------------
// Combine split partials -> reph2 (updated rep), final m,l per (bh,q)
// ---------------------------------------------------------------------------
__global__ __launch_bounds__(256) void attn1_combine(
    const float* __restrict__ rep, const float* __restrict__ m_part,
    const float* __restrict__ l_part, const float* __restrict__ delta_part,
    const float* __restrict__ step_rep,
    float* __restrict__ reph2, float* __restrict__ m_fin, float* __restrict__ l_fin) {
  int bh = blockIdx.x;
  int h = bh % HEADS;
  int t = threadIdx.x;
  __shared__ float Mf[NQ], Lf[NQ];
  if (t < NQ) {
    int q = t;
    float M = -INFINITY;
#pragma unroll
    for (int s2 = 0; s2 < NSPLIT; ++s2)
      M = fmaxf(M, m_part[((size_t)bh * NSPLIT + s2) * NQ + q]);
    float L = 0.f;
#pragma unroll
    for (int s2 = 0; s2 < NSPLIT; ++s2)
      L += l_part[((size_t)bh * NSPLIT + s2) * NQ + q] *
           __expf(m_part[((size_t)bh * NSPLIT + s2) * NQ + q] - M);
    Mf[q] = M; Lf[q] = L;
    m_fin[(size_t)bh * NQ + q] = M;
    l_fin[(size_t)bh * NQ + q] = L;
  }
  __syncthreads();
  float sr = step_rep[h];
  for (int idx = t; idx < NQ * DHEAD; idx += 256) {
    int q = idx / DHEAD, d = idx % DHEAD;
    float sum = 0.f;
#pragma unroll
    for (int s2 = 0; s2 < NSPLIT; ++s2) {
      size_t pb = ((size_t)bh * NSPLIT + s2) * NQ + q;
      sum += __expf(m_part[pb] - Mf[q]) * delta_part[pb * DHEAD + d];
    }
    float rd = sum / Lf[q];
    reph2[(size_t)bh * NQ * DHEAD + idx] =
        rep[(size_t)bh * NQ * DHEAD + idx] + sr * rd;
  }
}

// ---------------------------------------------------------------------------
// Stage-2 self attention on reph2 -> xq = step_x[h] * (softmax(r2 r2^T s) r2)
// ---------------------------------------------------------------------------
__global__ __launch_bounds__(256) void attn2_kernel(
    const float* __restrict__ reph2, const float* __restrict__ step_x,
    float* __restrict__ xq) {
  int bh = blockIdx.x;
  int h = bh % HEADS;
  int t = threadIdx.x;
  __shared__ float r2[NQ * DHEAD];
  __shared__ float att[NQ * NQ];

  for (int idx = t; idx < NQ * DHEAD; idx += 256)
    r2[idx] = reph2[(size_t)bh * NQ * DHEAD + idx];
  __syncthreads();

  for (int idx = t; idx < NQ * NQ; idx += 256) {
    int qq = idx / NQ, jj = idx % NQ;
    float s = 0.f;
#pragma unroll
    for (int k = 0; k < DHEAD; ++k) s += r2[qq * DHEAD + k] * r2[jj * DHEAD + k];
    att[idx] = s * SCALE;
  }
  __syncthreads();
  if (t < NQ) {
    float M = -INFINITY;
    for (int j = 0; j < NQ; ++j) M = fmaxf(M, att[t * NQ + j]);
    float L = 0.f;
    for (int j = 0; j < NQ; ++j) { float e = __expf(att[t * NQ + j] - M); att[t * NQ + j] = e; L += e; }
    float inv = 1.f / L;
    for (int j = 0; j < NQ; ++j) att[t * NQ + j] *= inv;
  }
  __syncthreads();
  float sx = step_x[h];
  for (int idx = t; idx < NQ * DHEAD; idx += 256) {
    int qd_q = idx / DHEAD, d = idx % DHEAD;
    float v = 0.f;
#pragma unroll
    for (int j = 0; j < NQ; ++j) v += att[qd_q * NQ + j] * r2[j * DHEAD + d];
    xq[(size_t)bh * NQ * DHEAD + idx] = sx * v;
  }
}

// ---------------------------------------------------------------------------
// Pass 2 rewrite: per (128-token tile, b, h): recompute attn columns from
// (m,l) and apply attn^T @ xq, fully LDS/register resident.
// grid (80, NBH), block 256. thread: tok = t&127, dhalf = t>>7 (25 d each).
// LDS: wT 26KB + pch 10.4KB + rq/xqs 8.3KB ~= 44.9KB -> 3 blocks/CU.
// ---------------------------------------------------------------------------
#define TTOK2 128
#define QCH   20
__global__ __launch_bounds__(256) void bcast2_kernel(
    const float* __restrict__ w, const float* __restrict__ rep,
    const float* __restrict__ xq, const float* __restrict__ m_fin,
    const float* __restrict__ l_fin, float* __restrict__ xd) {
  const int tile = blockIdx.x, bh = blockIdx.y;
  const int b = bh / HEADS, h = bh % HEADS;
  const int tok0 = tile * TTOK2;
  const int t = threadIdx.x;

  __shared__ float wT[DHEAD][TTOK2 + 2];   // [k][tok]
  __shared__ float pch[QCH][TTOK2 + 2];    // [q][tok]
  __shared__ float rq[QCH][DHEAD + 2];     // rep rows * SCALE
  __shared__ float xqs[QCH][DHEAD + 2];
  __shared__ float mi[QCH], linv[QCH];

  // stage w tile transposed: wT[k][tok]
  for (int idx = t; idx < TTOK2 * DHEAD; idx += 256) {
    int tok = idx / DHEAD, k = idx % DHEAD;
    float v = (tok0 + tok < NTOK)
                  ? w[((size_t)b * NTOK + tok0 + tok) * INNERC + h * DHEAD + k]
                  : 0.f;
    wT[k][tok] = v;
  }

  const int mytok = t & (TTOK2 - 1);
  const int dh = t >> 7;                   // 0 or 1 -> d = dh*25 + dd
  float acc[25];
#pragma unroll
  for (int dd = 0; dd < 25; ++dd) acc[dd] = 0.f;

  for (int q0 = 0; q0 < NQ; q0 += QCH) {
    // stage rep chunk (pre-scaled), xq chunk, m and 1/l
    for (int idx = t; idx < QCH * DHEAD; idx += 256) {
      int qq = idx / DHEAD, k = idx % DHEAD;
      rq[qq][k] = rep[((size_t)bh * NQ + q0 + qq) * DHEAD + k] * SCALE;
      xqs[qq][k] = xq[((size_t)bh * NQ + q0 + qq) * DHEAD + k];
    }
    if (t < QCH) {
      mi[t] = m_fin[(size_t)bh * NQ + q0 + t];
      linv[t] = 1.f / l_fin[(size_t)bh * NQ + q0 + t];
    }
    __syncthreads();

    // phase 1: p[q][tok] = exp(rq.wT - m)/l   (QCH*128 elems, 10 per thread)
    for (int idx = t; idx < QCH * TTOK2; idx += 256) {
      int tok = idx & (TTOK2 - 1), qq = idx >> 7;
      float dsum = 0.f;
#pragma unroll
      for (int k = 0; k < DHEAD; ++k) dsum += rq[qq][k] * wT[k][tok];
      pch[qq][tok] = __expf(dsum - mi[qq]) * linv[qq];
    }
    __syncthreads();

    // phase 2: acc[dd] += p[q][mytok] * xq[q][dh*25+dd]
#pragma unroll
    for (int qq = 0; qq < QCH; ++qq) {
      float pv = pch[qq][mytok];
#pragma unroll
      for (int dd = 0; dd < 25; ++dd) acc[dd] += pv * xqs[qq][dh * 25 + dd];
    }
    __syncthreads();
  }

  if (tok0 + mytok < NTOK) {
    float* op = &xd[((size_t)b * NTOK + tok0 + mytok) * INNERC + h * DHEAD + dh * 25];
#pragma unroll
    for (int dd = 0; dd < 25; ++dd) op[dd] = acc[dd];
  }
}

// ---------------------------------------------------------------------------
extern "C" void kernel_launch(void* const* d_in, const int* in_sizes, int n_in,
                              void* d_out, int out_size, void* d_ws, size_t ws_size,
                              hipStream_t stream) {
  const float* x        = (const float*)d_in[0];
  const float* proj_w   = (const float*)d_in[1];
  const float* step_x   = (const float*)d_in[2];
  const float* step_rep = (const float*)d_in[3];
  const float* out_w    = (const float*)d_in[4];
  const float* out_b    = (const float*)d_in[5];
  float* out = (float*)d_out;

  float* ws = (float*)d_ws;
  float* w      = ws;                       // 24,360,000
  float* rep    = w      + 24360000;        //    240,000
  float* reph2  = rep    + 240000;          //    240,000
  float* xq     = reph2  + 240000;          //    240,000
  float* m_part = xq     + 240000;          //     76,800
  float* l_part = m_part + 76800;           //     76,800
  float* m_fin  = l_part + 76800;           //      4,800
  float* l_fin  = m_fin  + 4800;            //      4,800
  float* delta  = l_fin  + 4800;            //  3,840,000
  float* xd     = delta  + 3840000;         // 24,360,000

  // 1. w = x @ proj_w^T   [81200 x 300], K=768
  gemm_nt<<<dim3(5, 1269), 256, 0, stream>>>(x, proj_w, w, nullptr, MTOT, INNERC, DIMC);
  // 2. pooling -> rep[b][h][q][d]
  pool_kernel<<<dim3(NQ, BATCH), 320, 0, stream>>>(w, rep);
  // 3. stage-1 attention (split flash) + combine
  attn1_partial<<<dim3(NBH, NSPLIT), 256, 0, stream>>>(w, rep, m_part, l_part, delta);
  attn1_combine<<<NBH, 256, 0, stream>>>(rep, m_part, l_part, delta, step_rep,
                                         reph2, m_fin, l_fin);
  // 4. stage-2 self-attention -> xq (pre-scaled by step_x)
  attn2_kernel<<<NBH, 256, 0, stream>>>(reph2, step_x, xq);
  // 5. broadcast back through attn^T -> xd[b][n][300]
  bcast2_kernel<<<dim3(80, NBH), 256, 0, stream>>>(w, rep, xq, m_fin, l_fin, xd);
  // 6. out = xd @ out_w^T + out_b   [81200 x 768], K=300
  gemm_nt<<<dim3(12, 1269), 256, 0, stream>>>(xd, out_w, out, out_b, MTOT, DIMC, INNERC);
}

// Round 3
// 2090.360 us; speedup vs baseline: 1.2502x; 1.0820x over previous
//
#include <hip/hip_runtime.h>
#include <math.h>

#define BATCH   8
#define NTOK    10150
#define DIMC    768
#define INNERC  300
#define HEADS   6
#define DHEAD   50
#define NQ      100
#define NBH     48          // BATCH*HEADS
#define NSPLIT  32
#define CHUNK   320         // 32*320 = 10240 >= 10150; all splits non-empty
#define SCALE   0.14142135623730951f   // 50^-0.5
#define MTOT    (BATCH*NTOK)           // 81200

// ---------------------------------------------------------------------------
// Generic fp32 GEMM (NT): C[m][n] = sum_k A[m][k]*B[n][k] (+ bias[n])
// 64x64 tile, BK=16, 256 threads, 4x4 microtile.
// ---------------------------------------------------------------------------
__global__ __launch_bounds__(256) void gemm_nt(
    const float* __restrict__ A, const float* __restrict__ Bm,
    float* __restrict__ Cm, const float* __restrict__ bias,
    int M, int Nn, int K) {
  __shared__ float As[16][68];
  __shared__ float Bs[16][68];
  const int t  = threadIdx.x;
  const int tx = t & 15, ty = t >> 4;
  const int n0 = blockIdx.x * 64;
  const int m0 = blockIdx.y * 64;
  const int lr = t >> 2;          // 0..63
  const int lk = (t & 3) * 4;     // 0,4,8,12

  float c[4][4];
#pragma unroll
  for (int i = 0; i < 4; ++i)
#pragma unroll
    for (int j = 0; j < 4; ++j) c[i][j] = 0.f;

  for (int k0 = 0; k0 < K; k0 += 16) {
    float4 av = make_float4(0.f, 0.f, 0.f, 0.f);
    if (m0 + lr < M && k0 + lk < K) {
      const float* p = &A[(size_t)(m0 + lr) * K];
      if (k0 + lk + 3 < K) av = *(const float4*)&p[k0 + lk];
      else {
        av.x = p[k0 + lk];
        if (k0 + lk + 1 < K) av.y = p[k0 + lk + 1];
        if (k0 + lk + 2 < K) av.z = p[k0 + lk + 2];
      }
    }
    As[lk + 0][lr] = av.x; As[lk + 1][lr] = av.y;
    As[lk + 2][lr] = av.z; As[lk + 3][lr] = av.w;

    float4 bv = make_float4(0.f, 0.f, 0.f, 0.f);
    if (n0 + lr < Nn && k0 + lk < K) {
      const float* p = &Bm[(size_t)(n0 + lr) * K];
      if (k0 + lk + 3 < K) bv = *(const float4*)&p[k0 + lk];
      else {
        bv.x = p[k0 + lk];
        if (k0 + lk + 1 < K) bv.y = p[k0 + lk + 1];
        if (k0 + lk + 2 < K) bv.z = p[k0 + lk + 2];
      }
    }
    Bs[lk + 0][lr] = bv.x; Bs[lk + 1][lr] = bv.y;
    Bs[lk + 2][lr] = bv.z; Bs[lk + 3][lr] = bv.w;

    __syncthreads();
#pragma unroll
    for (int kk = 0; kk < 16; ++kk) {
      float4 a4 = *(const float4*)&As[kk][ty * 4];
      float4 b4 = *(const float4*)&Bs[kk][tx * 4];
      float a[4] = {a4.x, a4.y, a4.z, a4.w};
      float b[4] = {b4.x, b4.y, b4.z, b4.w};
#pragma unroll
      for (int i = 0; i < 4; ++i)
#pragma unroll
        for (int j = 0; j < 4; ++j) c[i][j] += a[i] * b[j];
    }
    __syncthreads();
  }

#pragma unroll
  for (int i = 0; i < 4; ++i) {
    int m = m0 + ty * 4 + i;
    if (m >= M) continue;
#pragma unroll
    for (int j = 0; j < 4; ++j) {
      int n = n0 + tx * 4 + j;
      if (n < Nn) Cm[(size_t)m * Nn + n] = c[i][j] + (bias ? bias[n] : 0.f);
    }
  }
}

// ---------------------------------------------------------------------------
// Adaptive avg-pool of spatial tokens -> rep[b][h][q][d]   (q = pr*10+pc)
// ---------------------------------------------------------------------------
__global__ void pool_kernel(const float* __restrict__ w, float* __restrict__ rep) {
  int q = blockIdx.x, b = blockIdx.y;
  int i = threadIdx.x;
  if (i >= INNERC) return;
  int pr = q / 10, pc = q % 10;
  float s = 0.f;
  for (int kr = 0; kr < 10; ++kr)
    for (int kc = 0; kc < 10; ++kc) {
      int tok = (pr * 10 + kr) * 100 + (pc * 10 + kc);
      s += w[((size_t)b * NTOK + tok) * INNERC + i];
    }
  s *= 0.01f;
  int h = i / DHEAD, d = i % DHEAD;
  rep[(((size_t)b * HEADS + h) * NQ + q) * DHEAD + d] = s;
}

// ---------------------------------------------------------------------------
// Stage-1 attention, split-flash partials, v2.
// grid (NBH, NSPLIT), block 256.  Pair (2q,2q+1): dt = k-half.
// Dot split across the pair (25 FMA each) + one shfl_xor to combine.
// 32-token K-tiles staged in LDS; two 16-token register sub-chunks.
// ---------------------------------------------------------------------------
__global__ __launch_bounds__(256) void attn1_partial(
    const float* __restrict__ w, const float* __restrict__ rep,
    float* __restrict__ m_part, float* __restrict__ l_part,
    float* __restrict__ delta_part) {
  const int bh = blockIdx.x, s = blockIdx.y;
  const int b = bh / HEADS, h = bh % HEADS;
  const int t = threadIdx.x;
  const int q = t >> 1, dt = t & 1;
  const bool active = (q < NQ);

  __shared__ float kv[32][DHEAD];

  float Q[25];
  if (active) {
    const float* qp = &rep[((size_t)bh * NQ + q) * DHEAD + dt * 25];
#pragma unroll
    for (int k = 0; k < 25; ++k) Q[k] = qp[k] * SCALE;
  }
  float mval = -INFINITY, lval = 0.f;
  float acc[25];
#pragma unroll
  for (int dd = 0; dd < 25; ++dd) acc[dd] = 0.f;

  const int n0 = s * CHUNK;
  const int n1 = min(NTOK, n0 + CHUNK);

  for (int nt = n0; nt < n1; nt += 32) {
    const int jn = min(32, n1 - nt);
    __syncthreads();
    for (int idx = t; idx < 32 * DHEAD; idx += 256) {
      int j = idx / DHEAD, k = idx % DHEAD;
      kv[j][k] = (nt + j < n1) ? w[((size_t)b * NTOK + nt + j) * INNERC + h * DHEAD + k] : 0.f;
    }
    __syncthreads();
    if (active) {
#pragma unroll
      for (int sub = 0; sub < 2; ++sub) {
        float dots[16];
        float tmax = -INFINITY;
#pragma unroll
        for (int j = 0; j < 16; ++j) {
          const int jj = sub * 16 + j;
          float pd = 0.f;
#pragma unroll
          for (int kk = 0; kk < 25; ++kk) pd += Q[kk] * kv[jj][dt * 25 + kk];
          float full = pd + __shfl_xor(pd, 1);
          dots[j] = (jj < jn) ? full : -INFINITY;
          tmax = fmaxf(tmax, dots[j]);
        }
        float m_new = fmaxf(mval, tmax);
        float sc = __expf(mval - m_new);
        lval *= sc;
#pragma unroll
        for (int dd = 0; dd < 25; ++dd) acc[dd] *= sc;
#pragma unroll
        for (int j = 0; j < 16; ++j) {
          const int jj = sub * 16 + j;
          float p = __expf(dots[j] - m_new);
          lval += p;
#pragma unroll
          for (int dd = 0; dd < 25; ++dd) acc[dd] += p * kv[jj][dt * 25 + dd];
        }
        mval = m_new;
      }
    }
  }

  if (active) {
    size_t base = ((size_t)bh * NSPLIT + s) * NQ + q;
    if (dt == 0) { m_part[base] = mval; l_part[base] = lval; }
#pragma unroll
    for (int dd = 0; dd < 25; ++dd)
      delta_part[base * DHEAD + dt * 25 + dd] = acc[dd];
  }
}

// ---------------------------------------------------------------------------
// Combine split partials -> reph2 (updated rep), final m,l per (bh,q)
// ---------------------------------------------------------------------------
__global__ __launch_bounds__(256) void attn1_combine(
    const float* __restrict__ rep, const float* __restrict__ m_part,
    const float* __restrict__ l_part, const float* __restrict__ delta_part,
    const float* __restrict__ step_rep,
    float* __restrict__ reph2, float* __restrict__ m_fin, float* __restrict__ l_fin) {
  int bh = blockIdx.x;
  int h = bh % HEADS;
  int t = threadIdx.x;
  __shared__ float Mf[NQ], Lf[NQ];
  if (t < NQ) {
    int q = t;
    float M = -INFINITY;
#pragma unroll
    for (int s2 = 0; s2 < NSPLIT; ++s2)
      M = fmaxf(M, m_part[((size_t)bh * NSPLIT + s2) * NQ + q]);
    float L = 0.f;
#pragma unroll
    for (int s2 = 0; s2 < NSPLIT; ++s2)
      L += l_part[((size_t)bh * NSPLIT + s2) * NQ + q] *
           __expf(m_part[((size_t)bh * NSPLIT + s2) * NQ + q] - M);
    Mf[q] = M; Lf[q] = L;
    m_fin[(size_t)bh * NQ + q] = M;
    l_fin[(size_t)bh * NQ + q] = L;
  }
  __syncthreads();
  float sr = step_rep[h];
  for (int idx = t; idx < NQ * DHEAD; idx += 256) {
    int q = idx / DHEAD, d = idx % DHEAD;
    float sum = 0.f;
#pragma unroll
    for (int s2 = 0; s2 < NSPLIT; ++s2) {
      size_t pb = ((size_t)bh * NSPLIT + s2) * NQ + q;
      sum += __expf(m_part[pb] - Mf[q]) * delta_part[pb * DHEAD + d];
    }
    float rd = sum / Lf[q];
    reph2[(size_t)bh * NQ * DHEAD + idx] =
        rep[(size_t)bh * NQ * DHEAD + idx] + sr * rd;
  }
}

// ---------------------------------------------------------------------------
// Stage-2 self attention on reph2 -> xq = step_x[h] * (softmax(r2 r2^T s) r2)
// ---------------------------------------------------------------------------
__global__ __launch_bounds__(256) void attn2_kernel(
    const float* __restrict__ reph2, const float* __restrict__ step_x,
    float* __restrict__ xq) {
  int bh = blockIdx.x;
  int h = bh % HEADS;
  int t = threadIdx.x;
  __shared__ float r2[NQ * DHEAD];
  __shared__ float att[NQ * NQ];

  for (int idx = t; idx < NQ * DHEAD; idx += 256)
    r2[idx] = reph2[(size_t)bh * NQ * DHEAD + idx];
  __syncthreads();

  for (int idx = t; idx < NQ * NQ; idx += 256) {
    int qq = idx / NQ, jj = idx % NQ;
    float s = 0.f;
#pragma unroll
    for (int k = 0; k < DHEAD; ++k) s += r2[qq * DHEAD + k] * r2[jj * DHEAD + k];
    att[idx] = s * SCALE;
  }
  __syncthreads();
  if (t < NQ) {
    float M = -INFINITY;
    for (int j = 0; j < NQ; ++j) M = fmaxf(M, att[t * NQ + j]);
    float L = 0.f;
    for (int j = 0; j < NQ; ++j) { float e = __expf(att[t * NQ + j] - M); att[t * NQ + j] = e; L += e; }
    float inv = 1.f / L;
    for (int j = 0; j < NQ; ++j) att[t * NQ + j] *= inv;
  }
  __syncthreads();
  float sx = step_x[h];
  for (int idx = t; idx < NQ * DHEAD; idx += 256) {
    int qd_q = idx / DHEAD, d = idx % DHEAD;
    float v = 0.f;
#pragma unroll
    for (int j = 0; j < NQ; ++j) v += att[qd_q * NQ + j] * r2[j * DHEAD + d];
    xq[(size_t)bh * NQ * DHEAD + idx] = sx * v;
  }
}

// ---------------------------------------------------------------------------
// Pass 2: per (128-token tile, b, h): recompute attn columns from (m,l)
// and apply attn^T @ xq, fully LDS/register resident.
// ---------------------------------------------------------------------------
#define TTOK2 128
#define QCH   20
__global__ __launch_bounds__(256) void bcast2_kernel(
    const float* __restrict__ w, const float* __restrict__ rep,
    const float* __restrict__ xq, const float* __restrict__ m_fin,
    const float* __restrict__ l_fin, float* __restrict__ xd) {
  const int tile = blockIdx.x, bh = blockIdx.y;
  const int b = bh / HEADS, h = bh % HEADS;
  const int tok0 = tile * TTOK2;
  const int t = threadIdx.x;

  __shared__ float wT[DHEAD][TTOK2 + 2];   // [k][tok]
  __shared__ float pch[QCH][TTOK2 + 2];    // [q][tok]
  __shared__ float rq[QCH][DHEAD + 2];     // rep rows * SCALE
  __shared__ float xqs[QCH][DHEAD + 2];
  __shared__ float mi[QCH], linv[QCH];

  for (int idx = t; idx < TTOK2 * DHEAD; idx += 256) {
    int tok = idx / DHEAD, k = idx % DHEAD;
    float v = (tok0 + tok < NTOK)
                  ? w[((size_t)b * NTOK + tok0 + tok) * INNERC + h * DHEAD + k]
                  : 0.f;
    wT[k][tok] = v;
  }

  const int mytok = t & (TTOK2 - 1);
  const int dh = t >> 7;                   // 0 or 1 -> d = dh*25 + dd
  float acc[25];
#pragma unroll
  for (int dd = 0; dd < 25; ++dd) acc[dd] = 0.f;

  for (int q0 = 0; q0 < NQ; q0 += QCH) {
    for (int idx = t; idx < QCH * DHEAD; idx += 256) {
      int qq = idx / DHEAD, k = idx % DHEAD;
      rq[qq][k] = rep[((size_t)bh * NQ + q0 + qq) * DHEAD + k] * SCALE;
      xqs[qq][k] = xq[((size_t)bh * NQ + q0 + qq) * DHEAD + k];
    }
    if (t < QCH) {
      mi[t] = m_fin[(size_t)bh * NQ + q0 + t];
      linv[t] = 1.f / l_fin[(size_t)bh * NQ + q0 + t];
    }
    __syncthreads();

    for (int idx = t; idx < QCH * TTOK2; idx += 256) {
      int tok = idx & (TTOK2 - 1), qq = idx >> 7;
      float dsum = 0.f;
#pragma unroll
      for (int k = 0; k < DHEAD; ++k) dsum += rq[qq][k] * wT[k][tok];
      pch[qq][tok] = __expf(dsum - mi[qq]) * linv[qq];
    }
    __syncthreads();

#pragma unroll
    for (int qq = 0; qq < QCH; ++qq) {
      float pv = pch[qq][mytok];
#pragma unroll
      for (int dd = 0; dd < 25; ++dd) acc[dd] += pv * xqs[qq][dh * 25 + dd];
    }
    __syncthreads();
  }

  if (tok0 + mytok < NTOK) {
    float* op = &xd[((size_t)b * NTOK + tok0 + mytok) * INNERC + h * DHEAD + dh * 25];
#pragma unroll
    for (int dd = 0; dd < 25; ++dd) op[dd] = acc[dd];
  }
}

// ---------------------------------------------------------------------------
extern "C" void kernel_launch(void* const* d_in, const int* in_sizes, int n_in,
                              void* d_out, int out_size, void* d_ws, size_t ws_size,
                              hipStream_t stream) {
  const float* x        = (const float*)d_in[0];
  const float* proj_w   = (const float*)d_in[1];
  const float* step_x   = (const float*)d_in[2];
  const float* step_rep = (const float*)d_in[3];
  const float* out_w    = (const float*)d_in[4];
  const float* out_b    = (const float*)d_in[5];
  float* out = (float*)d_out;

  float* ws = (float*)d_ws;
  float* w      = ws;                       // 24,360,000
  float* rep    = w      + 24360000;        //    240,000
  float* reph2  = rep    + 240000;          //    240,000
  float* xq     = reph2  + 240000;          //    240,000
  float* m_part = xq     + 240000;          //    153,600  (48*32*100)
  float* l_part = m_part + 153600;          //    153,600
  float* m_fin  = l_part + 153600;          //      4,800
  float* l_fin  = m_fin  + 4800;            //      4,800
  float* xd     = l_fin  + 4800;            // 24,360,000
  // delta_part (48*32*100*50 = 7,680,000) aliases the xd buffer: combine
  // consumes it BEFORE bcast2 overwrites xd (stream-ordered).
  float* delta  = xd;
  // total ~199 MB < round-1's proven 214 MB

  // 1. w = x @ proj_w^T   [81200 x 300], K=768
  gemm_nt<<<dim3(5, 1269), 256, 0, stream>>>(x, proj_w, w, nullptr, MTOT, INNERC, DIMC);
  // 2. pooling -> rep[b][h][q][d]
  pool_kernel<<<dim3(NQ, BATCH), 320, 0, stream>>>(w, rep);
  // 3. stage-1 attention (split flash) + combine
  attn1_partial<<<dim3(NBH, NSPLIT), 256, 0, stream>>>(w, rep, m_part, l_part, delta);
  attn1_combine<<<NBH, 256, 0, stream>>>(rep, m_part, l_part, delta, step_rep,
                                         reph2, m_fin, l_fin);
  // 4. stage-2 self-attention -> xq (pre-scaled by step_x)
  attn2_kernel<<<NBH, 256, 0, stream>>>(reph2, step_x, xq);
  // 5. broadcast back through attn^T -> xd[b][n][300]
  bcast2_kernel<<<dim3(80, NBH), 256, 0, stream>>>(w, rep, xq, m_fin, l_fin, xd);
  // 6. out = xd @ out_w^T + out_b   [81200 x 768], K=300
  gemm_nt<<<dim3(12, 1269), 256, 0, stream>>>(xd, out_w, out, out_b, MTOT, DIMC, INNERC);
}

// Round 4
// 1649.939 us; speedup vs baseline: 1.5839x; 1.2669x over previous
//
#include <hip/hip_runtime.h>
#include <math.h>

#define BATCH   8
#define NTOK    10150
#define DIMC    768
#define INNERC  300
#define HEADS   6
#define DHEAD   50
#define NQ      100
#define NBH     48          // BATCH*HEADS
#define NSPLIT  32
#define CHUNK   320         // 32*320 = 10240 >= 10150; all splits non-empty
#define SCALE   0.14142135623730951f   // 50^-0.5
#define MTOT    (BATCH*NTOK)           // 81200

typedef __attribute__((ext_vector_type(8))) short short8;
typedef __attribute__((ext_vector_type(4))) float f32x4;

__device__ __forceinline__ ushort f2bf(float x) {
  uint u = __float_as_uint(x);
  uint r = (u + 0x7fffu + ((u >> 16) & 1u)) >> 16;
  return (ushort)r;
}
__device__ __forceinline__ float bf2f(ushort h) {
  return __uint_as_float(((uint)h) << 16);
}

// ---------------------------------------------------------------------------
// Split-bf16 MFMA GEMM (NT): C[m][n] = sum_k A[m][k]*B[n][k] (+ bias[n])
// A,B fp32 in global; converted to hi/lo bf16 during LDS staging.
// C = Ahi*Bhi + Alo*Bhi + Ahi*Blo  (lo*lo dropped, ~2^-16 relative)
// Tile 128x64, BK=32, 256 threads = 4 waves (2x2), 4x2 16x16 frags per wave.
// grid = (ceil(N/64), ceil(M/128)); K need not divide 32 (zero-padded).
// ---------------------------------------------------------------------------
#define BM 128
#define BN 64
#define BK 32
#define LDK 40   // padded bf16 stride: row stride 80B -> conflict-free-ish
__global__ __launch_bounds__(256) void gemm_nt_mfma(
    const float* __restrict__ A, const float* __restrict__ Bm,
    float* __restrict__ Cm, const float* __restrict__ bias,
    int M, int Nn, int K) {
  __shared__ ushort aHi[BM][LDK], aLo[BM][LDK];
  __shared__ ushort bHi[BN][LDK], bLo[BN][LDK];
  const int t = threadIdx.x;
  const int lane = t & 63;
  const int wid = t >> 6;
  const int wr = wid >> 1, wc = wid & 1;     // wave 2x2 -> 64x32 per wave
  const int n0 = blockIdx.x * BN;
  const int m0 = blockIdx.y * BM;
  const int lrow = t >> 3;                   // 0..31 (rows per staging pass)
  const int lkq = (t & 7) * 4;               // k-quad within BK

  f32x4 acc[4][2];
#pragma unroll
  for (int i = 0; i < 4; ++i)
#pragma unroll
    for (int j = 0; j < 2; ++j) acc[i][j] = (f32x4){0.f, 0.f, 0.f, 0.f};

  const int lr15 = lane & 15;
  const int lk8 = (lane >> 4) * 8;

  for (int k0 = 0; k0 < K; k0 += BK) {
    __syncthreads();
    // ---- stage A tile (128 x 32) as hi/lo bf16 ----
#pragma unroll
    for (int it = 0; it < 4; ++it) {
      const int row = it * 32 + lrow;
      const int m = m0 + row;
      float4 v = make_float4(0.f, 0.f, 0.f, 0.f);
      if (m < M && k0 + lkq < K)
        v = *(const float4*)&A[(size_t)m * K + k0 + lkq];
      ushort h0 = f2bf(v.x), h1 = f2bf(v.y), h2 = f2bf(v.z), h3 = f2bf(v.w);
      ushort l0 = f2bf(v.x - bf2f(h0)), l1 = f2bf(v.y - bf2f(h1));
      ushort l2 = f2bf(v.z - bf2f(h2)), l3 = f2bf(v.w - bf2f(h3));
      *(ushort4*)&aHi[row][lkq] = make_ushort4(h0, h1, h2, h3);
      *(ushort4*)&aLo[row][lkq] = make_ushort4(l0, l1, l2, l3);
    }
    // ---- stage B tile (64 x 32) ----
#pragma unroll
    for (int it = 0; it < 2; ++it) {
      const int row = it * 32 + lrow;
      const int n = n0 + row;
      float4 v = make_float4(0.f, 0.f, 0.f, 0.f);
      if (n < Nn && k0 + lkq < K)
        v = *(const float4*)&Bm[(size_t)n * K + k0 + lkq];
      ushort h0 = f2bf(v.x), h1 = f2bf(v.y), h2 = f2bf(v.z), h3 = f2bf(v.w);
      ushort l0 = f2bf(v.x - bf2f(h0)), l1 = f2bf(v.y - bf2f(h1));
      ushort l2 = f2bf(v.z - bf2f(h2)), l3 = f2bf(v.w - bf2f(h3));
      *(ushort4*)&bHi[row][lkq] = make_ushort4(h0, h1, h2, h3);
      *(ushort4*)&bLo[row][lkq] = make_ushort4(l0, l1, l2, l3);
    }
    __syncthreads();

    // ---- fragments + MFMA ----
    short8 ah[4], al[4], bh[2], bl[2];
#pragma unroll
    for (int i = 0; i < 4; ++i) {
      const int row = wr * 64 + i * 16 + lr15;
      ah[i] = *(const short8*)&aHi[row][lk8];
      al[i] = *(const short8*)&aLo[row][lk8];
    }
#pragma unroll
    for (int j = 0; j < 2; ++j) {
      const int row = wc * 32 + j * 16 + lr15;
      bh[j] = *(const short8*)&bHi[row][lk8];
      bl[j] = *(const short8*)&bLo[row][lk8];
    }
#pragma unroll
    for (int i = 0; i < 4; ++i)
#pragma unroll
      for (int j = 0; j < 2; ++j) {
        acc[i][j] = __builtin_amdgcn_mfma_f32_16x16x32_bf16(ah[i], bh[j], acc[i][j], 0, 0, 0);
        acc[i][j] = __builtin_amdgcn_mfma_f32_16x16x32_bf16(al[i], bh[j], acc[i][j], 0, 0, 0);
        acc[i][j] = __builtin_amdgcn_mfma_f32_16x16x32_bf16(ah[i], bl[j], acc[i][j], 0, 0, 0);
      }
  }

  // ---- epilogue: C/D layout col=lane&15, row=(lane>>4)*4+reg ----
#pragma unroll
  for (int j = 0; j < 2; ++j) {
    const int col = n0 + wc * 32 + j * 16 + lr15;
    if (col >= Nn) continue;
    const float bv = bias ? bias[col] : 0.f;
#pragma unroll
    for (int i = 0; i < 4; ++i) {
#pragma unroll
      for (int r = 0; r < 4; ++r) {
        const int m = m0 + wr * 64 + i * 16 + (lane >> 4) * 4 + r;
        if (m < M) Cm[(size_t)m * Nn + col] = acc[i][j][r] + bv;
      }
    }
  }
}

// ---------------------------------------------------------------------------
// Adaptive avg-pool of spatial tokens -> rep[b][h][q][d]   (q = pr*10+pc)
// ---------------------------------------------------------------------------
__global__ void pool_kernel(const float* __restrict__ w, float* __restrict__ rep) {
  int q = blockIdx.x, b = blockIdx.y;
  int i = threadIdx.x;
  if (i >= INNERC) return;
  int pr = q / 10, pc = q % 10;
  float s = 0.f;
  for (int kr = 0; kr < 10; ++kr)
    for (int kc = 0; kc < 10; ++kc) {
      int tok = (pr * 10 + kr) * 100 + (pc * 10 + kc);
      s += w[((size_t)b * NTOK + tok) * INNERC + i];
    }
  s *= 0.01f;
  int h = i / DHEAD, d = i % DHEAD;
  rep[(((size_t)b * HEADS + h) * NQ + q) * DHEAD + d] = s;
}

// ---------------------------------------------------------------------------
// Stage-1 attention, split-flash partials.
// grid (NBH, NSPLIT), block 256.  Pair (2q,2q+1): dt = k-half.
// ---------------------------------------------------------------------------
__global__ __launch_bounds__(256) void attn1_partial(
    const float* __restrict__ w, const float* __restrict__ rep,
    float* __restrict__ m_part, float* __restrict__ l_part,
    float* __restrict__ delta_part) {
  const int bh = blockIdx.x, s = blockIdx.y;
  const int b = bh / HEADS, h = bh % HEADS;
  const int t = threadIdx.x;
  const int q = t >> 1, dt = t & 1;
  const bool active = (q < NQ);

  __shared__ float kv[32][DHEAD];

  float Q[25];
  if (active) {
    const float* qp = &rep[((size_t)bh * NQ + q) * DHEAD + dt * 25];
#pragma unroll
    for (int k = 0; k < 25; ++k) Q[k] = qp[k] * SCALE;
  }
  float mval = -INFINITY, lval = 0.f;
  float acc[25];
#pragma unroll
  for (int dd = 0; dd < 25; ++dd) acc[dd] = 0.f;

  const int n0 = s * CHUNK;
  const int n1 = min(NTOK, n0 + CHUNK);

  for (int nt = n0; nt < n1; nt += 32) {
    const int jn = min(32, n1 - nt);
    __syncthreads();
    for (int idx = t; idx < 32 * DHEAD; idx += 256) {
      int j = idx / DHEAD, k = idx % DHEAD;
      kv[j][k] = (nt + j < n1) ? w[((size_t)b * NTOK + nt + j) * INNERC + h * DHEAD + k] : 0.f;
    }
    __syncthreads();
    if (active) {
#pragma unroll
      for (int sub = 0; sub < 2; ++sub) {
        float dots[16];
        float tmax = -INFINITY;
#pragma unroll
        for (int j = 0; j < 16; ++j) {
          const int jj = sub * 16 + j;
          float pd = 0.f;
#pragma unroll
          for (int kk = 0; kk < 25; ++kk) pd += Q[kk] * kv[jj][dt * 25 + kk];
          float full = pd + __shfl_xor(pd, 1);
          dots[j] = (jj < jn) ? full : -INFINITY;
          tmax = fmaxf(tmax, dots[j]);
        }
        float m_new = fmaxf(mval, tmax);
        float sc = __expf(mval - m_new);
        lval *= sc;
#pragma unroll
        for (int dd = 0; dd < 25; ++dd) acc[dd] *= sc;
#pragma unroll
        for (int j = 0; j < 16; ++j) {
          const int jj = sub * 16 + j;
          float p = __expf(dots[j] - m_new);
          lval += p;
#pragma unroll
          for (int dd = 0; dd < 25; ++dd) acc[dd] += p * kv[jj][dt * 25 + dd];
        }
        mval = m_new;
      }
    }
  }

  if (active) {
    size_t base = ((size_t)bh * NSPLIT + s) * NQ + q;
    if (dt == 0) { m_part[base] = mval; l_part[base] = lval; }
#pragma unroll
    for (int dd = 0; dd < 25; ++dd)
      delta_part[base * DHEAD + dt * 25 + dd] = acc[dd];
  }
}

// ---------------------------------------------------------------------------
// Combine split partials -> reph2 (updated rep), final m,l per (bh,q)
// ---------------------------------------------------------------------------
__global__ __launch_bounds__(256) void attn1_combine(
    const float* __restrict__ rep, const float* __restrict__ m_part,
    const float* __restrict__ l_part, const float* __restrict__ delta_part,
    const float* __restrict__ step_rep,
    float* __restrict__ reph2, float* __restrict__ m_fin, float* __restrict__ l_fin) {
  int bh = blockIdx.x;
  int h = bh % HEADS;
  int t = threadIdx.x;
  __shared__ float Mf[NQ], Lf[NQ];
  if (t < NQ) {
    int q = t;
    float M = -INFINITY;
#pragma unroll
    for (int s2 = 0; s2 < NSPLIT; ++s2)
      M = fmaxf(M, m_part[((size_t)bh * NSPLIT + s2) * NQ + q]);
    float L = 0.f;
#pragma unroll
    for (int s2 = 0; s2 < NSPLIT; ++s2)
      L += l_part[((size_t)bh * NSPLIT + s2) * NQ + q] *
           __expf(m_part[((size_t)bh * NSPLIT + s2) * NQ + q] - M);
    Mf[q] = M; Lf[q] = L;
    m_fin[(size_t)bh * NQ + q] = M;
    l_fin[(size_t)bh * NQ + q] = L;
  }
  __syncthreads();
  float sr = step_rep[h];
  for (int idx = t; idx < NQ * DHEAD; idx += 256) {
    int q = idx / DHEAD, d = idx % DHEAD;
    float sum = 0.f;
#pragma unroll
    for (int s2 = 0; s2 < NSPLIT; ++s2) {
      size_t pb = ((size_t)bh * NSPLIT + s2) * NQ + q;
      sum += __expf(m_part[pb] - Mf[q]) * delta_part[pb * DHEAD + d];
    }
    float rd = sum / Lf[q];
    reph2[(size_t)bh * NQ * DHEAD + idx] =
        rep[(size_t)bh * NQ * DHEAD + idx] + sr * rd;
  }
}

// ---------------------------------------------------------------------------
// Stage-2 self attention on reph2 -> xq = step_x[h] * (softmax(r2 r2^T s) r2)
// ---------------------------------------------------------------------------
__global__ __launch_bounds__(256) void attn2_kernel(
    const float* __restrict__ reph2, const float* __restrict__ step_x,
    float* __restrict__ xq) {
  int bh = blockIdx.x;
  int h = bh % HEADS;
  int t = threadIdx.x;
  __shared__ float r2[NQ * DHEAD];
  __shared__ float att[NQ * NQ];

  for (int idx = t; idx < NQ * DHEAD; idx += 256)
    r2[idx] = reph2[(size_t)bh * NQ * DHEAD + idx];
  __syncthreads();

  for (int idx = t; idx < NQ * NQ; idx += 256) {
    int qq = idx / NQ, jj = idx % NQ;
    float s = 0.f;
#pragma unroll
    for (int k = 0; k < DHEAD; ++k) s += r2[qq * DHEAD + k] * r2[jj * DHEAD + k];
    att[idx] = s * SCALE;
  }
  __syncthreads();
  if (t < NQ) {
    float M = -INFINITY;
    for (int j = 0; j < NQ; ++j) M = fmaxf(M, att[t * NQ + j]);
    float L = 0.f;
    for (int j = 0; j < NQ; ++j) { float e = __expf(att[t * NQ + j] - M); att[t * NQ + j] = e; L += e; }
    float inv = 1.f / L;
    for (int j = 0; j < NQ; ++j) att[t * NQ + j] *= inv;
  }
  __syncthreads();
  float sx = step_x[h];
  for (int idx = t; idx < NQ * DHEAD; idx += 256) {
    int qd_q = idx / DHEAD, d = idx % DHEAD;
    float v = 0.f;
#pragma unroll
    for (int j = 0; j < NQ; ++j) v += att[qd_q * NQ + j] * r2[j * DHEAD + d];
    xq[(size_t)bh * NQ * DHEAD + idx] = sx * v;
  }
}

// ---------------------------------------------------------------------------
// Pass 2: per (128-token tile, b, h): recompute attn columns from (m,l)
// and apply attn^T @ xq, fully LDS/register resident.
// ---------------------------------------------------------------------------
#define TTOK2 128
#define QCH   20
__global__ __launch_bounds__(256) void bcast2_kernel(
    const float* __restrict__ w, const float* __restrict__ rep,
    const float* __restrict__ xq, const float* __restrict__ m_fin,
    const float* __restrict__ l_fin, float* __restrict__ xd) {
  const int tile = blockIdx.x, bh = blockIdx.y;
  const int b = bh / HEADS, h = bh % HEADS;
  const int tok0 = tile * TTOK2;
  const int t = threadIdx.x;

  __shared__ float wT[DHEAD][TTOK2 + 2];   // [k][tok]
  __shared__ float pch[QCH][TTOK2 + 2];    // [q][tok]
  __shared__ float rq[QCH][DHEAD + 2];     // rep rows * SCALE
  __shared__ float xqs[QCH][DHEAD + 2];
  __shared__ float mi[QCH], linv[QCH];

  for (int idx = t; idx < TTOK2 * DHEAD; idx += 256) {
    int tok = idx / DHEAD, k = idx % DHEAD;
    float v = (tok0 + tok < NTOK)
                  ? w[((size_t)b * NTOK + tok0 + tok) * INNERC + h * DHEAD + k]
                  : 0.f;
    wT[k][tok] = v;
  }

  const int mytok = t & (TTOK2 - 1);
  const int dh = t >> 7;                   // 0 or 1 -> d = dh*25 + dd
  float acc[25];
#pragma unroll
  for (int dd = 0; dd < 25; ++dd) acc[dd] = 0.f;

  for (int q0 = 0; q0 < NQ; q0 += QCH) {
    for (int idx = t; idx < QCH * DHEAD; idx += 256) {
      int qq = idx / DHEAD, k = idx % DHEAD;
      rq[qq][k] = rep[((size_t)bh * NQ + q0 + qq) * DHEAD + k] * SCALE;
      xqs[qq][k] = xq[((size_t)bh * NQ + q0 + qq) * DHEAD + k];
    }
    if (t < QCH) {
      mi[t] = m_fin[(size_t)bh * NQ + q0 + t];
      linv[t] = 1.f / l_fin[(size_t)bh * NQ + q0 + t];
    }
    __syncthreads();

    for (int idx = t; idx < QCH * TTOK2; idx += 256) {
      int tok = idx & (TTOK2 - 1), qq = idx >> 7;
      float dsum = 0.f;
#pragma unroll
      for (int k = 0; k < DHEAD; ++k) dsum += rq[qq][k] * wT[k][tok];
      pch[qq][tok] = __expf(dsum - mi[qq]) * linv[qq];
    }
    __syncthreads();

#pragma unroll
    for (int qq = 0; qq < QCH; ++qq) {
      float pv = pch[qq][mytok];
#pragma unroll
      for (int dd = 0; dd < 25; ++dd) acc[dd] += pv * xqs[qq][dh * 25 + dd];
    }
    __syncthreads();
  }

  if (tok0 + mytok < NTOK) {
    float* op = &xd[((size_t)b * NTOK + tok0 + mytok) * INNERC + h * DHEAD + dh * 25];
#pragma unroll
    for (int dd = 0; dd < 25; ++dd) op[dd] = acc[dd];
  }
}

// ---------------------------------------------------------------------------
extern "C" void kernel_launch(void* const* d_in, const int* in_sizes, int n_in,
                              void* d_out, int out_size, void* d_ws, size_t ws_size,
                              hipStream_t stream) {
  const float* x        = (const float*)d_in[0];
  const float* proj_w   = (const float*)d_in[1];
  const float* step_x   = (const float*)d_in[2];
  const float* step_rep = (const float*)d_in[3];
  const float* out_w    = (const float*)d_in[4];
  const float* out_b    = (const float*)d_in[5];
  float* out = (float*)d_out;

  float* ws = (float*)d_ws;
  float* w      = ws;                       // 24,360,000
  float* rep    = w      + 24360000;        //    240,000
  float* reph2  = rep    + 240000;          //    240,000
  float* xq     = reph2  + 240000;          //    240,000
  float* m_part = xq     + 240000;          //    153,600  (48*32*100)
  float* l_part = m_part + 153600;          //    153,600
  float* m_fin  = l_part + 153600;          //      4,800
  float* l_fin  = m_fin  + 4800;            //      4,800
  float* xd     = l_fin  + 4800;            // 24,360,000
  // delta_part (48*32*100*50 = 7,680,000) aliases the xd buffer: combine
  // consumes it BEFORE bcast2 overwrites xd (stream-ordered).
  float* delta  = xd;

  // 1. w = x @ proj_w^T   [81200 x 300], K=768  (split-bf16 MFMA)
  gemm_nt_mfma<<<dim3(5, 635), 256, 0, stream>>>(x, proj_w, w, nullptr, MTOT, INNERC, DIMC);
  // 2. pooling -> rep[b][h][q][d]
  pool_kernel<<<dim3(NQ, BATCH), 320, 0, stream>>>(w, rep);
  // 3. stage-1 attention (split flash) + combine
  attn1_partial<<<dim3(NBH, NSPLIT), 256, 0, stream>>>(w, rep, m_part, l_part, delta);
  attn1_combine<<<NBH, 256, 0, stream>>>(rep, m_part, l_part, delta, step_rep,
                                         reph2, m_fin, l_fin);
  // 4. stage-2 self-attention -> xq (pre-scaled by step_x)
  attn2_kernel<<<NBH, 256, 0, stream>>>(reph2, step_x, xq);
  // 5. broadcast back through attn^T -> xd[b][n][300]
  bcast2_kernel<<<dim3(80, NBH), 256, 0, stream>>>(w, rep, xq, m_fin, l_fin, xd);
  // 6. out = xd @ out_w^T + out_b   [81200 x 768], K=300  (split-bf16 MFMA)
  gemm_nt_mfma<<<dim3(12, 635), 256, 0, stream>>>(xd, out_w, out, out_b, MTOT, DIMC, INNERC);
}

// Round 5
// 1414.118 us; speedup vs baseline: 1.8480x; 1.1668x over previous
//
#include <hip/hip_runtime.h>
#include <math.h>

#define BATCH   8
#define NTOK    10150
#define DIMC    768
#define INNERC  300
#define HEADS   6
#define DHEAD   50
#define NQ      100
#define NBH     48          // BATCH*HEADS
#define NSPLIT  16
#define CHUNK   640         // 16*640 = 10240 >= 10150; all splits non-empty
#define SCALE   0.14142135623730951f   // 50^-0.5
#define MTOT    (BATCH*NTOK)           // 81200
#define NEGBIG  -1.0e30f

typedef __attribute__((ext_vector_type(8))) short short8;
typedef __attribute__((ext_vector_type(4))) float f32x4;

__device__ __forceinline__ ushort f2bf(float x) {
  uint u = __float_as_uint(x);
  uint r = (u + 0x7fffu + ((u >> 16) & 1u)) >> 16;
  return (ushort)r;
}
__device__ __forceinline__ float bf2f(ushort h) {
  return __uint_as_float(((uint)h) << 16);
}

// ---------------------------------------------------------------------------
// Split-bf16 MFMA GEMM (NT): C[m][n] = sum_k A[m][k]*B[n][k] (+ bias[n])
// (unchanged from round 3 — verified)
// ---------------------------------------------------------------------------
#define BM 128
#define BN 64
#define BK 32
#define LDK 40
__global__ __launch_bounds__(256) void gemm_nt_mfma(
    const float* __restrict__ A, const float* __restrict__ Bm,
    float* __restrict__ Cm, const float* __restrict__ bias,
    int M, int Nn, int K) {
  __shared__ ushort aHi[BM][LDK], aLo[BM][LDK];
  __shared__ ushort bHi[BN][LDK], bLo[BN][LDK];
  const int t = threadIdx.x;
  const int lane = t & 63;
  const int wid = t >> 6;
  const int wr = wid >> 1, wc = wid & 1;
  const int n0 = blockIdx.x * BN;
  const int m0 = blockIdx.y * BM;
  const int lrow = t >> 3;
  const int lkq = (t & 7) * 4;

  f32x4 acc[4][2];
#pragma unroll
  for (int i = 0; i < 4; ++i)
#pragma unroll
    for (int j = 0; j < 2; ++j) acc[i][j] = (f32x4){0.f, 0.f, 0.f, 0.f};

  const int lr15 = lane & 15;
  const int lk8 = (lane >> 4) * 8;

  for (int k0 = 0; k0 < K; k0 += BK) {
    __syncthreads();
#pragma unroll
    for (int it = 0; it < 4; ++it) {
      const int row = it * 32 + lrow;
      const int m = m0 + row;
      float4 v = make_float4(0.f, 0.f, 0.f, 0.f);
      if (m < M && k0 + lkq < K)
        v = *(const float4*)&A[(size_t)m * K + k0 + lkq];
      ushort h0 = f2bf(v.x), h1 = f2bf(v.y), h2 = f2bf(v.z), h3 = f2bf(v.w);
      ushort l0 = f2bf(v.x - bf2f(h0)), l1 = f2bf(v.y - bf2f(h1));
      ushort l2 = f2bf(v.z - bf2f(h2)), l3 = f2bf(v.w - bf2f(h3));
      *(ushort4*)&aHi[row][lkq] = make_ushort4(h0, h1, h2, h3);
      *(ushort4*)&aLo[row][lkq] = make_ushort4(l0, l1, l2, l3);
    }
#pragma unroll
    for (int it = 0; it < 2; ++it) {
      const int row = it * 32 + lrow;
      const int n = n0 + row;
      float4 v = make_float4(0.f, 0.f, 0.f, 0.f);
      if (n < Nn && k0 + lkq < K)
        v = *(const float4*)&Bm[(size_t)n * K + k0 + lkq];
      ushort h0 = f2bf(v.x), h1 = f2bf(v.y), h2 = f2bf(v.z), h3 = f2bf(v.w);
      ushort l0 = f2bf(v.x - bf2f(h0)), l1 = f2bf(v.y - bf2f(h1));
      ushort l2 = f2bf(v.z - bf2f(h2)), l3 = f2bf(v.w - bf2f(h3));
      *(ushort4*)&bHi[row][lkq] = make_ushort4(h0, h1, h2, h3);
      *(ushort4*)&bLo[row][lkq] = make_ushort4(l0, l1, l2, l3);
    }
    __syncthreads();

    short8 ah[4], al[4], bh[2], bl[2];
#pragma unroll
    for (int i = 0; i < 4; ++i) {
      const int row = wr * 64 + i * 16 + lr15;
      ah[i] = *(const short8*)&aHi[row][lk8];
      al[i] = *(const short8*)&aLo[row][lk8];
    }
#pragma unroll
    for (int j = 0; j < 2; ++j) {
      const int row = wc * 32 + j * 16 + lr15;
      bh[j] = *(const short8*)&bHi[row][lk8];
      bl[j] = *(const short8*)&bLo[row][lk8];
    }
#pragma unroll
    for (int i = 0; i < 4; ++i)
#pragma unroll
      for (int j = 0; j < 2; ++j) {
        acc[i][j] = __builtin_amdgcn_mfma_f32_16x16x32_bf16(ah[i], bh[j], acc[i][j], 0, 0, 0);
        acc[i][j] = __builtin_amdgcn_mfma_f32_16x16x32_bf16(al[i], bh[j], acc[i][j], 0, 0, 0);
        acc[i][j] = __builtin_amdgcn_mfma_f32_16x16x32_bf16(ah[i], bl[j], acc[i][j], 0, 0, 0);
      }
  }

#pragma unroll
  for (int j = 0; j < 2; ++j) {
    const int col = n0 + wc * 32 + j * 16 + lr15;
    if (col >= Nn) continue;
    const float bv = bias ? bias[col] : 0.f;
#pragma unroll
    for (int i = 0; i < 4; ++i) {
#pragma unroll
      for (int r = 0; r < 4; ++r) {
        const int m = m0 + wr * 64 + i * 16 + (lane >> 4) * 4 + r;
        if (m < M) Cm[(size_t)m * Nn + col] = acc[i][j][r] + bv;
      }
    }
  }
}

// ---------------------------------------------------------------------------
// Adaptive avg-pool of spatial tokens -> rep[b][h][q][d]
// ---------------------------------------------------------------------------
__global__ void pool_kernel(const float* __restrict__ w, float* __restrict__ rep) {
  int q = blockIdx.x, b = blockIdx.y;
  int i = threadIdx.x;
  if (i >= INNERC) return;
  int pr = q / 10, pc = q % 10;
  float s = 0.f;
  for (int kr = 0; kr < 10; ++kr)
    for (int kc = 0; kc < 10; ++kc) {
      int tok = (pr * 10 + kr) * 100 + (pc * 10 + kc);
      s += w[((size_t)b * NTOK + tok) * INNERC + i];
    }
  s *= 0.01f;
  int h = i / DHEAD, d = i % DHEAD;
  rep[(((size_t)b * HEADS + h) * NQ + q) * DHEAD + d] = s;
}

// ---------------------------------------------------------------------------
// Stage-1 attention, MFMA split-flash.
// grid (NBH, NSPLIT), block 256 = 4 waves. Wave wv owns q-rows 32wv..32wv+31
// (Q padded to 128 rows, d padded to 64). Per 32-token tile:
//   S = Q K^T (split-bf16, 3 products), online softmax in C/D regs,
//   P hi/lo -> LDS, O += P V (split-bf16, 3 products, swizzled V^T).
// ---------------------------------------------------------------------------
__global__ __launch_bounds__(256, 3) void attn1_mfma(
    const float* __restrict__ w, const float* __restrict__ rep,
    float* __restrict__ m_part, float* __restrict__ l_part,
    float* __restrict__ delta_part) {
  const int bh = blockIdx.x, s = blockIdx.y;
  const int b = bh / HEADS, h = bh % HEADS;
  const int t = threadIdx.x;
  const int lane = t & 63, wv = t >> 6;
  const int l15 = lane & 15, l4 = lane >> 4;

  __shared__ ushort Khi[32][72], Klo[32][72];     // [tok][d]
  __shared__ ushort VThi[64][40], VTlo[64][40];   // [d][slot-rotated tok]
  __shared__ ushort Phi[128][40], Plo[128][40];   // [q][tok]

  // ---- Q fragments in registers (hi/lo), rows 32wv..+31, scaled ----
  short8 qhi[2][2], qlo[2][2];
#pragma unroll
  for (int mi = 0; mi < 2; ++mi) {
#pragma unroll
    for (int ks = 0; ks < 2; ++ks) {
      const int qr = 32 * wv + 16 * mi + l15;
      short8 th, tl;
#pragma unroll
      for (int j = 0; j < 8; ++j) {
        const int k = 32 * ks + 8 * l4 + j;
        float v = (qr < NQ && k < DHEAD)
                      ? rep[((size_t)bh * NQ + qr) * DHEAD + k] * SCALE : 0.f;
        ushort hh = f2bf(v);
        th[j] = (short)hh;
        tl[j] = (short)f2bf(v - bf2f(hh));
      }
      qhi[mi][ks] = th; qlo[mi][ks] = tl;
    }
  }

  f32x4 accO[2][4];
  float m_run[2][4], l_run[2][4];
#pragma unroll
  for (int mi = 0; mi < 2; ++mi) {
#pragma unroll
    for (int r = 0; r < 4; ++r) { m_run[mi][r] = NEGBIG; l_run[mi][r] = 0.f; }
#pragma unroll
    for (int di = 0; di < 4; ++di) accO[mi][di] = (f32x4){0.f, 0.f, 0.f, 0.f};
  }

  const int n0 = s * CHUNK;
  const int n1 = min(NTOK, n0 + CHUNK);

  for (int nt = n0; nt < n1; nt += 32) {
    __syncthreads();   // previous tile's S/PV reads done
    // ---- stage K (and slot-rotated V^T) hi/lo ----
#pragma unroll
    for (int i = 0; i < 8; ++i) {
      const int idx = t + i * 256;
      const int tr = idx >> 6, d = idx & 63;
      float v = (nt + tr < n1 && d < DHEAD)
                    ? w[((size_t)b * NTOK + nt + tr) * INNERC + h * DHEAD + d] : 0.f;
      ushort hh = f2bf(v);
      ushort ll = f2bf(v - bf2f(hh));
      Khi[tr][d] = hh; Klo[tr][d] = ll;
      const int ps = ((((tr >> 3) + (d >> 3)) & 3) << 3) + (tr & 7);
      VThi[d][ps] = hh; VTlo[d][ps] = ll;
    }
    __syncthreads();

    // ---- S = Q K^T ----
    f32x4 accS[2][2];
#pragma unroll
    for (int mi = 0; mi < 2; ++mi)
#pragma unroll
      for (int ni = 0; ni < 2; ++ni) accS[mi][ni] = (f32x4){0.f, 0.f, 0.f, 0.f};
#pragma unroll
    for (int ks = 0; ks < 2; ++ks) {
      short8 kh[2], kl[2];
#pragma unroll
      for (int ni = 0; ni < 2; ++ni) {
        kh[ni] = *(const short8*)&Khi[16 * ni + l15][32 * ks + 8 * l4];
        kl[ni] = *(const short8*)&Klo[16 * ni + l15][32 * ks + 8 * l4];
      }
#pragma unroll
      for (int mi = 0; mi < 2; ++mi)
#pragma unroll
        for (int ni = 0; ni < 2; ++ni) {
          accS[mi][ni] = __builtin_amdgcn_mfma_f32_16x16x32_bf16(qhi[mi][ks], kh[ni], accS[mi][ni], 0, 0, 0);
          accS[mi][ni] = __builtin_amdgcn_mfma_f32_16x16x32_bf16(qlo[mi][ks], kh[ni], accS[mi][ni], 0, 0, 0);
          accS[mi][ni] = __builtin_amdgcn_mfma_f32_16x16x32_bf16(qhi[mi][ks], kl[ni], accS[mi][ni], 0, 0, 0);
        }
    }

    // ---- online softmax (C/D layout: col=16ni+l15, row=32wv+16mi+4*l4+r) ----
    bool cval[2];
#pragma unroll
    for (int ni = 0; ni < 2; ++ni) cval[ni] = (nt + 16 * ni + l15) < n1;
#pragma unroll
    for (int mi = 0; mi < 2; ++mi) {
#pragma unroll
      for (int ni = 0; ni < 2; ++ni)
        if (!cval[ni]) {
#pragma unroll
          for (int r = 0; r < 4; ++r) accS[mi][ni][r] = NEGBIG;
        }
#pragma unroll
      for (int r = 0; r < 4; ++r) {
        float mx = fmaxf(accS[mi][0][r], accS[mi][1][r]);
        mx = fmaxf(mx, __shfl_xor(mx, 1));
        mx = fmaxf(mx, __shfl_xor(mx, 2));
        mx = fmaxf(mx, __shfl_xor(mx, 4));
        mx = fmaxf(mx, __shfl_xor(mx, 8));
        const float m_new = fmaxf(m_run[mi][r], mx);
        const float sc = __expf(m_run[mi][r] - m_new);
        m_run[mi][r] = m_new;
        l_run[mi][r] *= sc;
#pragma unroll
        for (int di = 0; di < 4; ++di) accO[mi][di][r] *= sc;
        float ps = 0.f;
#pragma unroll
        for (int ni = 0; ni < 2; ++ni) {
          const float p = __expf(accS[mi][ni][r] - m_new);
          accS[mi][ni][r] = p;
          ps += p;
        }
        ps += __shfl_xor(ps, 1);
        ps += __shfl_xor(ps, 2);
        ps += __shfl_xor(ps, 4);
        ps += __shfl_xor(ps, 8);
        l_run[mi][r] += ps;
      }
      // write P hi/lo to LDS (intra-wave producer/consumer, no barrier)
#pragma unroll
      for (int ni = 0; ni < 2; ++ni)
#pragma unroll
        for (int r = 0; r < 4; ++r) {
          const int row = 32 * wv + 16 * mi + 4 * l4 + r;
          const int col = 16 * ni + l15;
          const float p = accS[mi][ni][r];
          const ushort ph = f2bf(p);
          Phi[row][col] = ph;
          Plo[row][col] = f2bf(p - bf2f(ph));
        }
    }

    // ---- O += P V ----
#pragma unroll
    for (int mi = 0; mi < 2; ++mi) {
      const short8 pah = *(const short8*)&Phi[32 * wv + 16 * mi + l15][8 * l4];
      const short8 pal = *(const short8*)&Plo[32 * wv + 16 * mi + l15][8 * l4];
#pragma unroll
      for (int di = 0; di < 4; ++di) {
        const int vs = (((l4 + 2 * di + (l15 >> 3)) & 3)) << 3;
        const short8 vbh = *(const short8*)&VThi[16 * di + l15][vs];
        const short8 vbl = *(const short8*)&VTlo[16 * di + l15][vs];
        accO[mi][di] = __builtin_amdgcn_mfma_f32_16x16x32_bf16(pah, vbh, accO[mi][di], 0, 0, 0);
        accO[mi][di] = __builtin_amdgcn_mfma_f32_16x16x32_bf16(pal, vbh, accO[mi][di], 0, 0, 0);
        accO[mi][di] = __builtin_amdgcn_mfma_f32_16x16x32_bf16(pah, vbl, accO[mi][di], 0, 0, 0);
      }
    }
  }

  // ---- write partials ----
  const size_t base = ((size_t)bh * NSPLIT + s) * NQ;
#pragma unroll
  for (int mi = 0; mi < 2; ++mi)
#pragma unroll
    for (int r = 0; r < 4; ++r) {
      const int q = 32 * wv + 16 * mi + 4 * l4 + r;
      if (q < NQ && l15 == 0) {
        m_part[base + q] = m_run[mi][r];
        l_part[base + q] = l_run[mi][r];
      }
#pragma unroll
      for (int di = 0; di < 4; ++di) {
        const int d = 16 * di + l15;
        if (q < NQ && d < DHEAD)
          delta_part[(base + q) * DHEAD + d] = accO[mi][di][r];
      }
    }
}

// ---------------------------------------------------------------------------
// Combine split partials -> reph2 (updated rep), final m,l per (bh,q)
// ---------------------------------------------------------------------------
__global__ __launch_bounds__(256) void attn1_combine(
    const float* __restrict__ rep, const float* __restrict__ m_part,
    const float* __restrict__ l_part, const float* __restrict__ delta_part,
    const float* __restrict__ step_rep,
    float* __restrict__ reph2, float* __restrict__ m_fin, float* __restrict__ l_fin) {
  int bh = blockIdx.x;
  int h = bh % HEADS;
  int t = threadIdx.x;
  __shared__ float Mf[NQ], Lf[NQ];
  if (t < NQ) {
    int q = t;
    float M = -INFINITY;
#pragma unroll
    for (int s2 = 0; s2 < NSPLIT; ++s2)
      M = fmaxf(M, m_part[((size_t)bh * NSPLIT + s2) * NQ + q]);
    float L = 0.f;
#pragma unroll
    for (int s2 = 0; s2 < NSPLIT; ++s2)
      L += l_part[((size_t)bh * NSPLIT + s2) * NQ + q] *
           __expf(m_part[((size_t)bh * NSPLIT + s2) * NQ + q] - M);
    Mf[q] = M; Lf[q] = L;
    m_fin[(size_t)bh * NQ + q] = M;
    l_fin[(size_t)bh * NQ + q] = L;
  }
  __syncthreads();
  float sr = step_rep[h];
  for (int idx = t; idx < NQ * DHEAD; idx += 256) {
    int q = idx / DHEAD, d = idx % DHEAD;
    float sum = 0.f;
#pragma unroll
    for (int s2 = 0; s2 < NSPLIT; ++s2) {
      size_t pb = ((size_t)bh * NSPLIT + s2) * NQ + q;
      sum += __expf(m_part[pb] - Mf[q]) * delta_part[pb * DHEAD + d];
    }
    float rd = sum / Lf[q];
    reph2[(size_t)bh * NQ * DHEAD + idx] =
        rep[(size_t)bh * NQ * DHEAD + idx] + sr * rd;
  }
}

// ---------------------------------------------------------------------------
// Stage-2 self attention on reph2 -> xq = step_x[h] * (softmax(r2 r2^T s) r2)
// ---------------------------------------------------------------------------
__global__ __launch_bounds__(256) void attn2_kernel(
    const float* __restrict__ reph2, const float* __restrict__ step_x,
    float* __restrict__ xq) {
  int bh = blockIdx.x;
  int h = bh % HEADS;
  int t = threadIdx.x;
  __shared__ float r2[NQ * DHEAD];
  __shared__ float att[NQ * NQ];

  for (int idx = t; idx < NQ * DHEAD; idx += 256)
    r2[idx] = reph2[(size_t)bh * NQ * DHEAD + idx];
  __syncthreads();

  for (int idx = t; idx < NQ * NQ; idx += 256) {
    int qq = idx / NQ, jj = idx % NQ;
    float s = 0.f;
#pragma unroll
    for (int k = 0; k < DHEAD; ++k) s += r2[qq * DHEAD + k] * r2[jj * DHEAD + k];
    att[idx] = s * SCALE;
  }
  __syncthreads();
  if (t < NQ) {
    float M = -INFINITY;
    for (int j = 0; j < NQ; ++j) M = fmaxf(M, att[t * NQ + j]);
    float L = 0.f;
    for (int j = 0; j < NQ; ++j) { float e = __expf(att[t * NQ + j] - M); att[t * NQ + j] = e; L += e; }
    float inv = 1.f / L;
    for (int j = 0; j < NQ; ++j) att[t * NQ + j] *= inv;
  }
  __syncthreads();
  float sx = step_x[h];
  for (int idx = t; idx < NQ * DHEAD; idx += 256) {
    int qd_q = idx / DHEAD, d = idx % DHEAD;
    float v = 0.f;
#pragma unroll
    for (int j = 0; j < NQ; ++j) v += att[qd_q * NQ + j] * r2[j * DHEAD + d];
    xq[(size_t)bh * NQ * DHEAD + idx] = sx * v;
  }
}

// ---------------------------------------------------------------------------
// Pass 2: per (128-token tile, b, h): recompute attn columns from (m,l)
// and apply attn^T @ xq, fully LDS/register resident.
// ---------------------------------------------------------------------------
#define TTOK2 128
#define QCH   20
__global__ __launch_bounds__(256) void bcast2_kernel(
    const float* __restrict__ w, const float* __restrict__ rep,
    const float* __restrict__ xq, const float* __restrict__ m_fin,
    const float* __restrict__ l_fin, float* __restrict__ xd) {
  const int tile = blockIdx.x, bh = blockIdx.y;
  const int b = bh / HEADS, h = bh % HEADS;
  const int tok0 = tile * TTOK2;
  const int t = threadIdx.x;

  __shared__ float wT[DHEAD][TTOK2 + 2];
  __shared__ float pch[QCH][TTOK2 + 2];
  __shared__ float rq[QCH][DHEAD + 2];
  __shared__ float xqs[QCH][DHEAD + 2];
  __shared__ float mi[QCH], linv[QCH];

  for (int idx = t; idx < TTOK2 * DHEAD; idx += 256) {
    int tok = idx / DHEAD, k = idx % DHEAD;
    float v = (tok0 + tok < NTOK)
                  ? w[((size_t)b * NTOK + tok0 + tok) * INNERC + h * DHEAD + k]
                  : 0.f;
    wT[k][tok] = v;
  }

  const int mytok = t & (TTOK2 - 1);
  const int dh = t >> 7;
  float acc[25];
#pragma unroll
  for (int dd = 0; dd < 25; ++dd) acc[dd] = 0.f;

  for (int q0 = 0; q0 < NQ; q0 += QCH) {
    for (int idx = t; idx < QCH * DHEAD; idx += 256) {
      int qq = idx / DHEAD, k = idx % DHEAD;
      rq[qq][k] = rep[((size_t)bh * NQ + q0 + qq) * DHEAD + k] * SCALE;
      xqs[qq][k] = xq[((size_t)bh * NQ + q0 + qq) * DHEAD + k];
    }
    if (t < QCH) {
      mi[t] = m_fin[(size_t)bh * NQ + q0 + t];
      linv[t] = 1.f / l_fin[(size_t)bh * NQ + q0 + t];
    }
    __syncthreads();

    for (int idx = t; idx < QCH * TTOK2; idx += 256) {
      int tok = idx & (TTOK2 - 1), qq = idx >> 7;
      float dsum = 0.f;
#pragma unroll
      for (int k = 0; k < DHEAD; ++k) dsum += rq[qq][k] * wT[k][tok];
      pch[qq][tok] = __expf(dsum - mi[qq]) * linv[qq];
    }
    __syncthreads();

#pragma unroll
    for (int qq = 0; qq < QCH; ++qq) {
      float pv = pch[qq][mytok];
#pragma unroll
      for (int dd = 0; dd < 25; ++dd) acc[dd] += pv * xqs[qq][dh * 25 + dd];
    }
    __syncthreads();
  }

  if (tok0 + mytok < NTOK) {
    float* op = &xd[((size_t)b * NTOK + tok0 + mytok) * INNERC + h * DHEAD + dh * 25];
#pragma unroll
    for (int dd = 0; dd < 25; ++dd) op[dd] = acc[dd];
  }
}

// ---------------------------------------------------------------------------
extern "C" void kernel_launch(void* const* d_in, const int* in_sizes, int n_in,
                              void* d_out, int out_size, void* d_ws, size_t ws_size,
                              hipStream_t stream) {
  const float* x        = (const float*)d_in[0];
  const float* proj_w   = (const float*)d_in[1];
  const float* step_x   = (const float*)d_in[2];
  const float* step_rep = (const float*)d_in[3];
  const float* out_w    = (const float*)d_in[4];
  const float* out_b    = (const float*)d_in[5];
  float* out = (float*)d_out;

  float* ws = (float*)d_ws;
  float* w      = ws;                       // 24,360,000
  float* rep    = w      + 24360000;        //    240,000
  float* reph2  = rep    + 240000;          //    240,000
  float* xq     = reph2  + 240000;          //    240,000
  float* m_part = xq     + 240000;          //     76,800  (48*16*100)
  float* l_part = m_part + 76800;           //     76,800
  float* m_fin  = l_part + 76800;           //      4,800
  float* l_fin  = m_fin  + 4800;            //      4,800
  float* xd     = l_fin  + 4800;            // 24,360,000
  // delta_part (48*16*100*50 = 3,840,000) aliases xd: combine consumes it
  // before bcast2 overwrites xd (stream-ordered).
  float* delta  = xd;

  // 1. w = x @ proj_w^T   [81200 x 300], K=768  (split-bf16 MFMA)
  gemm_nt_mfma<<<dim3(5, 635), 256, 0, stream>>>(x, proj_w, w, nullptr, MTOT, INNERC, DIMC);
  // 2. pooling -> rep[b][h][q][d]
  pool_kernel<<<dim3(NQ, BATCH), 320, 0, stream>>>(w, rep);
  // 3. stage-1 attention (MFMA split flash) + combine
  attn1_mfma<<<dim3(NBH, NSPLIT), 256, 0, stream>>>(w, rep, m_part, l_part, delta);
  attn1_combine<<<NBH, 256, 0, stream>>>(rep, m_part, l_part, delta, step_rep,
                                         reph2, m_fin, l_fin);
  // 4. stage-2 self-attention -> xq (pre-scaled by step_x)
  attn2_kernel<<<NBH, 256, 0, stream>>>(reph2, step_x, xq);
  // 5. broadcast back through attn^T -> xd[b][n][300]
  bcast2_kernel<<<dim3(80, NBH), 256, 0, stream>>>(w, rep, xq, m_fin, l_fin, xd);
  // 6. out = xd @ out_w^T + out_b   [81200 x 768], K=300  (split-bf16 MFMA)
  gemm_nt_mfma<<<dim3(12, 635), 256, 0, stream>>>(xd, out_w, out, out_b, MTOT, DIMC, INNERC);
}

// Round 6
// 1192.204 us; speedup vs baseline: 2.1920x; 1.1861x over previous
//
#include <hip/hip_runtime.h>
#include <math.h>

#define BATCH   8
#define NTOK    10150
#define DIMC    768
#define INNERC  300
#define HEADS   6
#define DHEAD   50
#define NQ      100
#define NBH     48          // BATCH*HEADS
#define NSPLIT  16
#define CHUNK   640         // 16*640 = 10240 >= 10150; all splits non-empty
#define SCALE   0.14142135623730951f   // 50^-0.5
#define MTOT    (BATCH*NTOK)           // 81200
#define NEGBIG  -1.0e30f

typedef __attribute__((ext_vector_type(8))) short short8;
typedef __attribute__((ext_vector_type(4))) float f32x4;

__device__ __forceinline__ ushort f2bf(float x) {
  uint u = __float_as_uint(x);
  uint r = (u + 0x7fffu + ((u >> 16) & 1u)) >> 16;
  return (ushort)r;
}
__device__ __forceinline__ float bf2f(ushort h) {
  return __uint_as_float(((uint)h) << 16);
}
__device__ __forceinline__ void split4(float4 v, ushort4& hi, ushort4& lo) {
  ushort h0 = f2bf(v.x), h1 = f2bf(v.y), h2 = f2bf(v.z), h3 = f2bf(v.w);
  hi = make_ushort4(h0, h1, h2, h3);
  lo = make_ushort4(f2bf(v.x - bf2f(h0)), f2bf(v.y - bf2f(h1)),
                    f2bf(v.z - bf2f(h2)), f2bf(v.w - bf2f(h3)));
}

// ---------------------------------------------------------------------------
// Split-bf16 MFMA GEMM (NT): C[m][n] = sum_k A[m][k]*B[n][k] (+ bias[n])
// (unchanged from round 3 — verified)
// ---------------------------------------------------------------------------
#define BM 128
#define BN 64
#define BK 32
#define LDK 40
__global__ __launch_bounds__(256) void gemm_nt_mfma(
    const float* __restrict__ A, const float* __restrict__ Bm,
    float* __restrict__ Cm, const float* __restrict__ bias,
    int M, int Nn, int K) {
  __shared__ ushort aHi[BM][LDK], aLo[BM][LDK];
  __shared__ ushort bHi[BN][LDK], bLo[BN][LDK];
  const int t = threadIdx.x;
  const int lane = t & 63;
  const int wid = t >> 6;
  const int wr = wid >> 1, wc = wid & 1;
  const int n0 = blockIdx.x * BN;
  const int m0 = blockIdx.y * BM;
  const int lrow = t >> 3;
  const int lkq = (t & 7) * 4;

  f32x4 acc[4][2];
#pragma unroll
  for (int i = 0; i < 4; ++i)
#pragma unroll
    for (int j = 0; j < 2; ++j) acc[i][j] = (f32x4){0.f, 0.f, 0.f, 0.f};

  const int lr15 = lane & 15;
  const int lk8 = (lane >> 4) * 8;

  for (int k0 = 0; k0 < K; k0 += BK) {
    __syncthreads();
#pragma unroll
    for (int it = 0; it < 4; ++it) {
      const int row = it * 32 + lrow;
      const int m = m0 + row;
      float4 v = make_float4(0.f, 0.f, 0.f, 0.f);
      if (m < M && k0 + lkq < K)
        v = *(const float4*)&A[(size_t)m * K + k0 + lkq];
      ushort4 hi, lo; split4(v, hi, lo);
      *(ushort4*)&aHi[row][lkq] = hi;
      *(ushort4*)&aLo[row][lkq] = lo;
    }
#pragma unroll
    for (int it = 0; it < 2; ++it) {
      const int row = it * 32 + lrow;
      const int n = n0 + row;
      float4 v = make_float4(0.f, 0.f, 0.f, 0.f);
      if (n < Nn && k0 + lkq < K)
        v = *(const float4*)&Bm[(size_t)n * K + k0 + lkq];
      ushort4 hi, lo; split4(v, hi, lo);
      *(ushort4*)&bHi[row][lkq] = hi;
      *(ushort4*)&bLo[row][lkq] = lo;
    }
    __syncthreads();

    short8 ah[4], al[4], bh[2], bl[2];
#pragma unroll
    for (int i = 0; i < 4; ++i) {
      const int row = wr * 64 + i * 16 + lr15;
      ah[i] = *(const short8*)&aHi[row][lk8];
      al[i] = *(const short8*)&aLo[row][lk8];
    }
#pragma unroll
    for (int j = 0; j < 2; ++j) {
      const int row = wc * 32 + j * 16 + lr15;
      bh[j] = *(const short8*)&bHi[row][lk8];
      bl[j] = *(const short8*)&bLo[row][lk8];
    }
#pragma unroll
    for (int i = 0; i < 4; ++i)
#pragma unroll
      for (int j = 0; j < 2; ++j) {
        acc[i][j] = __builtin_amdgcn_mfma_f32_16x16x32_bf16(ah[i], bh[j], acc[i][j], 0, 0, 0);
        acc[i][j] = __builtin_amdgcn_mfma_f32_16x16x32_bf16(al[i], bh[j], acc[i][j], 0, 0, 0);
        acc[i][j] = __builtin_amdgcn_mfma_f32_16x16x32_bf16(ah[i], bl[j], acc[i][j], 0, 0, 0);
      }
  }

#pragma unroll
  for (int j = 0; j < 2; ++j) {
    const int col = n0 + wc * 32 + j * 16 + lr15;
    if (col >= Nn) continue;
    const float bv = bias ? bias[col] : 0.f;
#pragma unroll
    for (int i = 0; i < 4; ++i) {
#pragma unroll
      for (int r = 0; r < 4; ++r) {
        const int m = m0 + wr * 64 + i * 16 + (lane >> 4) * 4 + r;
        if (m < M) Cm[(size_t)m * Nn + col] = acc[i][j][r] + bv;
      }
    }
  }
}

// ---------------------------------------------------------------------------
// Adaptive avg-pool of spatial tokens -> rep[b][h][q][d]
// ---------------------------------------------------------------------------
__global__ void pool_kernel(const float* __restrict__ w, float* __restrict__ rep) {
  int q = blockIdx.x, b = blockIdx.y;
  int i = threadIdx.x;
  if (i >= INNERC) return;
  int pr = q / 10, pc = q % 10;
  float s = 0.f;
  for (int kr = 0; kr < 10; ++kr)
    for (int kc = 0; kc < 10; ++kc) {
      int tok = (pr * 10 + kr) * 100 + (pc * 10 + kc);
      s += w[((size_t)b * NTOK + tok) * INNERC + i];
    }
  s *= 0.01f;
  int h = i / DHEAD, d = i % DHEAD;
  rep[(((size_t)b * HEADS + h) * NQ + q) * DHEAD + d] = s;
}

// ---------------------------------------------------------------------------
// Stage-1 attention, MFMA split-flash.  (unchanged from round 4 — verified)
// ---------------------------------------------------------------------------
__global__ __launch_bounds__(256, 3) void attn1_mfma(
    const float* __restrict__ w, const float* __restrict__ rep,
    float* __restrict__ m_part, float* __restrict__ l_part,
    float* __restrict__ delta_part) {
  const int bh = blockIdx.x, s = blockIdx.y;
  const int b = bh / HEADS, h = bh % HEADS;
  const int t = threadIdx.x;
  const int lane = t & 63, wv = t >> 6;
  const int l15 = lane & 15, l4 = lane >> 4;

  __shared__ ushort Khi[32][72], Klo[32][72];
  __shared__ ushort VThi[64][40], VTlo[64][40];
  __shared__ ushort Phi[128][40], Plo[128][40];

  short8 qhi[2][2], qlo[2][2];
#pragma unroll
  for (int mi = 0; mi < 2; ++mi) {
#pragma unroll
    for (int ks = 0; ks < 2; ++ks) {
      const int qr = 32 * wv + 16 * mi + l15;
      short8 th, tl;
#pragma unroll
      for (int j = 0; j < 8; ++j) {
        const int k = 32 * ks + 8 * l4 + j;
        float v = (qr < NQ && k < DHEAD)
                      ? rep[((size_t)bh * NQ + qr) * DHEAD + k] * SCALE : 0.f;
        ushort hh = f2bf(v);
        th[j] = (short)hh;
        tl[j] = (short)f2bf(v - bf2f(hh));
      }
      qhi[mi][ks] = th; qlo[mi][ks] = tl;
    }
  }

  f32x4 accO[2][4];
  float m_run[2][4], l_run[2][4];
#pragma unroll
  for (int mi = 0; mi < 2; ++mi) {
#pragma unroll
    for (int r = 0; r < 4; ++r) { m_run[mi][r] = NEGBIG; l_run[mi][r] = 0.f; }
#pragma unroll
    for (int di = 0; di < 4; ++di) accO[mi][di] = (f32x4){0.f, 0.f, 0.f, 0.f};
  }

  const int n0 = s * CHUNK;
  const int n1 = min(NTOK, n0 + CHUNK);

  for (int nt = n0; nt < n1; nt += 32) {
    __syncthreads();
#pragma unroll
    for (int i = 0; i < 8; ++i) {
      const int idx = t + i * 256;
      const int tr = idx >> 6, d = idx & 63;
      float v = (nt + tr < n1 && d < DHEAD)
                    ? w[((size_t)b * NTOK + nt + tr) * INNERC + h * DHEAD + d] : 0.f;
      ushort hh = f2bf(v);
      ushort ll = f2bf(v - bf2f(hh));
      Khi[tr][d] = hh; Klo[tr][d] = ll;
      const int ps = ((((tr >> 3) + (d >> 3)) & 3) << 3) + (tr & 7);
      VThi[d][ps] = hh; VTlo[d][ps] = ll;
    }
    __syncthreads();

    f32x4 accS[2][2];
#pragma unroll
    for (int mi = 0; mi < 2; ++mi)
#pragma unroll
      for (int ni = 0; ni < 2; ++ni) accS[mi][ni] = (f32x4){0.f, 0.f, 0.f, 0.f};
#pragma unroll
    for (int ks = 0; ks < 2; ++ks) {
      short8 kh[2], kl[2];
#pragma unroll
      for (int ni = 0; ni < 2; ++ni) {
        kh[ni] = *(const short8*)&Khi[16 * ni + l15][32 * ks + 8 * l4];
        kl[ni] = *(const short8*)&Klo[16 * ni + l15][32 * ks + 8 * l4];
      }
#pragma unroll
      for (int mi = 0; mi < 2; ++mi)
#pragma unroll
        for (int ni = 0; ni < 2; ++ni) {
          accS[mi][ni] = __builtin_amdgcn_mfma_f32_16x16x32_bf16(qhi[mi][ks], kh[ni], accS[mi][ni], 0, 0, 0);
          accS[mi][ni] = __builtin_amdgcn_mfma_f32_16x16x32_bf16(qlo[mi][ks], kh[ni], accS[mi][ni], 0, 0, 0);
          accS[mi][ni] = __builtin_amdgcn_mfma_f32_16x16x32_bf16(qhi[mi][ks], kl[ni], accS[mi][ni], 0, 0, 0);
        }
    }

    bool cval[2];
#pragma unroll
    for (int ni = 0; ni < 2; ++ni) cval[ni] = (nt + 16 * ni + l15) < n1;
#pragma unroll
    for (int mi = 0; mi < 2; ++mi) {
#pragma unroll
      for (int ni = 0; ni < 2; ++ni)
        if (!cval[ni]) {
#pragma unroll
          for (int r = 0; r < 4; ++r) accS[mi][ni][r] = NEGBIG;
        }
#pragma unroll
      for (int r = 0; r < 4; ++r) {
        float mx = fmaxf(accS[mi][0][r], accS[mi][1][r]);
        mx = fmaxf(mx, __shfl_xor(mx, 1));
        mx = fmaxf(mx, __shfl_xor(mx, 2));
        mx = fmaxf(mx, __shfl_xor(mx, 4));
        mx = fmaxf(mx, __shfl_xor(mx, 8));
        const float m_new = fmaxf(m_run[mi][r], mx);
        const float sc = __expf(m_run[mi][r] - m_new);
        m_run[mi][r] = m_new;
        l_run[mi][r] *= sc;
#pragma unroll
        for (int di = 0; di < 4; ++di) accO[mi][di][r] *= sc;
        float ps = 0.f;
#pragma unroll
        for (int ni = 0; ni < 2; ++ni) {
          const float p = __expf(accS[mi][ni][r] - m_new);
          accS[mi][ni][r] = p;
          ps += p;
        }
        ps += __shfl_xor(ps, 1);
        ps += __shfl_xor(ps, 2);
        ps += __shfl_xor(ps, 4);
        ps += __shfl_xor(ps, 8);
        l_run[mi][r] += ps;
      }
#pragma unroll
      for (int ni = 0; ni < 2; ++ni)
#pragma unroll
        for (int r = 0; r < 4; ++r) {
          const int row = 32 * wv + 16 * mi + 4 * l4 + r;
          const int col = 16 * ni + l15;
          const float p = accS[mi][ni][r];
          const ushort ph = f2bf(p);
          Phi[row][col] = ph;
          Plo[row][col] = f2bf(p - bf2f(ph));
        }
    }

#pragma unroll
    for (int mi = 0; mi < 2; ++mi) {
      const short8 pah = *(const short8*)&Phi[32 * wv + 16 * mi + l15][8 * l4];
      const short8 pal = *(const short8*)&Plo[32 * wv + 16 * mi + l15][8 * l4];
#pragma unroll
      for (int di = 0; di < 4; ++di) {
        const int vs = (((l4 + 2 * di + (l15 >> 3)) & 3)) << 3;
        const short8 vbh = *(const short8*)&VThi[16 * di + l15][vs];
        const short8 vbl = *(const short8*)&VTlo[16 * di + l15][vs];
        accO[mi][di] = __builtin_amdgcn_mfma_f32_16x16x32_bf16(pah, vbh, accO[mi][di], 0, 0, 0);
        accO[mi][di] = __builtin_amdgcn_mfma_f32_16x16x32_bf16(pal, vbh, accO[mi][di], 0, 0, 0);
        accO[mi][di] = __builtin_amdgcn_mfma_f32_16x16x32_bf16(pah, vbl, accO[mi][di], 0, 0, 0);
      }
    }
  }

  const size_t base = ((size_t)bh * NSPLIT + s) * NQ;
#pragma unroll
  for (int mi = 0; mi < 2; ++mi)
#pragma unroll
    for (int r = 0; r < 4; ++r) {
      const int q = 32 * wv + 16 * mi + 4 * l4 + r;
      if (q < NQ && l15 == 0) {
        m_part[base + q] = m_run[mi][r];
        l_part[base + q] = l_run[mi][r];
      }
#pragma unroll
      for (int di = 0; di < 4; ++di) {
        const int d = 16 * di + l15;
        if (q < NQ && d < DHEAD)
          delta_part[(base + q) * DHEAD + d] = accO[mi][di][r];
      }
    }
}

// ---------------------------------------------------------------------------
// Combine split partials -> reph2 (updated rep), final m,l per (bh,q)
// ---------------------------------------------------------------------------
__global__ __launch_bounds__(256) void attn1_combine(
    const float* __restrict__ rep, const float* __restrict__ m_part,
    const float* __restrict__ l_part, const float* __restrict__ delta_part,
    const float* __restrict__ step_rep,
    float* __restrict__ reph2, float* __restrict__ m_fin, float* __restrict__ l_fin) {
  int bh = blockIdx.x;
  int h = bh % HEADS;
  int t = threadIdx.x;
  __shared__ float Mf[NQ], Lf[NQ];
  if (t < NQ) {
    int q = t;
    float M = -INFINITY;
#pragma unroll
    for (int s2 = 0; s2 < NSPLIT; ++s2)
      M = fmaxf(M, m_part[((size_t)bh * NSPLIT + s2) * NQ + q]);
    float L = 0.f;
#pragma unroll
    for (int s2 = 0; s2 < NSPLIT; ++s2)
      L += l_part[((size_t)bh * NSPLIT + s2) * NQ + q] *
           __expf(m_part[((size_t)bh * NSPLIT + s2) * NQ + q] - M);
    Mf[q] = M; Lf[q] = L;
    m_fin[(size_t)bh * NQ + q] = M;
    l_fin[(size_t)bh * NQ + q] = L;
  }
  __syncthreads();
  float sr = step_rep[h];
  for (int idx = t; idx < NQ * DHEAD; idx += 256) {
    int q = idx / DHEAD, d = idx % DHEAD;
    float sum = 0.f;
#pragma unroll
    for (int s2 = 0; s2 < NSPLIT; ++s2) {
      size_t pb = ((size_t)bh * NSPLIT + s2) * NQ + q;
      sum += __expf(m_part[pb] - Mf[q]) * delta_part[pb * DHEAD + d];
    }
    float rd = sum / Lf[q];
    reph2[(size_t)bh * NQ * DHEAD + idx] =
        rep[(size_t)bh * NQ * DHEAD + idx] + sr * rd;
  }
}

// ---------------------------------------------------------------------------
// Stage-2 self attention on reph2 -> xq = step_x[h] * (softmax(r2 r2^T s) r2)
// ---------------------------------------------------------------------------
__global__ __launch_bounds__(256) void attn2_kernel(
    const float* __restrict__ reph2, const float* __restrict__ step_x,
    float* __restrict__ xq) {
  int bh = blockIdx.x;
  int h = bh % HEADS;
  int t = threadIdx.x;
  __shared__ float r2[NQ * DHEAD];
  __shared__ float att[NQ * NQ];

  for (int idx = t; idx < NQ * DHEAD; idx += 256)
    r2[idx] = reph2[(size_t)bh * NQ * DHEAD + idx];
  __syncthreads();

  for (int idx = t; idx < NQ * NQ; idx += 256) {
    int qq = idx / NQ, jj = idx % NQ;
    float s = 0.f;
#pragma unroll
    for (int k = 0; k < DHEAD; ++k) s += r2[qq * DHEAD + k] * r2[jj * DHEAD + k];
    att[idx] = s * SCALE;
  }
  __syncthreads();
  if (t < NQ) {
    float M = -INFINITY;
    for (int j = 0; j < NQ; ++j) M = fmaxf(M, att[t * NQ + j]);
    float L = 0.f;
    for (int j = 0; j < NQ; ++j) { float e = __expf(att[t * NQ + j] - M); att[t * NQ + j] = e; L += e; }
    float inv = 1.f / L;
    for (int j = 0; j < NQ; ++j) att[t * NQ + j] *= inv;
  }
  __syncthreads();
  float sx = step_x[h];
  for (int idx = t; idx < NQ * DHEAD; idx += 256) {
    int qd_q = idx / DHEAD, d = idx % DHEAD;
    float v = 0.f;
#pragma unroll
    for (int j = 0; j < NQ; ++j) v += att[qd_q * NQ + j] * r2[j * DHEAD + d];
    xq[(size_t)bh * NQ * DHEAD + idx] = sx * v;
  }
}

// ---------------------------------------------------------------------------
// Pass 2 v3 (MFMA): per (64-token tile, bh):
//   S'[tok][q] = w_tile . (rep*SCALE)^T    (split-bf16 MFMA, NT)
//   p = exp(S'-m_fin[q])*linv[q]           (per-column m,l -> no reduce)
//   xd_tile[tok][d] += P . xqT^T           (split-bf16 MFMA, NT)
// q processed in 2 chunks of 64 (100 padded with zeros).
// LDS 73.7KB -> 2 blocks/CU. grid (159, NBH), 256 thr = 4 waves x 16 tok rows.
// ---------------------------------------------------------------------------
#define TT3 64
__global__ __launch_bounds__(256, 2) void bcast3_kernel(
    const float* __restrict__ w, const float* __restrict__ rep,
    const float* __restrict__ xq, const float* __restrict__ m_fin,
    const float* __restrict__ l_fin, float* __restrict__ xd) {
  const int tile = blockIdx.x, bh = blockIdx.y;
  const int b = bh / HEADS, h = bh % HEADS;
  const int tok0 = tile * TT3;
  const int t = threadIdx.x;
  const int lane = t & 63, wv = t >> 6;
  const int l15 = lane & 15, l4 = lane >> 4;

  __shared__ ushort wH[64][72], wL[64][72];   // A: w tile [tok][d]
  __shared__ ushort rH[64][72], rL[64][72];   // B1: rep chunk [q][d] (*SCALE)
  __shared__ ushort xH[64][72], xL[64][72];   // B2: xq^T chunk [d][q]
  __shared__ ushort pH[64][72], pL[64][72];   // A2: P [tok][q]

  // ---- stage w tile [64 tok][64 d] hi/lo (once) ----
#pragma unroll
  for (int i = 0; i < 4; ++i) {
    const int idx = t + i * 256;
    const int row = idx >> 4;
    const int d0 = (idx & 15) * 4;
    const int tok = tok0 + row;
    float4 v = make_float4(0.f, 0.f, 0.f, 0.f);
    if (tok < NTOK && d0 < DHEAD) {
      const float* wp = &w[((size_t)b * NTOK + tok) * INNERC + h * DHEAD];
      if (d0 + 3 < DHEAD) v = *(const float4*)&wp[d0];
      else { v.x = wp[d0]; if (d0 + 1 < DHEAD) v.y = wp[d0 + 1]; }
    }
    ushort4 hi, lo; split4(v, hi, lo);
    *(ushort4*)&wH[row][d0] = hi;
    *(ushort4*)&wL[row][d0] = lo;
  }

  f32x4 accO[4];
#pragma unroll
  for (int di = 0; di < 4; ++di) accO[di] = (f32x4){0.f, 0.f, 0.f, 0.f};

  for (int qc = 0; qc < 2; ++qc) {
    const int q0 = qc * 64;
    __syncthreads();   // prior chunk's readers done (also orders w staging)
    // ---- stage rep chunk [64 q][64 d] (*SCALE) ----
#pragma unroll
    for (int i = 0; i < 4; ++i) {
      const int idx = t + i * 256;
      const int row = idx >> 4;
      const int d0 = (idx & 15) * 4;
      const int q = q0 + row;
      float4 v = make_float4(0.f, 0.f, 0.f, 0.f);
      if (q < NQ && d0 < DHEAD) {
        const float* rp = &rep[((size_t)bh * NQ + q) * DHEAD];
        if (d0 + 3 < DHEAD) v = *(const float4*)&rp[d0];
        else { v.x = rp[d0]; if (d0 + 1 < DHEAD) v.y = rp[d0 + 1]; }
        v.x *= SCALE; v.y *= SCALE; v.z *= SCALE; v.w *= SCALE;
      }
      ushort4 hi, lo; split4(v, hi, lo);
      *(ushort4*)&rH[row][d0] = hi;
      *(ushort4*)&rL[row][d0] = lo;
    }
    // ---- stage xq^T chunk [64 d][64 q] ----
#pragma unroll
    for (int i = 0; i < 4; ++i) {
      const int idx = t + i * 256;
      const int drow = idx >> 4;
      const int ql0 = (idx & 15) * 4;
      float vv[4] = {0.f, 0.f, 0.f, 0.f};
      if (drow < DHEAD) {
#pragma unroll
        for (int j = 0; j < 4; ++j) {
          const int q = q0 + ql0 + j;
          if (q < NQ) vv[j] = xq[((size_t)bh * NQ + q) * DHEAD + drow];
        }
      }
      float4 v = make_float4(vv[0], vv[1], vv[2], vv[3]);
      ushort4 hi, lo; split4(v, hi, lo);
      *(ushort4*)&xH[drow][ql0] = hi;
      *(ushort4*)&xL[drow][ql0] = lo;
    }
    __syncthreads();

    // ---- S' = w . rep^T  (wave rows: tok = 16wv..+15) ----
    f32x4 accS[4];
#pragma unroll
    for (int ni = 0; ni < 4; ++ni) accS[ni] = (f32x4){0.f, 0.f, 0.f, 0.f};
#pragma unroll
    for (int ks = 0; ks < 2; ++ks) {
      const short8 ah = *(const short8*)&wH[wv * 16 + l15][ks * 32 + 8 * l4];
      const short8 al = *(const short8*)&wL[wv * 16 + l15][ks * 32 + 8 * l4];
#pragma unroll
      for (int ni = 0; ni < 4; ++ni) {
        const short8 bhf = *(const short8*)&rH[ni * 16 + l15][ks * 32 + 8 * l4];
        const short8 blf = *(const short8*)&rL[ni * 16 + l15][ks * 32 + 8 * l4];
        accS[ni] = __builtin_amdgcn_mfma_f32_16x16x32_bf16(ah, bhf, accS[ni], 0, 0, 0);
        accS[ni] = __builtin_amdgcn_mfma_f32_16x16x32_bf16(al, bhf, accS[ni], 0, 0, 0);
        accS[ni] = __builtin_amdgcn_mfma_f32_16x16x32_bf16(ah, blf, accS[ni], 0, 0, 0);
      }
    }

    // ---- p = exp(S'-m[q])*linv[q]; write P hi/lo (own wave rows only) ----
#pragma unroll
    for (int ni = 0; ni < 4; ++ni) {
      const int q = q0 + ni * 16 + l15;
      const bool valid = (q < NQ);
      float mq = 0.f, li = 0.f;
      if (valid) {
        mq = m_fin[(size_t)bh * NQ + q];
        li = 1.f / l_fin[(size_t)bh * NQ + q];
      }
#pragma unroll
      for (int r = 0; r < 4; ++r) {
        const float p = valid ? __expf(accS[ni][r] - mq) * li : 0.f;
        const int row = wv * 16 + 4 * l4 + r;
        const ushort ph = f2bf(p);
        pH[row][ni * 16 + l15] = ph;
        pL[row][ni * 16 + l15] = f2bf(p - bf2f(ph));
      }
    }
    // no barrier: PV reads only this wave's own 16 P-rows

    // ---- O += P . xqT^T ----
#pragma unroll
    for (int ks2 = 0; ks2 < 2; ++ks2) {
      const short8 pah = *(const short8*)&pH[wv * 16 + l15][ks2 * 32 + 8 * l4];
      const short8 pal = *(const short8*)&pL[wv * 16 + l15][ks2 * 32 + 8 * l4];
#pragma unroll
      for (int di = 0; di < 4; ++di) {
        const short8 vh = *(const short8*)&xH[di * 16 + l15][ks2 * 32 + 8 * l4];
        const short8 vl = *(const short8*)&xL[di * 16 + l15][ks2 * 32 + 8 * l4];
        accO[di] = __builtin_amdgcn_mfma_f32_16x16x32_bf16(pah, vh, accO[di], 0, 0, 0);
        accO[di] = __builtin_amdgcn_mfma_f32_16x16x32_bf16(pal, vh, accO[di], 0, 0, 0);
        accO[di] = __builtin_amdgcn_mfma_f32_16x16x32_bf16(pah, vl, accO[di], 0, 0, 0);
      }
    }
  }

  // ---- epilogue: C/D [tok][d], col=d=16di+l15, row=tok=16wv+4*l4+r ----
#pragma unroll
  for (int di = 0; di < 4; ++di) {
    const int d = di * 16 + l15;
    if (d >= DHEAD) continue;
#pragma unroll
    for (int r = 0; r < 4; ++r) {
      const int tok = tok0 + wv * 16 + 4 * l4 + r;
      if (tok < NTOK)
        xd[((size_t)b * NTOK + tok) * INNERC + h * DHEAD + d] = accO[di][r];
    }
  }
}

// ---------------------------------------------------------------------------
extern "C" void kernel_launch(void* const* d_in, const int* in_sizes, int n_in,
                              void* d_out, int out_size, void* d_ws, size_t ws_size,
                              hipStream_t stream) {
  const float* x        = (const float*)d_in[0];
  const float* proj_w   = (const float*)d_in[1];
  const float* step_x   = (const float*)d_in[2];
  const float* step_rep = (const float*)d_in[3];
  const float* out_w    = (const float*)d_in[4];
  const float* out_b    = (const float*)d_in[5];
  float* out = (float*)d_out;

  float* ws = (float*)d_ws;
  float* w      = ws;                       // 24,360,000
  float* rep    = w      + 24360000;        //    240,000
  float* reph2  = rep    + 240000;          //    240,000
  float* xq     = reph2  + 240000;          //    240,000
  float* m_part = xq     + 240000;          //     76,800  (48*16*100)
  float* l_part = m_part + 76800;           //     76,800
  float* m_fin  = l_part + 76800;           //      4,800
  float* l_fin  = m_fin  + 4800;            //      4,800
  float* xd     = l_fin  + 4800;            // 24,360,000
  // delta_part (48*16*100*50 = 3,840,000) aliases xd: combine consumes it
  // before bcast3 overwrites xd (stream-ordered).
  float* delta  = xd;

  // 1. w = x @ proj_w^T   [81200 x 300], K=768  (split-bf16 MFMA)
  gemm_nt_mfma<<<dim3(5, 635), 256, 0, stream>>>(x, proj_w, w, nullptr, MTOT, INNERC, DIMC);
  // 2. pooling -> rep[b][h][q][d]
  pool_kernel<<<dim3(NQ, BATCH), 320, 0, stream>>>(w, rep);
  // 3. stage-1 attention (MFMA split flash) + combine
  attn1_mfma<<<dim3(NBH, NSPLIT), 256, 0, stream>>>(w, rep, m_part, l_part, delta);
  attn1_combine<<<NBH, 256, 0, stream>>>(rep, m_part, l_part, delta, step_rep,
                                         reph2, m_fin, l_fin);
  // 4. stage-2 self-attention -> xq (pre-scaled by step_x)
  attn2_kernel<<<NBH, 256, 0, stream>>>(reph2, step_x, xq);
  // 5. broadcast back through attn^T -> xd[b][n][300]  (MFMA)
  bcast3_kernel<<<dim3(159, NBH), 256, 0, stream>>>(w, rep, xq, m_fin, l_fin, xd);
  // 6. out = xd @ out_w^T + out_b   [81200 x 768], K=300  (split-bf16 MFMA)
  gemm_nt_mfma<<<dim3(12, 635), 256, 0, stream>>>(xd, out_w, out, out_b, MTOT, DIMC, INNERC);
}

// Round 8
// 967.248 us; speedup vs baseline: 2.7018x; 1.2326x over previous
//
#include <hip/hip_runtime.h>
#include <math.h>

#define BATCH   8
#define NTOK    10150
#define DIMC    768
#define INNERC  300
#define HEADS   6
#define DHEAD   50
#define NQ      100
#define NBH     48          // BATCH*HEADS
#define NSPLIT  16
#define CHUNK   640         // 16*640 = 10240 >= 10150
#define SCALE   0.14142135623730951f   // 50^-0.5
#define MTOT    (BATCH*NTOK)           // 81200
#define XDK     320                    // padded K stride for xd planes
#define NEGBIG  -1.0e30f

typedef __attribute__((ext_vector_type(8))) short short8;
typedef __attribute__((ext_vector_type(4))) float f32x4;

__device__ __forceinline__ ushort f2bf(float x) {
  uint u = __float_as_uint(x);
  uint r = (u + 0x7fffu + ((u >> 16) & 1u)) >> 16;
  return (ushort)r;
}
__device__ __forceinline__ float bf2f(ushort h) {
  return __uint_as_float(((uint)h) << 16);
}

// ---------------------------------------------------------------------------
// Pre-split fp32 -> padded hi/lo bf16 planes.  dst is [Rp][Cp]; src [R][C].
// ---------------------------------------------------------------------------
__global__ void split_pad(const float* __restrict__ src, ushort* __restrict__ dHi,
                          ushort* __restrict__ dLo, int R, int C, int Rp, int Cp) {
  const int total = Rp * Cp;
  for (int i = blockIdx.x * blockDim.x + threadIdx.x; i < total;
       i += gridDim.x * blockDim.x) {
    const int r = i / Cp, c = i % Cp;
    const float v = (r < R && c < C) ? src[r * C + c] : 0.f;
    const ushort hh = f2bf(v);
    dHi[i] = hh;
    dLo[i] = f2bf(v - bf2f(hh));
  }
}

// Zero the k-pad columns (300..319) of the xd planes.
// MUST run AFTER attn1_combine (delta aliases xdHi) and BEFORE bcast3/gemm2.
__global__ void zero_xd_pad(ushort* __restrict__ xdHi, ushort* __restrict__ xdLo) {
  const int total = MTOT * 20;
  for (int i = blockIdx.x * blockDim.x + threadIdx.x; i < total;
       i += gridDim.x * blockDim.x) {
    const size_t g = (size_t)(i / 20) * XDK + 300 + (i % 20);
    xdHi[g] = 0;
    xdLo[g] = 0;
  }
}

// ---------------------------------------------------------------------------
// GEMM 1: w(planes) = x @ proj_w^T.   BM=64, BN=320 (single N pass), BK=32.
// A (x fp32) converted in-kernel ONCE; B from pre-split planes.
// ---------------------------------------------------------------------------
__global__ __launch_bounds__(256, 2) void gemm1_xw(
    const float* __restrict__ x, const ushort* __restrict__ pwHi,
    const ushort* __restrict__ pwLo, ushort* __restrict__ wHi,
    ushort* __restrict__ wLo) {
  __shared__ ushort aH[64][40], aL[64][40];
  __shared__ ushort bH[320][40], bL[320][40];
  const int t = threadIdx.x;
  const int lane = t & 63, wv = t >> 6;
  const int l15 = lane & 15, l4 = lane >> 4;
  const int m0 = blockIdx.x * 64;
  const int arow = t >> 2, aslot = t & 3;

  f32x4 acc[4][5];
#pragma unroll
  for (int i = 0; i < 4; ++i)
#pragma unroll
    for (int j = 0; j < 5; ++j) acc[i][j] = (f32x4){0.f, 0.f, 0.f, 0.f};

  for (int k0 = 0; k0 < DIMC; k0 += 32) {
    __syncthreads();
    // ---- stage A: each thread one 16B slot (8 elems), convert hi/lo ----
    {
      float v[8];
      const int m = m0 + arow;
      if (m < MTOT) {
        const float* xp = &x[(size_t)m * DIMC + k0 + aslot * 8];
        const float4 u0 = *(const float4*)xp;
        const float4 u1 = *(const float4*)(xp + 4);
        v[0] = u0.x; v[1] = u0.y; v[2] = u0.z; v[3] = u0.w;
        v[4] = u1.x; v[5] = u1.y; v[6] = u1.z; v[7] = u1.w;
      } else {
#pragma unroll
        for (int j = 0; j < 8; ++j) v[j] = 0.f;
      }
      short8 th, tl;
#pragma unroll
      for (int j = 0; j < 8; ++j) {
        const ushort hh = f2bf(v[j]);
        th[j] = (short)hh;
        tl[j] = (short)f2bf(v[j] - bf2f(hh));
      }
      *(short8*)&aH[arow][aslot * 8] = th;
      *(short8*)&aL[arow][aslot * 8] = tl;
    }
    // ---- stage B: plane copy, 5 slots per thread ----
#pragma unroll
    for (int i = 0; i < 5; ++i) {
      const int sid = t + i * 256;
      const int row = sid >> 2, slot = sid & 3;
      const size_t g = (size_t)row * DIMC + k0 + slot * 8;
      *(short8*)&bH[row][slot * 8] = *(const short8*)&pwHi[g];
      *(short8*)&bL[row][slot * 8] = *(const short8*)&pwLo[g];
    }
    __syncthreads();

    short8 ah[4], al[4];
#pragma unroll
    for (int i = 0; i < 4; ++i) {
      ah[i] = *(const short8*)&aH[i * 16 + l15][l4 * 8];
      al[i] = *(const short8*)&aL[i * 16 + l15][l4 * 8];
    }
#pragma unroll
    for (int j = 0; j < 5; ++j) {
      const int brow = wv * 80 + j * 16 + l15;
      const short8 bhf = *(const short8*)&bH[brow][l4 * 8];
      const short8 blf = *(const short8*)&bL[brow][l4 * 8];
#pragma unroll
      for (int i = 0; i < 4; ++i) {
        acc[i][j] = __builtin_amdgcn_mfma_f32_16x16x32_bf16(ah[i], bhf, acc[i][j], 0, 0, 0);
        acc[i][j] = __builtin_amdgcn_mfma_f32_16x16x32_bf16(al[i], bhf, acc[i][j], 0, 0, 0);
        acc[i][j] = __builtin_amdgcn_mfma_f32_16x16x32_bf16(ah[i], blf, acc[i][j], 0, 0, 0);
      }
    }
  }

  // ---- epilogue: write w hi/lo planes ----
#pragma unroll
  for (int j = 0; j < 5; ++j) {
    const int col = wv * 80 + j * 16 + l15;
    if (col >= INNERC) continue;
#pragma unroll
    for (int i = 0; i < 4; ++i)
#pragma unroll
      for (int r = 0; r < 4; ++r) {
        const int m = m0 + i * 16 + l4 * 4 + r;
        if (m < MTOT) {
          const float val = acc[i][j][r];
          const ushort hh = f2bf(val);
          const size_t g = (size_t)m * INNERC + col;
          wHi[g] = hh;
          wLo[g] = f2bf(val - bf2f(hh));
        }
      }
  }
}

// ---------------------------------------------------------------------------
// GEMM 2: out = xd(planes) @ out_w(planes)^T + bias.
// BM=64, BN=256, BK=32, K=320 (padded).  grid 1269*3, XCD-bijective swizzle.
// ---------------------------------------------------------------------------
__global__ __launch_bounds__(256, 2) void gemm2_out(
    const ushort* __restrict__ xdHi, const ushort* __restrict__ xdLo,
    const ushort* __restrict__ owHi, const ushort* __restrict__ owLo,
    const float* __restrict__ out_b, float* __restrict__ out) {
  __shared__ ushort aH[64][40], aL[64][40];
  __shared__ ushort bH[256][40], bL[256][40];
  const int t = threadIdx.x;
  const int lane = t & 63, wv = t >> 6;
  const int l15 = lane & 15, l4 = lane >> 4;
  const int nwg = gridDim.x;
  const int q = nwg >> 3, r = nwg & 7;
  const int xcd = blockIdx.x & 7, idx = blockIdx.x >> 3;
  const int wg = (xcd < r ? xcd * (q + 1) : r * (q + 1) + (xcd - r) * q) + idx;
  const int bn = wg % 3, bm = wg / 3;
  const int m0 = bm * 64, n0 = bn * 256;
  const int arow = t >> 2, aslot = t & 3;

  f32x4 acc[4][4];
#pragma unroll
  for (int i = 0; i < 4; ++i)
#pragma unroll
    for (int j = 0; j < 4; ++j) acc[i][j] = (f32x4){0.f, 0.f, 0.f, 0.f};

  for (int k0 = 0; k0 < XDK; k0 += 32) {
    __syncthreads();
    {
      const int m = m0 + arow;
      if (m < MTOT) {
        const size_t g = (size_t)m * XDK + k0 + aslot * 8;
        *(short8*)&aH[arow][aslot * 8] = *(const short8*)&xdHi[g];
        *(short8*)&aL[arow][aslot * 8] = *(const short8*)&xdLo[g];
      } else {
        const short8 z = {0, 0, 0, 0, 0, 0, 0, 0};
        *(short8*)&aH[arow][aslot * 8] = z;
        *(short8*)&aL[arow][aslot * 8] = z;
      }
    }
#pragma unroll
    for (int i = 0; i < 4; ++i) {
      const int sid = t + i * 256;
      const int row = sid >> 2, slot = sid & 3;
      const size_t g = (size_t)(n0 + row) * XDK + k0 + slot * 8;
      *(short8*)&bH[row][slot * 8] = *(const short8*)&owHi[g];
      *(short8*)&bL[row][slot * 8] = *(const short8*)&owLo[g];
    }
    __syncthreads();

    short8 ah[4], al[4];
#pragma unroll
    for (int i = 0; i < 4; ++i) {
      ah[i] = *(const short8*)&aH[i * 16 + l15][l4 * 8];
      al[i] = *(const short8*)&aL[i * 16 + l15][l4 * 8];
    }
#pragma unroll
    for (int j = 0; j < 4; ++j) {
      const int brow = wv * 64 + j * 16 + l15;
      const short8 bhf = *(const short8*)&bH[brow][l4 * 8];
      const short8 blf = *(const short8*)&bL[brow][l4 * 8];
#pragma unroll
      for (int i = 0; i < 4; ++i) {
        acc[i][j] = __builtin_amdgcn_mfma_f32_16x16x32_bf16(ah[i], bhf, acc[i][j], 0, 0, 0);
        acc[i][j] = __builtin_amdgcn_mfma_f32_16x16x32_bf16(al[i], bhf, acc[i][j], 0, 0, 0);
        acc[i][j] = __builtin_amdgcn_mfma_f32_16x16x32_bf16(ah[i], blf, acc[i][j], 0, 0, 0);
      }
    }
  }

#pragma unroll
  for (int j = 0; j < 4; ++j) {
    const int col = n0 + wv * 64 + j * 16 + l15;
    const float bv = out_b[col];
#pragma unroll
    for (int i = 0; i < 4; ++i)
#pragma unroll
      for (int r = 0; r < 4; ++r) {
        const int m = m0 + i * 16 + l4 * 4 + r;
        if (m < MTOT) out[(size_t)m * DIMC + col] = acc[i][j][r] + bv;
      }
  }
}

// ---------------------------------------------------------------------------
// Adaptive avg-pool (reads w planes) -> rep[b][h][q][d]
// ---------------------------------------------------------------------------
__global__ void pool_kernel(const ushort* __restrict__ wHi,
                            const ushort* __restrict__ wLo,
                            float* __restrict__ rep) {
  int q = blockIdx.x, b = blockIdx.y;
  int i = threadIdx.x;
  if (i >= INNERC) return;
  int pr = q / 10, pc = q % 10;
  float s = 0.f;
  for (int kr = 0; kr < 10; ++kr)
    for (int kc = 0; kc < 10; ++kc) {
      int tok = (pr * 10 + kr) * 100 + (pc * 10 + kc);
      const size_t g = ((size_t)b * NTOK + tok) * INNERC + i;
      s += bf2f(wHi[g]) + bf2f(wLo[g]);
    }
  s *= 0.01f;
  int h = i / DHEAD, d = i % DHEAD;
  rep[(((size_t)b * HEADS + h) * NQ + q) * DHEAD + d] = s;
}

// ---------------------------------------------------------------------------
// Stage-1 attention, MFMA split-flash (K/V staged from w planes — no convert)
// ---------------------------------------------------------------------------
__global__ __launch_bounds__(256, 3) void attn1_mfma(
    const ushort* __restrict__ wHi, const ushort* __restrict__ wLo,
    const float* __restrict__ rep,
    float* __restrict__ m_part, float* __restrict__ l_part,
    float* __restrict__ delta_part) {
  const int bh = blockIdx.x, s = blockIdx.y;
  const int b = bh / HEADS, h = bh % HEADS;
  const int t = threadIdx.x;
  const int lane = t & 63, wv = t >> 6;
  const int l15 = lane & 15, l4 = lane >> 4;

  __shared__ ushort Khi[32][72], Klo[32][72];
  __shared__ ushort VThi[64][40], VTlo[64][40];
  __shared__ ushort Phi[128][40], Plo[128][40];

  short8 qhi[2][2], qlo[2][2];
#pragma unroll
  for (int mi = 0; mi < 2; ++mi) {
#pragma unroll
    for (int ks = 0; ks < 2; ++ks) {
      const int qr = 32 * wv + 16 * mi + l15;
      short8 th, tl;
#pragma unroll
      for (int j = 0; j < 8; ++j) {
        const int k = 32 * ks + 8 * l4 + j;
        float v = (qr < NQ && k < DHEAD)
                      ? rep[((size_t)bh * NQ + qr) * DHEAD + k] * SCALE : 0.f;
        ushort hh = f2bf(v);
        th[j] = (short)hh;
        tl[j] = (short)f2bf(v - bf2f(hh));
      }
      qhi[mi][ks] = th; qlo[mi][ks] = tl;
    }
  }

  f32x4 accO[2][4];
  float m_run[2][4], l_run[2][4];
#pragma unroll
  for (int mi = 0; mi < 2; ++mi) {
#pragma unroll
    for (int r = 0; r < 4; ++r) { m_run[mi][r] = NEGBIG; l_run[mi][r] = 0.f; }
#pragma unroll
    for (int di = 0; di < 4; ++di) accO[mi][di] = (f32x4){0.f, 0.f, 0.f, 0.f};
  }

  const int n0 = s * CHUNK;
  const int n1 = min(NTOK, n0 + CHUNK);

  for (int nt = n0; nt < n1; nt += 32) {
    __syncthreads();
#pragma unroll
    for (int i = 0; i < 8; ++i) {
      const int idx = t + i * 256;
      const int tr = idx >> 6, d = idx & 63;
      const bool inb = (nt + tr < n1) && (d < DHEAD);
      ushort hh = 0, ll = 0;
      if (inb) {
        const size_t g = ((size_t)b * NTOK + nt + tr) * INNERC + h * DHEAD + d;
        hh = wHi[g]; ll = wLo[g];
      }
      Khi[tr][d] = hh; Klo[tr][d] = ll;
      const int ps = ((((tr >> 3) + (d >> 3)) & 3) << 3) + (tr & 7);
      VThi[d][ps] = hh; VTlo[d][ps] = ll;
    }
    __syncthreads();

    f32x4 accS[2][2];
#pragma unroll
    for (int mi = 0; mi < 2; ++mi)
#pragma unroll
      for (int ni = 0; ni < 2; ++ni) accS[mi][ni] = (f32x4){0.f, 0.f, 0.f, 0.f};
#pragma unroll
    for (int ks = 0; ks < 2; ++ks) {
      short8 kh[2], kl[2];
#pragma unroll
      for (int ni = 0; ni < 2; ++ni) {
        kh[ni] = *(const short8*)&Khi[16 * ni + l15][32 * ks + 8 * l4];
        kl[ni] = *(const short8*)&Klo[16 * ni + l15][32 * ks + 8 * l4];
      }
#pragma unroll
      for (int mi = 0; mi < 2; ++mi)
#pragma unroll
        for (int ni = 0; ni < 2; ++ni) {
          accS[mi][ni] = __builtin_amdgcn_mfma_f32_16x16x32_bf16(qhi[mi][ks], kh[ni], accS[mi][ni], 0, 0, 0);
          accS[mi][ni] = __builtin_amdgcn_mfma_f32_16x16x32_bf16(qlo[mi][ks], kh[ni], accS[mi][ni], 0, 0, 0);
          accS[mi][ni] = __builtin_amdgcn_mfma_f32_16x16x32_bf16(qhi[mi][ks], kl[ni], accS[mi][ni], 0, 0, 0);
        }
    }

    bool cval[2];
#pragma unroll
    for (int ni = 0; ni < 2; ++ni) cval[ni] = (nt + 16 * ni + l15) < n1;
#pragma unroll
    for (int mi = 0; mi < 2; ++mi) {
#pragma unroll
      for (int ni = 0; ni < 2; ++ni)
        if (!cval[ni]) {
#pragma unroll
          for (int r = 0; r < 4; ++r) accS[mi][ni][r] = NEGBIG;
        }
#pragma unroll
      for (int r = 0; r < 4; ++r) {
        float mx = fmaxf(accS[mi][0][r], accS[mi][1][r]);
        mx = fmaxf(mx, __shfl_xor(mx, 1));
        mx = fmaxf(mx, __shfl_xor(mx, 2));
        mx = fmaxf(mx, __shfl_xor(mx, 4));
        mx = fmaxf(mx, __shfl_xor(mx, 8));
        const float m_new = fmaxf(m_run[mi][r], mx);
        const float sc = __expf(m_run[mi][r] - m_new);
        m_run[mi][r] = m_new;
        l_run[mi][r] *= sc;
#pragma unroll
        for (int di = 0; di < 4; ++di) accO[mi][di][r] *= sc;
        float ps = 0.f;
#pragma unroll
        for (int ni = 0; ni < 2; ++ni) {
          const float p = __expf(accS[mi][ni][r] - m_new);
          accS[mi][ni][r] = p;
          ps += p;
        }
        ps += __shfl_xor(ps, 1);
        ps += __shfl_xor(ps, 2);
        ps += __shfl_xor(ps, 4);
        ps += __shfl_xor(ps, 8);
        l_run[mi][r] += ps;
      }
#pragma unroll
      for (int ni = 0; ni < 2; ++ni)
#pragma unroll
        for (int r = 0; r < 4; ++r) {
          const int row = 32 * wv + 16 * mi + 4 * l4 + r;
          const int col = 16 * ni + l15;
          const float p = accS[mi][ni][r];
          const ushort ph = f2bf(p);
          Phi[row][col] = ph;
          Plo[row][col] = f2bf(p - bf2f(ph));
        }
    }

#pragma unroll
    for (int mi = 0; mi < 2; ++mi) {
      const short8 pah = *(const short8*)&Phi[32 * wv + 16 * mi + l15][8 * l4];
      const short8 pal = *(const short8*)&Plo[32 * wv + 16 * mi + l15][8 * l4];
#pragma unroll
      for (int di = 0; di < 4; ++di) {
        const int vs = (((l4 + 2 * di + (l15 >> 3)) & 3)) << 3;
        const short8 vbh = *(const short8*)&VThi[16 * di + l15][vs];
        const short8 vbl = *(const short8*)&VTlo[16 * di + l15][vs];
        accO[mi][di] = __builtin_amdgcn_mfma_f32_16x16x32_bf16(pah, vbh, accO[mi][di], 0, 0, 0);
        accO[mi][di] = __builtin_amdgcn_mfma_f32_16x16x32_bf16(pal, vbh, accO[mi][di], 0, 0, 0);
        accO[mi][di] = __builtin_amdgcn_mfma_f32_16x16x32_bf16(pah, vbl, accO[mi][di], 0, 0, 0);
      }
    }
  }

  const size_t base = ((size_t)bh * NSPLIT + s) * NQ;
#pragma unroll
  for (int mi = 0; mi < 2; ++mi)
#pragma unroll
    for (int r = 0; r < 4; ++r) {
      const int q = 32 * wv + 16 * mi + 4 * l4 + r;
      if (q < NQ && l15 == 0) {
        m_part[base + q] = m_run[mi][r];
        l_part[base + q] = l_run[mi][r];
      }
#pragma unroll
      for (int di = 0; di < 4; ++di) {
        const int d = 16 * di + l15;
        if (q < NQ && d < DHEAD)
          delta_part[(base + q) * DHEAD + d] = accO[mi][di][r];
      }
    }
}

// ---------------------------------------------------------------------------
// Combine split partials -> reph2, final m,l per (bh,q)
// ---------------------------------------------------------------------------
__global__ __launch_bounds__(256) void attn1_combine(
    const float* __restrict__ rep, const float* __restrict__ m_part,
    const float* __restrict__ l_part, const float* __restrict__ delta_part,
    const float* __restrict__ step_rep,
    float* __restrict__ reph2, float* __restrict__ m_fin, float* __restrict__ l_fin) {
  int bh = blockIdx.x;
  int h = bh % HEADS;
  int t = threadIdx.x;
  __shared__ float Mf[NQ], Lf[NQ];
  if (t < NQ) {
    int q = t;
    float M = -INFINITY;
#pragma unroll
    for (int s2 = 0; s2 < NSPLIT; ++s2)
      M = fmaxf(M, m_part[((size_t)bh * NSPLIT + s2) * NQ + q]);
    float L = 0.f;
#pragma unroll
    for (int s2 = 0; s2 < NSPLIT; ++s2)
      L += l_part[((size_t)bh * NSPLIT + s2) * NQ + q] *
           __expf(m_part[((size_t)bh * NSPLIT + s2) * NQ + q] - M);
    Mf[q] = M; Lf[q] = L;
    m_fin[(size_t)bh * NQ + q] = M;
    l_fin[(size_t)bh * NQ + q] = L;
  }
  __syncthreads();
  float sr = step_rep[h];
  for (int idx = t; idx < NQ * DHEAD; idx += 256) {
    int q = idx / DHEAD, d = idx % DHEAD;
    float sum = 0.f;
#pragma unroll
    for (int s2 = 0; s2 < NSPLIT; ++s2) {
      size_t pb = ((size_t)bh * NSPLIT + s2) * NQ + q;
      sum += __expf(m_part[pb] - Mf[q]) * delta_part[pb * DHEAD + d];
    }
    float rd = sum / Lf[q];
    reph2[(size_t)bh * NQ * DHEAD + idx] =
        rep[(size_t)bh * NQ * DHEAD + idx] + sr * rd;
  }
}

// ---------------------------------------------------------------------------
// Stage-2 self attention -> xq = step_x[h] * (softmax(r2 r2^T s) r2)
// ---------------------------------------------------------------------------
__global__ __launch_bounds__(256) void attn2_kernel(
    const float* __restrict__ reph2, const float* __restrict__ step_x,
    float* __restrict__ xq) {
  int bh = blockIdx.x;
  int h = bh % HEADS;
  int t = threadIdx.x;
  __shared__ float r2[NQ * DHEAD];
  __shared__ float att[NQ * NQ];

  for (int idx = t; idx < NQ * DHEAD; idx += 256)
    r2[idx] = reph2[(size_t)bh * NQ * DHEAD + idx];
  __syncthreads();

  for (int idx = t; idx < NQ * NQ; idx += 256) {
    int qq = idx / NQ, jj = idx % NQ;
    float s = 0.f;
#pragma unroll
    for (int k = 0; k < DHEAD; ++k) s += r2[qq * DHEAD + k] * r2[jj * DHEAD + k];
    att[idx] = s * SCALE;
  }
  __syncthreads();
  if (t < NQ) {
    float M = -INFINITY;
    for (int j = 0; j < NQ; ++j) M = fmaxf(M, att[t * NQ + j]);
    float L = 0.f;
    for (int j = 0; j < NQ; ++j) { float e = __expf(att[t * NQ + j] - M); att[t * NQ + j] = e; L += e; }
    float inv = 1.f / L;
    for (int j = 0; j < NQ; ++j) att[t * NQ + j] *= inv;
  }
  __syncthreads();
  float sx = step_x[h];
  for (int idx = t; idx < NQ * DHEAD; idx += 256) {
    int qd_q = idx / DHEAD, d = idx % DHEAD;
    float v = 0.f;
#pragma unroll
    for (int j = 0; j < NQ; ++j) v += att[qd_q * NQ + j] * r2[j * DHEAD + d];
    xq[(size_t)bh * NQ * DHEAD + idx] = sx * v;
  }
}

// ---------------------------------------------------------------------------
// Pass 2 (MFMA): w planes in, xd planes out.
// ---------------------------------------------------------------------------
#define TT3 64
__global__ __launch_bounds__(256, 2) void bcast3_kernel(
    const ushort* __restrict__ wHi, const ushort* __restrict__ wLo,
    const float* __restrict__ rep, const float* __restrict__ xq,
    const float* __restrict__ m_fin, const float* __restrict__ l_fin,
    ushort* __restrict__ xdHi, ushort* __restrict__ xdLo) {
  const int tile = blockIdx.x, bh = blockIdx.y;
  const int b = bh / HEADS, h = bh % HEADS;
  const int tok0 = tile * TT3;
  const int t = threadIdx.x;
  const int lane = t & 63, wv = t >> 6;
  const int l15 = lane & 15, l4 = lane >> 4;

  __shared__ ushort wH[64][72], wL[64][72];
  __shared__ ushort rH[64][72], rL[64][72];
  __shared__ ushort xH[64][72], xL[64][72];
  __shared__ ushort pH[64][72], pL[64][72];

  // ---- stage w tile from planes ----
#pragma unroll
  for (int i = 0; i < 4; ++i) {
    const int idx = t + i * 256;
    const int row = idx >> 4;
    const int d0 = (idx & 15) * 4;
    const int tok = tok0 + row;
    ushort h4[4], l4v[4];
#pragma unroll
    for (int j = 0; j < 4; ++j) {
      const int d = d0 + j;
      const bool inb = (tok < NTOK) && (d < DHEAD);
      if (inb) {
        const size_t g = ((size_t)b * NTOK + tok) * INNERC + h * DHEAD + d;
        h4[j] = wHi[g]; l4v[j] = wLo[g];
      } else { h4[j] = 0; l4v[j] = 0; }
    }
    *(ushort4*)&wH[row][d0] = make_ushort4(h4[0], h4[1], h4[2], h4[3]);
    *(ushort4*)&wL[row][d0] = make_ushort4(l4v[0], l4v[1], l4v[2], l4v[3]);
  }

  f32x4 accO[4];
#pragma unroll
  for (int di = 0; di < 4; ++di) accO[di] = (f32x4){0.f, 0.f, 0.f, 0.f};

  for (int qc = 0; qc < 2; ++qc) {
    const int q0 = qc * 64;
    __syncthreads();
    // ---- stage rep chunk (*SCALE) ----
#pragma unroll
    for (int i = 0; i < 4; ++i) {
      const int idx = t + i * 256;
      const int row = idx >> 4;
      const int d0 = (idx & 15) * 4;
      const int q = q0 + row;
      float4 v = make_float4(0.f, 0.f, 0.f, 0.f);
      if (q < NQ && d0 < DHEAD) {
        const float* rp = &rep[((size_t)bh * NQ + q) * DHEAD];
        if (d0 + 3 < DHEAD) v = *(const float4*)&rp[d0];
        else { v.x = rp[d0]; if (d0 + 1 < DHEAD) v.y = rp[d0 + 1]; }
        v.x *= SCALE; v.y *= SCALE; v.z *= SCALE; v.w *= SCALE;
      }
      ushort h0 = f2bf(v.x), h1 = f2bf(v.y), h2 = f2bf(v.z), h3 = f2bf(v.w);
      *(ushort4*)&rH[row][d0] = make_ushort4(h0, h1, h2, h3);
      *(ushort4*)&rL[row][d0] = make_ushort4(f2bf(v.x - bf2f(h0)), f2bf(v.y - bf2f(h1)),
                                             f2bf(v.z - bf2f(h2)), f2bf(v.w - bf2f(h3)));
    }
    // ---- stage xq^T chunk ----
#pragma unroll
    for (int i = 0; i < 4; ++i) {
      const int idx = t + i * 256;
      const int drow = idx >> 4;
      const int ql0 = (idx & 15) * 4;
      float vv[4] = {0.f, 0.f, 0.f, 0.f};
      if (drow < DHEAD) {
#pragma unroll
        for (int j = 0; j < 4; ++j) {
          const int q = q0 + ql0 + j;
          if (q < NQ) vv[j] = xq[((size_t)bh * NQ + q) * DHEAD + drow];
        }
      }
      ushort h0 = f2bf(vv[0]), h1 = f2bf(vv[1]), h2 = f2bf(vv[2]), h3 = f2bf(vv[3]);
      *(ushort4*)&xH[drow][ql0] = make_ushort4(h0, h1, h2, h3);
      *(ushort4*)&xL[drow][ql0] = make_ushort4(f2bf(vv[0] - bf2f(h0)), f2bf(vv[1] - bf2f(h1)),
                                               f2bf(vv[2] - bf2f(h2)), f2bf(vv[3] - bf2f(h3)));
    }
    __syncthreads();

    // ---- S' = w . rep^T ----
    f32x4 accS[4];
#pragma unroll
    for (int ni = 0; ni < 4; ++ni) accS[ni] = (f32x4){0.f, 0.f, 0.f, 0.f};
#pragma unroll
    for (int ks = 0; ks < 2; ++ks) {
      const short8 ah = *(const short8*)&wH[wv * 16 + l15][ks * 32 + 8 * l4];
      const short8 al = *(const short8*)&wL[wv * 16 + l15][ks * 32 + 8 * l4];
#pragma unroll
      for (int ni = 0; ni < 4; ++ni) {
        const short8 bhf = *(const short8*)&rH[ni * 16 + l15][ks * 32 + 8 * l4];
        const short8 blf = *(const short8*)&rL[ni * 16 + l15][ks * 32 + 8 * l4];
        accS[ni] = __builtin_amdgcn_mfma_f32_16x16x32_bf16(ah, bhf, accS[ni], 0, 0, 0);
        accS[ni] = __builtin_amdgcn_mfma_f32_16x16x32_bf16(al, bhf, accS[ni], 0, 0, 0);
        accS[ni] = __builtin_amdgcn_mfma_f32_16x16x32_bf16(ah, blf, accS[ni], 0, 0, 0);
      }
    }

    // ---- p = exp(S'-m[q])*linv[q]; write P (own wave rows) ----
#pragma unroll
    for (int ni = 0; ni < 4; ++ni) {
      const int q = q0 + ni * 16 + l15;
      const bool valid = (q < NQ);
      float mq = 0.f, li = 0.f;
      if (valid) {
        mq = m_fin[(size_t)bh * NQ + q];
        li = 1.f / l_fin[(size_t)bh * NQ + q];
      }
#pragma unroll
      for (int r = 0; r < 4; ++r) {
        const float p = valid ? __expf(accS[ni][r] - mq) * li : 0.f;
        const int row = wv * 16 + 4 * l4 + r;
        const ushort ph = f2bf(p);
        pH[row][ni * 16 + l15] = ph;
        pL[row][ni * 16 + l15] = f2bf(p - bf2f(ph));
      }
    }

    // ---- O += P . xqT^T ----
#pragma unroll
    for (int ks2 = 0; ks2 < 2; ++ks2) {
      const short8 pah = *(const short8*)&pH[wv * 16 + l15][ks2 * 32 + 8 * l4];
      const short8 pal = *(const short8*)&pL[wv * 16 + l15][ks2 * 32 + 8 * l4];
#pragma unroll
      for (int di = 0; di < 4; ++di) {
        const short8 vh = *(const short8*)&xH[di * 16 + l15][ks2 * 32 + 8 * l4];
        const short8 vl = *(const short8*)&xL[di * 16 + l15][ks2 * 32 + 8 * l4];
        accO[di] = __builtin_amdgcn_mfma_f32_16x16x32_bf16(pah, vh, accO[di], 0, 0, 0);
        accO[di] = __builtin_amdgcn_mfma_f32_16x16x32_bf16(pal, vh, accO[di], 0, 0, 0);
        accO[di] = __builtin_amdgcn_mfma_f32_16x16x32_bf16(pah, vl, accO[di], 0, 0, 0);
      }
    }
  }

  // ---- epilogue: write xd planes (stride XDK) ----
#pragma unroll
  for (int di = 0; di < 4; ++di) {
    const int d = di * 16 + l15;
    if (d >= DHEAD) continue;
#pragma unroll
    for (int r = 0; r < 4; ++r) {
      const int tok = tok0 + wv * 16 + 4 * l4 + r;
      if (tok < NTOK) {
        const float val = accO[di][r];
        const ushort hh = f2bf(val);
        const size_t g = ((size_t)b * NTOK + tok) * XDK + h * DHEAD + d;
        xdHi[g] = hh;
        xdLo[g] = f2bf(val - bf2f(hh));
      }
    }
  }
}

// ---------------------------------------------------------------------------
extern "C" void kernel_launch(void* const* d_in, const int* in_sizes, int n_in,
                              void* d_out, int out_size, void* d_ws, size_t ws_size,
                              hipStream_t stream) {
  const float* x        = (const float*)d_in[0];
  const float* proj_w   = (const float*)d_in[1];
  const float* step_x   = (const float*)d_in[2];
  const float* step_rep = (const float*)d_in[3];
  const float* out_w    = (const float*)d_in[4];
  const float* out_b    = (const float*)d_in[5];
  float* out = (float*)d_out;

  uint8_t* p8 = (uint8_t*)d_ws;
  ushort* wHi    = (ushort*)(p8);                  //  48,720,000 B
  ushort* wLo    = (ushort*)(p8 + 48720000);       //  48,720,000
  float*  rep    = (float*) (p8 + 97440000);       //     960,000
  float*  reph2  = (float*) (p8 + 98400000);       //     960,000
  float*  xq     = (float*) (p8 + 99360000);       //     960,000
  float*  m_part = (float*) (p8 + 100320000);      //     307,200
  float*  l_part = (float*) (p8 + 100627200);      //     307,200
  float*  m_fin  = (float*) (p8 + 100934400);      //      19,200
  float*  l_fin  = (float*) (p8 + 100953600);      //      19,200
  ushort* xdHi   = (ushort*)(p8 + 100972800);      //  51,968,000
  ushort* xdLo   = (ushort*)(p8 + 152940800);      //  51,968,000
  ushort* pwHi   = (ushort*)(p8 + 204908800);      //     491,520
  ushort* pwLo   = (ushort*)(p8 + 205400320);      //     491,520
  ushort* owHi   = (ushort*)(p8 + 205891840);      //     491,520
  ushort* owLo   = (ushort*)(p8 + 206383360);      //     491,520
  // end 206,874,880 B (~207 MB). delta aliases xdHi (15.36 MB < 51.97 MB):
  float* delta = (float*)xdHi;   // consumed by combine BEFORE pad-zero + bcast3

  // 0. pre-split weights
  split_pad<<<960, 256, 0, stream>>>(proj_w, pwHi, pwLo, INNERC, DIMC, 320, DIMC);
  split_pad<<<960, 256, 0, stream>>>(out_w, owHi, owLo, DIMC, INNERC, DIMC, XDK);
  // 1. w planes = x @ proj_w^T (single N pass)
  gemm1_xw<<<1269, 256, 0, stream>>>(x, pwHi, pwLo, wHi, wLo);
  // 2. pooling -> rep
  pool_kernel<<<dim3(NQ, BATCH), 320, 0, stream>>>(wHi, wLo, rep);
  // 3. stage-1 attention + combine (delta aliases xdHi!)
  attn1_mfma<<<dim3(NBH, NSPLIT), 256, 0, stream>>>(wHi, wLo, rep, m_part, l_part, delta);
  attn1_combine<<<NBH, 256, 0, stream>>>(rep, m_part, l_part, delta, step_rep,
                                         reph2, m_fin, l_fin);
  // 3b. NOW zero the xd pad columns (delta fully consumed; bcast3 only writes
  //     cols 0..299, so pads must be cleaned after the delta alias is dead).
  zero_xd_pad<<<2048, 256, 0, stream>>>(xdHi, xdLo);
  // 4. stage-2 self-attention -> xq
  attn2_kernel<<<NBH, 256, 0, stream>>>(reph2, step_x, xq);
  // 5. broadcast back -> xd planes
  bcast3_kernel<<<dim3(159, NBH), 256, 0, stream>>>(wHi, wLo, rep, xq, m_fin, l_fin,
                                                    xdHi, xdLo);
  // 6. out = xd @ out_w^T + bias (XCD-swizzled)
  gemm2_out<<<3807, 256, 0, stream>>>(xdHi, xdLo, owHi, owLo, out_b, out);
}

// Round 9
// 855.555 us; speedup vs baseline: 3.0545x; 1.1306x over previous
//
#include <hip/hip_runtime.h>
#include <math.h>

#define BATCH   8
#define NTOK    10150
#define DIMC    768
#define INNERC  300
#define HEADS   6
#define DHEAD   50
#define NQ      100
#define NBH     48          // BATCH*HEADS
#define NSPLIT  32
#define CHUNK   320         // 32*320 = 10240 >= 10150
#define SCALE   0.14142135623730951f   // 50^-0.5
#define MTOT    (BATCH*NTOK)           // 81200
#define XDK     320                    // padded K stride for xd planes
#define NEGBIG  -1.0e30f

typedef __attribute__((ext_vector_type(8))) short short8;
typedef __attribute__((ext_vector_type(4))) float f32x4;

__device__ __forceinline__ ushort f2bf(float x) {
  uint u = __float_as_uint(x);
  uint r = (u + 0x7fffu + ((u >> 16) & 1u)) >> 16;
  return (ushort)r;
}
__device__ __forceinline__ float bf2f(ushort h) {
  return __uint_as_float(((uint)h) << 16);
}

// ---------------------------------------------------------------------------
// Pre-split fp32 -> padded hi/lo bf16 planes.  dst is [Rp][Cp]; src [R][C].
// ---------------------------------------------------------------------------
__global__ void split_pad(const float* __restrict__ src, ushort* __restrict__ dHi,
                          ushort* __restrict__ dLo, int R, int C, int Rp, int Cp) {
  const int total = Rp * Cp;
  for (int i = blockIdx.x * blockDim.x + threadIdx.x; i < total;
       i += gridDim.x * blockDim.x) {
    const int r = i / Cp, c = i % Cp;
    const float v = (r < R && c < C) ? src[r * C + c] : 0.f;
    const ushort hh = f2bf(v);
    dHi[i] = hh;
    dLo[i] = f2bf(v - bf2f(hh));
  }
}

// Zero the k-pad columns (300..319) of the xd planes.
// MUST run AFTER attn1_combine (delta aliases xdHi) and BEFORE bcast3/gemm2.
__global__ void zero_xd_pad(ushort* __restrict__ xdHi, ushort* __restrict__ xdLo) {
  const int total = MTOT * 20;
  for (int i = blockIdx.x * blockDim.x + threadIdx.x; i < total;
       i += gridDim.x * blockDim.x) {
    const size_t g = (size_t)(i / 20) * XDK + 300 + (i % 20);
    xdHi[g] = 0;
    xdLo[g] = 0;
  }
}

// ---------------------------------------------------------------------------
// GEMM 1: w(planes) = x @ proj_w^T.   BM=64, BN=320 (single N pass), BK=32.
// ---------------------------------------------------------------------------
__global__ __launch_bounds__(256, 2) void gemm1_xw(
    const float* __restrict__ x, const ushort* __restrict__ pwHi,
    const ushort* __restrict__ pwLo, ushort* __restrict__ wHi,
    ushort* __restrict__ wLo) {
  __shared__ ushort aH[64][40], aL[64][40];
  __shared__ ushort bH[320][40], bL[320][40];
  const int t = threadIdx.x;
  const int lane = t & 63, wv = t >> 6;
  const int l15 = lane & 15, l4 = lane >> 4;
  const int m0 = blockIdx.x * 64;
  const int arow = t >> 2, aslot = t & 3;

  f32x4 acc[4][5];
#pragma unroll
  for (int i = 0; i < 4; ++i)
#pragma unroll
    for (int j = 0; j < 5; ++j) acc[i][j] = (f32x4){0.f, 0.f, 0.f, 0.f};

  for (int k0 = 0; k0 < DIMC; k0 += 32) {
    __syncthreads();
    {
      float v[8];
      const int m = m0 + arow;
      if (m < MTOT) {
        const float* xp = &x[(size_t)m * DIMC + k0 + aslot * 8];
        const float4 u0 = *(const float4*)xp;
        const float4 u1 = *(const float4*)(xp + 4);
        v[0] = u0.x; v[1] = u0.y; v[2] = u0.z; v[3] = u0.w;
        v[4] = u1.x; v[5] = u1.y; v[6] = u1.z; v[7] = u1.w;
      } else {
#pragma unroll
        for (int j = 0; j < 8; ++j) v[j] = 0.f;
      }
      short8 th, tl;
#pragma unroll
      for (int j = 0; j < 8; ++j) {
        const ushort hh = f2bf(v[j]);
        th[j] = (short)hh;
        tl[j] = (short)f2bf(v[j] - bf2f(hh));
      }
      *(short8*)&aH[arow][aslot * 8] = th;
      *(short8*)&aL[arow][aslot * 8] = tl;
    }
#pragma unroll
    for (int i = 0; i < 5; ++i) {
      const int sid = t + i * 256;
      const int row = sid >> 2, slot = sid & 3;
      const size_t g = (size_t)row * DIMC + k0 + slot * 8;
      *(short8*)&bH[row][slot * 8] = *(const short8*)&pwHi[g];
      *(short8*)&bL[row][slot * 8] = *(const short8*)&pwLo[g];
    }
    __syncthreads();

    short8 ah[4], al[4];
#pragma unroll
    for (int i = 0; i < 4; ++i) {
      ah[i] = *(const short8*)&aH[i * 16 + l15][l4 * 8];
      al[i] = *(const short8*)&aL[i * 16 + l15][l4 * 8];
    }
#pragma unroll
    for (int j = 0; j < 5; ++j) {
      const int brow = wv * 80 + j * 16 + l15;
      const short8 bhf = *(const short8*)&bH[brow][l4 * 8];
      const short8 blf = *(const short8*)&bL[brow][l4 * 8];
#pragma unroll
      for (int i = 0; i < 4; ++i) {
        acc[i][j] = __builtin_amdgcn_mfma_f32_16x16x32_bf16(ah[i], bhf, acc[i][j], 0, 0, 0);
        acc[i][j] = __builtin_amdgcn_mfma_f32_16x16x32_bf16(al[i], bhf, acc[i][j], 0, 0, 0);
        acc[i][j] = __builtin_amdgcn_mfma_f32_16x16x32_bf16(ah[i], blf, acc[i][j], 0, 0, 0);
      }
    }
  }

#pragma unroll
  for (int j = 0; j < 5; ++j) {
    const int col = wv * 80 + j * 16 + l15;
    if (col >= INNERC) continue;
#pragma unroll
    for (int i = 0; i < 4; ++i)
#pragma unroll
      for (int r = 0; r < 4; ++r) {
        const int m = m0 + i * 16 + l4 * 4 + r;
        if (m < MTOT) {
          const float val = acc[i][j][r];
          const ushort hh = f2bf(val);
          const size_t g = (size_t)m * INNERC + col;
          wHi[g] = hh;
          wLo[g] = f2bf(val - bf2f(hh));
        }
      }
  }
}

// ---------------------------------------------------------------------------
// GEMM 2: out = xd(planes) @ out_w(planes)^T + bias.
// BM=64, BN=256, BK=32, K=320 (padded).  grid 1269*3, XCD-bijective swizzle.
// ---------------------------------------------------------------------------
__global__ __launch_bounds__(256, 2) void gemm2_out(
    const ushort* __restrict__ xdHi, const ushort* __restrict__ xdLo,
    const ushort* __restrict__ owHi, const ushort* __restrict__ owLo,
    const float* __restrict__ out_b, float* __restrict__ out) {
  __shared__ ushort aH[64][40], aL[64][40];
  __shared__ ushort bH[256][40], bL[256][40];
  const int t = threadIdx.x;
  const int lane = t & 63, wv = t >> 6;
  const int l15 = lane & 15, l4 = lane >> 4;
  const int nwg = gridDim.x;
  const int q = nwg >> 3, r = nwg & 7;
  const int xcd = blockIdx.x & 7, idx = blockIdx.x >> 3;
  const int wg = (xcd < r ? xcd * (q + 1) : r * (q + 1) + (xcd - r) * q) + idx;
  const int bn = wg % 3, bm = wg / 3;
  const int m0 = bm * 64, n0 = bn * 256;
  const int arow = t >> 2, aslot = t & 3;

  f32x4 acc[4][4];
#pragma unroll
  for (int i = 0; i < 4; ++i)
#pragma unroll
    for (int j = 0; j < 4; ++j) acc[i][j] = (f32x4){0.f, 0.f, 0.f, 0.f};

  for (int k0 = 0; k0 < XDK; k0 += 32) {
    __syncthreads();
    {
      const int m = m0 + arow;
      if (m < MTOT) {
        const size_t g = (size_t)m * XDK + k0 + aslot * 8;
        *(short8*)&aH[arow][aslot * 8] = *(const short8*)&xdHi[g];
        *(short8*)&aL[arow][aslot * 8] = *(const short8*)&xdLo[g];
      } else {
        const short8 z = {0, 0, 0, 0, 0, 0, 0, 0};
        *(short8*)&aH[arow][aslot * 8] = z;
        *(short8*)&aL[arow][aslot * 8] = z;
      }
    }
#pragma unroll
    for (int i = 0; i < 4; ++i) {
      const int sid = t + i * 256;
      const int row = sid >> 2, slot = sid & 3;
      const size_t g = (size_t)(n0 + row) * XDK + k0 + slot * 8;
      *(short8*)&bH[row][slot * 8] = *(const short8*)&owHi[g];
      *(short8*)&bL[row][slot * 8] = *(const short8*)&owLo[g];
    }
    __syncthreads();

    short8 ah[4], al[4];
#pragma unroll
    for (int i = 0; i < 4; ++i) {
      ah[i] = *(const short8*)&aH[i * 16 + l15][l4 * 8];
      al[i] = *(const short8*)&aL[i * 16 + l15][l4 * 8];
    }
#pragma unroll
    for (int j = 0; j < 4; ++j) {
      const int brow = wv * 64 + j * 16 + l15;
      const short8 bhf = *(const short8*)&bH[brow][l4 * 8];
      const short8 blf = *(const short8*)&bL[brow][l4 * 8];
#pragma unroll
      for (int i = 0; i < 4; ++i) {
        acc[i][j] = __builtin_amdgcn_mfma_f32_16x16x32_bf16(ah[i], bhf, acc[i][j], 0, 0, 0);
        acc[i][j] = __builtin_amdgcn_mfma_f32_16x16x32_bf16(al[i], bhf, acc[i][j], 0, 0, 0);
        acc[i][j] = __builtin_amdgcn_mfma_f32_16x16x32_bf16(ah[i], blf, acc[i][j], 0, 0, 0);
      }
    }
  }

#pragma unroll
  for (int j = 0; j < 4; ++j) {
    const int col = n0 + wv * 64 + j * 16 + l15;
    const float bv = out_b[col];
#pragma unroll
    for (int i = 0; i < 4; ++i)
#pragma unroll
      for (int r = 0; r < 4; ++r) {
        const int m = m0 + i * 16 + l4 * 4 + r;
        if (m < MTOT) out[(size_t)m * DIMC + col] = acc[i][j][r] + bv;
      }
  }
}

// ---------------------------------------------------------------------------
// Adaptive avg-pool (reads w planes) -> rep[b][h][q][d]
// ---------------------------------------------------------------------------
__global__ void pool_kernel(const ushort* __restrict__ wHi,
                            const ushort* __restrict__ wLo,
                            float* __restrict__ rep) {
  int q = blockIdx.x, b = blockIdx.y;
  int i = threadIdx.x;
  if (i >= INNERC) return;
  int pr = q / 10, pc = q % 10;
  float s = 0.f;
  for (int kr = 0; kr < 10; ++kr)
    for (int kc = 0; kc < 10; ++kc) {
      int tok = (pr * 10 + kr) * 100 + (pc * 10 + kc);
      const size_t g = ((size_t)b * NTOK + tok) * INNERC + i;
      s += bf2f(wHi[g]) + bf2f(wLo[g]);
    }
  s *= 0.01f;
  int h = i / DHEAD, d = i % DHEAD;
  rep[(((size_t)b * HEADS + h) * NQ + q) * DHEAD + d] = s;
}

// ---------------------------------------------------------------------------
// Stage-1 attention, MFMA split-flash.  NSPLIT=32 (grid 1536 = 6 blk/CU),
// ushort2 4B-aligned staging (halved load count vs scalar).
// ---------------------------------------------------------------------------
__global__ __launch_bounds__(256, 3) void attn1_mfma(
    const ushort* __restrict__ wHi, const ushort* __restrict__ wLo,
    const float* __restrict__ rep,
    float* __restrict__ m_part, float* __restrict__ l_part,
    float* __restrict__ delta_part) {
  const int bh = blockIdx.x, s = blockIdx.y;
  const int b = bh / HEADS, h = bh % HEADS;
  const int t = threadIdx.x;
  const int lane = t & 63, wv = t >> 6;
  const int l15 = lane & 15, l4 = lane >> 4;

  __shared__ ushort Khi[32][72], Klo[32][72];
  __shared__ ushort VThi[64][40], VTlo[64][40];
  __shared__ ushort Phi[128][40], Plo[128][40];

  short8 qhi[2][2], qlo[2][2];
#pragma unroll
  for (int mi = 0; mi < 2; ++mi) {
#pragma unroll
    for (int ks = 0; ks < 2; ++ks) {
      const int qr = 32 * wv + 16 * mi + l15;
      short8 th, tl;
#pragma unroll
      for (int j = 0; j < 8; ++j) {
        const int k = 32 * ks + 8 * l4 + j;
        float v = (qr < NQ && k < DHEAD)
                      ? rep[((size_t)bh * NQ + qr) * DHEAD + k] * SCALE : 0.f;
        ushort hh = f2bf(v);
        th[j] = (short)hh;
        tl[j] = (short)f2bf(v - bf2f(hh));
      }
      qhi[mi][ks] = th; qlo[mi][ks] = tl;
    }
  }

  f32x4 accO[2][4];
  float m_run[2][4], l_run[2][4];
#pragma unroll
  for (int mi = 0; mi < 2; ++mi) {
#pragma unroll
    for (int r = 0; r < 4; ++r) { m_run[mi][r] = NEGBIG; l_run[mi][r] = 0.f; }
#pragma unroll
    for (int di = 0; di < 4; ++di) accO[mi][di] = (f32x4){0.f, 0.f, 0.f, 0.f};
  }

  const int n0 = s * CHUNK;
  const int n1 = min(NTOK, n0 + CHUNK);

  for (int nt = n0; nt < n1; nt += 32) {
    __syncthreads();
    // ---- stage K + slot-rotated V^T, ushort2 loads (4B-aligned all heads) ----
#pragma unroll
    for (int i = 0; i < 4; ++i) {
      const int idx = t + i * 256;       // 0..1023 = 32 tok x 32 pairs
      const int tr = idx >> 5;           // token row
      const int d = (idx & 31) * 2;      // even d
      const bool inb = (nt + tr < n1) && (d < DHEAD);
      uint hv = 0, lv = 0;
      if (inb) {
        const size_t g = ((size_t)b * NTOK + nt + tr) * INNERC + h * DHEAD + d;
        hv = *(const uint*)&wHi[g];
        lv = *(const uint*)&wLo[g];
      }
      *(uint*)&Khi[tr][d] = hv;
      *(uint*)&Klo[tr][d] = lv;
      const int ps = ((((tr >> 3) + (d >> 3)) & 3) << 3) + (tr & 7);
      VThi[d][ps] = (ushort)(hv & 0xffffu);
      VTlo[d][ps] = (ushort)(lv & 0xffffu);
      VThi[d + 1][ps] = (ushort)(hv >> 16);   // (d+1)>>3 == d>>3 since d even
      VTlo[d + 1][ps] = (ushort)(lv >> 16);
    }
    __syncthreads();

    f32x4 accS[2][2];
#pragma unroll
    for (int mi = 0; mi < 2; ++mi)
#pragma unroll
      for (int ni = 0; ni < 2; ++ni) accS[mi][ni] = (f32x4){0.f, 0.f, 0.f, 0.f};
#pragma unroll
    for (int ks = 0; ks < 2; ++ks) {
      short8 kh[2], kl[2];
#pragma unroll
      for (int ni = 0; ni < 2; ++ni) {
        kh[ni] = *(const short8*)&Khi[16 * ni + l15][32 * ks + 8 * l4];
        kl[ni] = *(const short8*)&Klo[16 * ni + l15][32 * ks + 8 * l4];
      }
#pragma unroll
      for (int mi = 0; mi < 2; ++mi)
#pragma unroll
        for (int ni = 0; ni < 2; ++ni) {
          accS[mi][ni] = __builtin_amdgcn_mfma_f32_16x16x32_bf16(qhi[mi][ks], kh[ni], accS[mi][ni], 0, 0, 0);
          accS[mi][ni] = __builtin_amdgcn_mfma_f32_16x16x32_bf16(qlo[mi][ks], kh[ni], accS[mi][ni], 0, 0, 0);
          accS[mi][ni] = __builtin_amdgcn_mfma_f32_16x16x32_bf16(qhi[mi][ks], kl[ni], accS[mi][ni], 0, 0, 0);
        }
    }

    bool cval[2];
#pragma unroll
    for (int ni = 0; ni < 2; ++ni) cval[ni] = (nt + 16 * ni + l15) < n1;
#pragma unroll
    for (int mi = 0; mi < 2; ++mi) {
#pragma unroll
      for (int ni = 0; ni < 2; ++ni)
        if (!cval[ni]) {
#pragma unroll
          for (int r = 0; r < 4; ++r) accS[mi][ni][r] = NEGBIG;
        }
#pragma unroll
      for (int r = 0; r < 4; ++r) {
        float mx = fmaxf(accS[mi][0][r], accS[mi][1][r]);
        mx = fmaxf(mx, __shfl_xor(mx, 1));
        mx = fmaxf(mx, __shfl_xor(mx, 2));
        mx = fmaxf(mx, __shfl_xor(mx, 4));
        mx = fmaxf(mx, __shfl_xor(mx, 8));
        const float m_new = fmaxf(m_run[mi][r], mx);
        const float sc = __expf(m_run[mi][r] - m_new);
        m_run[mi][r] = m_new;
        l_run[mi][r] *= sc;
#pragma unroll
        for (int di = 0; di < 4; ++di) accO[mi][di][r] *= sc;
        float ps = 0.f;
#pragma unroll
        for (int ni = 0; ni < 2; ++ni) {
          const float p = __expf(accS[mi][ni][r] - m_new);
          accS[mi][ni][r] = p;
          ps += p;
        }
        ps += __shfl_xor(ps, 1);
        ps += __shfl_xor(ps, 2);
        ps += __shfl_xor(ps, 4);
        ps += __shfl_xor(ps, 8);
        l_run[mi][r] += ps;
      }
#pragma unroll
      for (int ni = 0; ni < 2; ++ni)
#pragma unroll
        for (int r = 0; r < 4; ++r) {
          const int row = 32 * wv + 16 * mi + 4 * l4 + r;
          const int col = 16 * ni + l15;
          const float p = accS[mi][ni][r];
          const ushort ph = f2bf(p);
          Phi[row][col] = ph;
          Plo[row][col] = f2bf(p - bf2f(ph));
        }
    }

#pragma unroll
    for (int mi = 0; mi < 2; ++mi) {
      const short8 pah = *(const short8*)&Phi[32 * wv + 16 * mi + l15][8 * l4];
      const short8 pal = *(const short8*)&Plo[32 * wv + 16 * mi + l15][8 * l4];
#pragma unroll
      for (int di = 0; di < 4; ++di) {
        const int vs = (((l4 + 2 * di + (l15 >> 3)) & 3)) << 3;
        const short8 vbh = *(const short8*)&VThi[16 * di + l15][vs];
        const short8 vbl = *(const short8*)&VTlo[16 * di + l15][vs];
        accO[mi][di] = __builtin_amdgcn_mfma_f32_16x16x32_bf16(pah, vbh, accO[mi][di], 0, 0, 0);
        accO[mi][di] = __builtin_amdgcn_mfma_f32_16x16x32_bf16(pal, vbh, accO[mi][di], 0, 0, 0);
        accO[mi][di] = __builtin_amdgcn_mfma_f32_16x16x32_bf16(pah, vbl, accO[mi][di], 0, 0, 0);
      }
    }
  }

  const size_t base = ((size_t)bh * NSPLIT + s) * NQ;
#pragma unroll
  for (int mi = 0; mi < 2; ++mi)
#pragma unroll
    for (int r = 0; r < 4; ++r) {
      const int q = 32 * wv + 16 * mi + 4 * l4 + r;
      if (q < NQ && l15 == 0) {
        m_part[base + q] = m_run[mi][r];
        l_part[base + q] = l_run[mi][r];
      }
#pragma unroll
      for (int di = 0; di < 4; ++di) {
        const int d = 16 * di + l15;
        if (q < NQ && d < DHEAD)
          delta_part[(base + q) * DHEAD + d] = accO[mi][di][r];
      }
    }
}

// ---------------------------------------------------------------------------
// Combine split partials -> reph2, final m,l per (bh,q)
// ---------------------------------------------------------------------------
__global__ __launch_bounds__(256) void attn1_combine(
    const float* __restrict__ rep, const float* __restrict__ m_part,
    const float* __restrict__ l_part, const float* __restrict__ delta_part,
    const float* __restrict__ step_rep,
    float* __restrict__ reph2, float* __restrict__ m_fin, float* __restrict__ l_fin) {
  int bh = blockIdx.x;
  int h = bh % HEADS;
  int t = threadIdx.x;
  __shared__ float Mf[NQ], Lf[NQ];
  if (t < NQ) {
    int q = t;
    float M = -INFINITY;
#pragma unroll
    for (int s2 = 0; s2 < NSPLIT; ++s2)
      M = fmaxf(M, m_part[((size_t)bh * NSPLIT + s2) * NQ + q]);
    float L = 0.f;
#pragma unroll
    for (int s2 = 0; s2 < NSPLIT; ++s2)
      L += l_part[((size_t)bh * NSPLIT + s2) * NQ + q] *
           __expf(m_part[((size_t)bh * NSPLIT + s2) * NQ + q] - M);
    Mf[q] = M; Lf[q] = L;
    m_fin[(size_t)bh * NQ + q] = M;
    l_fin[(size_t)bh * NQ + q] = L;
  }
  __syncthreads();
  float sr = step_rep[h];
  for (int idx = t; idx < NQ * DHEAD; idx += 256) {
    int q = idx / DHEAD, d = idx % DHEAD;
    float sum = 0.f;
#pragma unroll
    for (int s2 = 0; s2 < NSPLIT; ++s2) {
      size_t pb = ((size_t)bh * NSPLIT + s2) * NQ + q;
      sum += __expf(m_part[pb] - Mf[q]) * delta_part[pb * DHEAD + d];
    }
    float rd = sum / Lf[q];
    reph2[(size_t)bh * NQ * DHEAD + idx] =
        rep[(size_t)bh * NQ * DHEAD + idx] + sr * rd;
  }
}

// ---------------------------------------------------------------------------
// Stage-2 self attention -> xq = step_x[h] * (softmax(r2 r2^T s) r2)
// ---------------------------------------------------------------------------
__global__ __launch_bounds__(256) void attn2_kernel(
    const float* __restrict__ reph2, const float* __restrict__ step_x,
    float* __restrict__ xq) {
  int bh = blockIdx.x;
  int h = bh % HEADS;
  int t = threadIdx.x;
  __shared__ float r2[NQ * DHEAD];
  __shared__ float att[NQ * NQ];

  for (int idx = t; idx < NQ * DHEAD; idx += 256)
    r2[idx] = reph2[(size_t)bh * NQ * DHEAD + idx];
  __syncthreads();

  for (int idx = t; idx < NQ * NQ; idx += 256) {
    int qq = idx / NQ, jj = idx % NQ;
    float s = 0.f;
#pragma unroll
    for (int k = 0; k < DHEAD; ++k) s += r2[qq * DHEAD + k] * r2[jj * DHEAD + k];
    att[idx] = s * SCALE;
  }
  __syncthreads();
  if (t < NQ) {
    float M = -INFINITY;
    for (int j = 0; j < NQ; ++j) M = fmaxf(M, att[t * NQ + j]);
    float L = 0.f;
    for (int j = 0; j < NQ; ++j) { float e = __expf(att[t * NQ + j] - M); att[t * NQ + j] = e; L += e; }
    float inv = 1.f / L;
    for (int j = 0; j < NQ; ++j) att[t * NQ + j] *= inv;
  }
  __syncthreads();
  float sx = step_x[h];
  for (int idx = t; idx < NQ * DHEAD; idx += 256) {
    int qd_q = idx / DHEAD, d = idx % DHEAD;
    float v = 0.f;
#pragma unroll
    for (int j = 0; j < NQ; ++j) v += att[qd_q * NQ + j] * r2[j * DHEAD + d];
    xq[(size_t)bh * NQ * DHEAD + idx] = sx * v;
  }
}

// ---------------------------------------------------------------------------
// Pass 2 (MFMA): w planes in, xd planes out.
// ---------------------------------------------------------------------------
#define TT3 64
__global__ __launch_bounds__(256, 2) void bcast3_kernel(
    const ushort* __restrict__ wHi, const ushort* __restrict__ wLo,
    const float* __restrict__ rep, const float* __restrict__ xq,
    const float* __restrict__ m_fin, const float* __restrict__ l_fin,
    ushort* __restrict__ xdHi, ushort* __restrict__ xdLo) {
  const int tile = blockIdx.x, bh = blockIdx.y;
  const int b = bh / HEADS, h = bh % HEADS;
  const int tok0 = tile * TT3;
  const int t = threadIdx.x;
  const int lane = t & 63, wv = t >> 6;
  const int l15 = lane & 15, l4 = lane >> 4;

  __shared__ ushort wH[64][72], wL[64][72];
  __shared__ ushort rH[64][72], rL[64][72];
  __shared__ ushort xH[64][72], xL[64][72];
  __shared__ ushort pH[64][72], pL[64][72];

  // ---- stage w tile from planes (ushort2 loads, 4B-aligned all heads) ----
#pragma unroll
  for (int i = 0; i < 8; ++i) {
    const int idx = t + i * 256;        // 0..2047 = 64 tok x 32 pairs
    const int row = idx >> 5;
    const int d = (idx & 31) * 2;
    const int tok = tok0 + row;
    uint hv = 0, lv = 0;
    if (tok < NTOK && d < DHEAD) {
      const size_t g = ((size_t)b * NTOK + tok) * INNERC + h * DHEAD + d;
      hv = *(const uint*)&wHi[g];
      lv = *(const uint*)&wLo[g];
    }
    *(uint*)&wH[row][d] = hv;
    *(uint*)&wL[row][d] = lv;
  }

  f32x4 accO[4];
#pragma unroll
  for (int di = 0; di < 4; ++di) accO[di] = (f32x4){0.f, 0.f, 0.f, 0.f};

  for (int qc = 0; qc < 2; ++qc) {
    const int q0 = qc * 64;
    __syncthreads();
#pragma unroll
    for (int i = 0; i < 4; ++i) {
      const int idx = t + i * 256;
      const int row = idx >> 4;
      const int d0 = (idx & 15) * 4;
      const int q = q0 + row;
      float4 v = make_float4(0.f, 0.f, 0.f, 0.f);
      if (q < NQ && d0 < DHEAD) {
        const float* rp = &rep[((size_t)bh * NQ + q) * DHEAD];
        if (d0 + 3 < DHEAD) v = *(const float4*)&rp[d0];
        else { v.x = rp[d0]; if (d0 + 1 < DHEAD) v.y = rp[d0 + 1]; }
        v.x *= SCALE; v.y *= SCALE; v.z *= SCALE; v.w *= SCALE;
      }
      ushort h0 = f2bf(v.x), h1 = f2bf(v.y), h2 = f2bf(v.z), h3 = f2bf(v.w);
      *(ushort4*)&rH[row][d0] = make_ushort4(h0, h1, h2, h3);
      *(ushort4*)&rL[row][d0] = make_ushort4(f2bf(v.x - bf2f(h0)), f2bf(v.y - bf2f(h1)),
                                             f2bf(v.z - bf2f(h2)), f2bf(v.w - bf2f(h3)));
    }
#pragma unroll
    for (int i = 0; i < 4; ++i) {
      const int idx = t + i * 256;
      const int drow = idx >> 4;
      const int ql0 = (idx & 15) * 4;
      float vv[4] = {0.f, 0.f, 0.f, 0.f};
      if (drow < DHEAD) {
#pragma unroll
        for (int j = 0; j < 4; ++j) {
          const int q = q0 + ql0 + j;
          if (q < NQ) vv[j] = xq[((size_t)bh * NQ + q) * DHEAD + drow];
        }
      }
      ushort h0 = f2bf(vv[0]), h1 = f2bf(vv[1]), h2 = f2bf(vv[2]), h3 = f2bf(vv[3]);
      *(ushort4*)&xH[drow][ql0] = make_ushort4(h0, h1, h2, h3);
      *(ushort4*)&xL[drow][ql0] = make_ushort4(f2bf(vv[0] - bf2f(h0)), f2bf(vv[1] - bf2f(h1)),
                                               f2bf(vv[2] - bf2f(h2)), f2bf(vv[3] - bf2f(h3)));
    }
    __syncthreads();

    f32x4 accS[4];
#pragma unroll
    for (int ni = 0; ni < 4; ++ni) accS[ni] = (f32x4){0.f, 0.f, 0.f, 0.f};
#pragma unroll
    for (int ks = 0; ks < 2; ++ks) {
      const short8 ah = *(const short8*)&wH[wv * 16 + l15][ks * 32 + 8 * l4];
      const short8 al = *(const short8*)&wL[wv * 16 + l15][ks * 32 + 8 * l4];
#pragma unroll
      for (int ni = 0; ni < 4; ++ni) {
        const short8 bhf = *(const short8*)&rH[ni * 16 + l15][ks * 32 + 8 * l4];
        const short8 blf = *(const short8*)&rL[ni * 16 + l15][ks * 32 + 8 * l4];
        accS[ni] = __builtin_amdgcn_mfma_f32_16x16x32_bf16(ah, bhf, accS[ni], 0, 0, 0);
        accS[ni] = __builtin_amdgcn_mfma_f32_16x16x32_bf16(al, bhf, accS[ni], 0, 0, 0);
        accS[ni] = __builtin_amdgcn_mfma_f32_16x16x32_bf16(ah, blf, accS[ni], 0, 0, 0);
      }
    }

#pragma unroll
    for (int ni = 0; ni < 4; ++ni) {
      const int q = q0 + ni * 16 + l15;
      const bool valid = (q < NQ);
      float mq = 0.f, li = 0.f;
      if (valid) {
        mq = m_fin[(size_t)bh * NQ + q];
        li = 1.f / l_fin[(size_t)bh * NQ + q];
      }
#pragma unroll
      for (int r = 0; r < 4; ++r) {
        const float p = valid ? __expf(accS[ni][r] - mq) * li : 0.f;
        const int row = wv * 16 + 4 * l4 + r;
        const ushort ph = f2bf(p);
        pH[row][ni * 16 + l15] = ph;
        pL[row][ni * 16 + l15] = f2bf(p - bf2f(ph));
      }
    }

#pragma unroll
    for (int ks2 = 0; ks2 < 2; ++ks2) {
      const short8 pah = *(const short8*)&pH[wv * 16 + l15][ks2 * 32 + 8 * l4];
      const short8 pal = *(const short8*)&pL[wv * 16 + l15][ks2 * 32 + 8 * l4];
#pragma unroll
      for (int di = 0; di < 4; ++di) {
        const short8 vh = *(const short8*)&xH[di * 16 + l15][ks2 * 32 + 8 * l4];
        const short8 vl = *(const short8*)&xL[di * 16 + l15][ks2 * 32 + 8 * l4];
        accO[di] = __builtin_amdgcn_mfma_f32_16x16x32_bf16(pah, vh, accO[di], 0, 0, 0);
        accO[di] = __builtin_amdgcn_mfma_f32_16x16x32_bf16(pal, vh, accO[di], 0, 0, 0);
        accO[di] = __builtin_amdgcn_mfma_f32_16x16x32_bf16(pah, vl, accO[di], 0, 0, 0);
      }
    }
  }

#pragma unroll
  for (int di = 0; di < 4; ++di) {
    const int d = di * 16 + l15;
    if (d >= DHEAD) continue;
#pragma unroll
    for (int r = 0; r < 4; ++r) {
      const int tok = tok0 + wv * 16 + 4 * l4 + r;
      if (tok < NTOK) {
        const float val = accO[di][r];
        const ushort hh = f2bf(val);
        const size_t g = ((size_t)b * NTOK + tok) * XDK + h * DHEAD + d;
        xdHi[g] = hh;
        xdLo[g] = f2bf(val - bf2f(hh));
      }
    }
  }
}

// ---------------------------------------------------------------------------
extern "C" void kernel_launch(void* const* d_in, const int* in_sizes, int n_in,
                              void* d_out, int out_size, void* d_ws, size_t ws_size,
                              hipStream_t stream) {
  const float* x        = (const float*)d_in[0];
  const float* proj_w   = (const float*)d_in[1];
  const float* step_x   = (const float*)d_in[2];
  const float* step_rep = (const float*)d_in[3];
  const float* out_w    = (const float*)d_in[4];
  const float* out_b    = (const float*)d_in[5];
  float* out = (float*)d_out;

  uint8_t* p8 = (uint8_t*)d_ws;
  ushort* wHi    = (ushort*)(p8);                  //  48,720,000 B
  ushort* wLo    = (ushort*)(p8 + 48720000);       //  48,720,000
  float*  rep    = (float*) (p8 + 97440000);       //     960,000
  float*  reph2  = (float*) (p8 + 98400000);       //     960,000
  float*  xq     = (float*) (p8 + 99360000);       //     960,000
  float*  m_part = (float*) (p8 + 100320000);      //     614,400 (48*32*100)
  float*  l_part = (float*) (p8 + 100934400);      //     614,400
  float*  m_fin  = (float*) (p8 + 101548800);      //      19,200
  float*  l_fin  = (float*) (p8 + 101568000);      //      19,200
  ushort* xdHi   = (ushort*)(p8 + 101587200);      //  51,968,000
  ushort* xdLo   = (ushort*)(p8 + 153555200);      //  51,968,000
  ushort* pwHi   = (ushort*)(p8 + 205523200);      //     491,520
  ushort* pwLo   = (ushort*)(p8 + 206014720);      //     491,520
  ushort* owHi   = (ushort*)(p8 + 206506240);      //     491,520
  ushort* owLo   = (ushort*)(p8 + 206997760);      //     491,520
  // end 207,489,280 B (~207.5 MB). delta (30.72 MB) aliases xdHi (51.97 MB):
  float* delta = (float*)xdHi;   // consumed by combine BEFORE pad-zero + bcast3

  // 0. pre-split weights
  split_pad<<<960, 256, 0, stream>>>(proj_w, pwHi, pwLo, INNERC, DIMC, 320, DIMC);
  split_pad<<<960, 256, 0, stream>>>(out_w, owHi, owLo, DIMC, INNERC, DIMC, XDK);
  // 1. w planes = x @ proj_w^T (single N pass)
  gemm1_xw<<<1269, 256, 0, stream>>>(x, pwHi, pwLo, wHi, wLo);
  // 2. pooling -> rep
  pool_kernel<<<dim3(NQ, BATCH), 320, 0, stream>>>(wHi, wLo, rep);
  // 3. stage-1 attention + combine (delta aliases xdHi!)
  attn1_mfma<<<dim3(NBH, NSPLIT), 256, 0, stream>>>(wHi, wLo, rep, m_part, l_part, delta);
  attn1_combine<<<NBH, 256, 0, stream>>>(rep, m_part, l_part, delta, step_rep,
                                         reph2, m_fin, l_fin);
  // 3b. zero xd pad columns AFTER delta is consumed, BEFORE bcast3/gemm2
  zero_xd_pad<<<2048, 256, 0, stream>>>(xdHi, xdLo);
  // 4. stage-2 self-attention -> xq
  attn2_kernel<<<NBH, 256, 0, stream>>>(reph2, step_x, xq);
  // 5. broadcast back -> xd planes
  bcast3_kernel<<<dim3(159, NBH), 256, 0, stream>>>(wHi, wLo, rep, xq, m_fin, l_fin,
                                                    xdHi, xdLo);
  // 6. out = xd @ out_w^T + bias (XCD-swizzled)
  gemm2_out<<<3807, 256, 0, stream>>>(xdHi, xdLo, owHi, owLo, out_b, out);
}

// Round 10
// 850.248 us; speedup vs baseline: 3.0736x; 1.0062x over previous
//
#include <hip/hip_runtime.h>
#include <math.h>

#define BATCH   8
#define NTOK    10150
#define DIMC    768
#define INNERC  300
#define HEADS   6
#define DHEAD   50
#define NQ      100
#define NBH     48          // BATCH*HEADS
#define NSPLIT  32
#define CHUNK   320         // 32*320 = 10240 >= 10150
#define SCALE   0.14142135623730951f   // 50^-0.5
#define MTOT    (BATCH*NTOK)           // 81200
#define XDK     320                    // padded K stride for xd planes
#define NEGBIG  -1.0e30f

typedef __attribute__((ext_vector_type(8))) short short8;
typedef __attribute__((ext_vector_type(4))) float f32x4;

__device__ __forceinline__ ushort f2bf(float x) {
  uint u = __float_as_uint(x);
  uint r = (u + 0x7fffu + ((u >> 16) & 1u)) >> 16;
  return (ushort)r;
}
__device__ __forceinline__ float bf2f(ushort h) {
  return __uint_as_float(((uint)h) << 16);
}

// ---------------------------------------------------------------------------
// Pre-split fp32 -> padded hi/lo bf16 planes.  dst is [Rp][Cp]; src [R][C].
// ---------------------------------------------------------------------------
__global__ void split_pad(const float* __restrict__ src, ushort* __restrict__ dHi,
                          ushort* __restrict__ dLo, int R, int C, int Rp, int Cp) {
  const int total = Rp * Cp;
  for (int i = blockIdx.x * blockDim.x + threadIdx.x; i < total;
       i += gridDim.x * blockDim.x) {
    const int r = i / Cp, c = i % Cp;
    const float v = (r < R && c < C) ? src[r * C + c] : 0.f;
    const ushort hh = f2bf(v);
    dHi[i] = hh;
    dLo[i] = f2bf(v - bf2f(hh));
  }
}

// Zero the k-pad columns (300..319) of the xd planes.
// MUST run AFTER attn1_combine (delta aliases xdHi) and BEFORE bcast/gemm2.
__global__ void zero_xd_pad(ushort* __restrict__ xdHi, ushort* __restrict__ xdLo) {
  const int total = MTOT * 20;
  for (int i = blockIdx.x * blockDim.x + threadIdx.x; i < total;
       i += gridDim.x * blockDim.x) {
    const size_t g = (size_t)(i / 20) * XDK + 300 + (i % 20);
    xdHi[g] = 0;
    xdLo[g] = 0;
  }
}

// ---------------------------------------------------------------------------
// GEMM 1: w(planes) = x @ proj_w^T.   BM=64, BN=320 (single N pass), BK=32.
// ---------------------------------------------------------------------------
__global__ __launch_bounds__(256, 2) void gemm1_xw(
    const float* __restrict__ x, const ushort* __restrict__ pwHi,
    const ushort* __restrict__ pwLo, ushort* __restrict__ wHi,
    ushort* __restrict__ wLo) {
  __shared__ ushort aH[64][40], aL[64][40];
  __shared__ ushort bH[320][40], bL[320][40];
  const int t = threadIdx.x;
  const int lane = t & 63, wv = t >> 6;
  const int l15 = lane & 15, l4 = lane >> 4;
  const int m0 = blockIdx.x * 64;
  const int arow = t >> 2, aslot = t & 3;

  f32x4 acc[4][5];
#pragma unroll
  for (int i = 0; i < 4; ++i)
#pragma unroll
    for (int j = 0; j < 5; ++j) acc[i][j] = (f32x4){0.f, 0.f, 0.f, 0.f};

  for (int k0 = 0; k0 < DIMC; k0 += 32) {
    __syncthreads();
    {
      float v[8];
      const int m = m0 + arow;
      if (m < MTOT) {
        const float* xp = &x[(size_t)m * DIMC + k0 + aslot * 8];
        const float4 u0 = *(const float4*)xp;
        const float4 u1 = *(const float4*)(xp + 4);
        v[0] = u0.x; v[1] = u0.y; v[2] = u0.z; v[3] = u0.w;
        v[4] = u1.x; v[5] = u1.y; v[6] = u1.z; v[7] = u1.w;
      } else {
#pragma unroll
        for (int j = 0; j < 8; ++j) v[j] = 0.f;
      }
      short8 th, tl;
#pragma unroll
      for (int j = 0; j < 8; ++j) {
        const ushort hh = f2bf(v[j]);
        th[j] = (short)hh;
        tl[j] = (short)f2bf(v[j] - bf2f(hh));
      }
      *(short8*)&aH[arow][aslot * 8] = th;
      *(short8*)&aL[arow][aslot * 8] = tl;
    }
#pragma unroll
    for (int i = 0; i < 5; ++i) {
      const int sid = t + i * 256;
      const int row = sid >> 2, slot = sid & 3;
      const size_t g = (size_t)row * DIMC + k0 + slot * 8;
      *(short8*)&bH[row][slot * 8] = *(const short8*)&pwHi[g];
      *(short8*)&bL[row][slot * 8] = *(const short8*)&pwLo[g];
    }
    __syncthreads();

    short8 ah[4], al[4];
#pragma unroll
    for (int i = 0; i < 4; ++i) {
      ah[i] = *(const short8*)&aH[i * 16 + l15][l4 * 8];
      al[i] = *(const short8*)&aL[i * 16 + l15][l4 * 8];
    }
#pragma unroll
    for (int j = 0; j < 5; ++j) {
      const int brow = wv * 80 + j * 16 + l15;
      const short8 bhf = *(const short8*)&bH[brow][l4 * 8];
      const short8 blf = *(const short8*)&bL[brow][l4 * 8];
#pragma unroll
      for (int i = 0; i < 4; ++i) {
        acc[i][j] = __builtin_amdgcn_mfma_f32_16x16x32_bf16(ah[i], bhf, acc[i][j], 0, 0, 0);
        acc[i][j] = __builtin_amdgcn_mfma_f32_16x16x32_bf16(al[i], bhf, acc[i][j], 0, 0, 0);
        acc[i][j] = __builtin_amdgcn_mfma_f32_16x16x32_bf16(ah[i], blf, acc[i][j], 0, 0, 0);
      }
    }
  }

#pragma unroll
  for (int j = 0; j < 5; ++j) {
    const int col = wv * 80 + j * 16 + l15;
    if (col >= INNERC) continue;
#pragma unroll
    for (int i = 0; i < 4; ++i)
#pragma unroll
      for (int r = 0; r < 4; ++r) {
        const int m = m0 + i * 16 + l4 * 4 + r;
        if (m < MTOT) {
          const float val = acc[i][j][r];
          const ushort hh = f2bf(val);
          const size_t g = (size_t)m * INNERC + col;
          wHi[g] = hh;
          wLo[g] = f2bf(val - bf2f(hh));
        }
      }
  }
}

// ---------------------------------------------------------------------------
// GEMM 2: out = xd(planes) @ out_w(planes)^T + bias.
// ---------------------------------------------------------------------------
__global__ __launch_bounds__(256, 2) void gemm2_out(
    const ushort* __restrict__ xdHi, const ushort* __restrict__ xdLo,
    const ushort* __restrict__ owHi, const ushort* __restrict__ owLo,
    const float* __restrict__ out_b, float* __restrict__ out) {
  __shared__ ushort aH[64][40], aL[64][40];
  __shared__ ushort bH[256][40], bL[256][40];
  const int t = threadIdx.x;
  const int lane = t & 63, wv = t >> 6;
  const int l15 = lane & 15, l4 = lane >> 4;
  const int nwg = gridDim.x;
  const int q = nwg >> 3, r = nwg & 7;
  const int xcd = blockIdx.x & 7, idx = blockIdx.x >> 3;
  const int wg = (xcd < r ? xcd * (q + 1) : r * (q + 1) + (xcd - r) * q) + idx;
  const int bn = wg % 3, bm = wg / 3;
  const int m0 = bm * 64, n0 = bn * 256;
  const int arow = t >> 2, aslot = t & 3;

  f32x4 acc[4][4];
#pragma unroll
  for (int i = 0; i < 4; ++i)
#pragma unroll
    for (int j = 0; j < 4; ++j) acc[i][j] = (f32x4){0.f, 0.f, 0.f, 0.f};

  for (int k0 = 0; k0 < XDK; k0 += 32) {
    __syncthreads();
    {
      const int m = m0 + arow;
      if (m < MTOT) {
        const size_t g = (size_t)m * XDK + k0 + aslot * 8;
        *(short8*)&aH[arow][aslot * 8] = *(const short8*)&xdHi[g];
        *(short8*)&aL[arow][aslot * 8] = *(const short8*)&xdLo[g];
      } else {
        const short8 z = {0, 0, 0, 0, 0, 0, 0, 0};
        *(short8*)&aH[arow][aslot * 8] = z;
        *(short8*)&aL[arow][aslot * 8] = z;
      }
    }
#pragma unroll
    for (int i = 0; i < 4; ++i) {
      const int sid = t + i * 256;
      const int row = sid >> 2, slot = sid & 3;
      const size_t g = (size_t)(n0 + row) * XDK + k0 + slot * 8;
      *(short8*)&bH[row][slot * 8] = *(const short8*)&owHi[g];
      *(short8*)&bL[row][slot * 8] = *(const short8*)&owLo[g];
    }
    __syncthreads();

    short8 ah[4], al[4];
#pragma unroll
    for (int i = 0; i < 4; ++i) {
      ah[i] = *(const short8*)&aH[i * 16 + l15][l4 * 8];
      al[i] = *(const short8*)&aL[i * 16 + l15][l4 * 8];
    }
#pragma unroll
    for (int j = 0; j < 4; ++j) {
      const int brow = wv * 64 + j * 16 + l15;
      const short8 bhf = *(const short8*)&bH[brow][l4 * 8];
      const short8 blf = *(const short8*)&bL[brow][l4 * 8];
#pragma unroll
      for (int i = 0; i < 4; ++i) {
        acc[i][j] = __builtin_amdgcn_mfma_f32_16x16x32_bf16(ah[i], bhf, acc[i][j], 0, 0, 0);
        acc[i][j] = __builtin_amdgcn_mfma_f32_16x16x32_bf16(al[i], bhf, acc[i][j], 0, 0, 0);
        acc[i][j] = __builtin_amdgcn_mfma_f32_16x16x32_bf16(ah[i], blf, acc[i][j], 0, 0, 0);
      }
    }
  }

#pragma unroll
  for (int j = 0; j < 4; ++j) {
    const int col = n0 + wv * 64 + j * 16 + l15;
    const float bv = out_b[col];
#pragma unroll
    for (int i = 0; i < 4; ++i)
#pragma unroll
      for (int r = 0; r < 4; ++r) {
        const int m = m0 + i * 16 + l4 * 4 + r;
        if (m < MTOT) out[(size_t)m * DIMC + col] = acc[i][j][r] + bv;
      }
  }
}

// ---------------------------------------------------------------------------
// Adaptive avg-pool -> rep fp32 AND padded rep*SCALE hi/lo planes [bh][128][64]
// ---------------------------------------------------------------------------
__global__ void pool_kernel(const ushort* __restrict__ wHi,
                            const ushort* __restrict__ wLo,
                            float* __restrict__ rep,
                            ushort* __restrict__ repPH, ushort* __restrict__ repPL) {
  int q = blockIdx.x, b = blockIdx.y;
  int i = threadIdx.x;
  if (i < INNERC) {
    int pr = q / 10, pc = q % 10;
    float s = 0.f;
    for (int kr = 0; kr < 10; ++kr)
      for (int kc = 0; kc < 10; ++kc) {
        int tok = (pr * 10 + kr) * 100 + (pc * 10 + kc);
        const size_t g = ((size_t)b * NTOK + tok) * INNERC + i;
        s += bf2f(wHi[g]) + bf2f(wLo[g]);
      }
    s *= 0.01f;
    int h = i / DHEAD, d = i % DHEAD;
    rep[(((size_t)b * HEADS + h) * NQ + q) * DHEAD + d] = s;
    const float sv = s * SCALE;
    const ushort hh = f2bf(sv);
    const size_t pg = (((size_t)b * HEADS + h) * 128 + q) * 64 + d;
    repPH[pg] = hh;
    repPL[pg] = f2bf(sv - bf2f(hh));
  }
  // zero d-pad columns 50..63 for this (b,q) across all heads
  for (int j = threadIdx.x; j < HEADS * 14; j += 320) {
    int h2 = j / 14, d2 = DHEAD + (j % 14);
    const size_t pg = (((size_t)b * HEADS + h2) * 128 + q) * 64 + d2;
    repPH[pg] = 0;
    repPL[pg] = 0;
  }
}

// ---------------------------------------------------------------------------
// Stage-1 attention, MFMA split-flash (unchanged from R9 — verified)
// ---------------------------------------------------------------------------
__global__ __launch_bounds__(256, 3) void attn1_mfma(
    const ushort* __restrict__ wHi, const ushort* __restrict__ wLo,
    const float* __restrict__ rep,
    float* __restrict__ m_part, float* __restrict__ l_part,
    float* __restrict__ delta_part) {
  const int bh = blockIdx.x, s = blockIdx.y;
  const int b = bh / HEADS, h = bh % HEADS;
  const int t = threadIdx.x;
  const int lane = t & 63, wv = t >> 6;
  const int l15 = lane & 15, l4 = lane >> 4;

  __shared__ ushort Khi[32][72], Klo[32][72];
  __shared__ ushort VThi[64][40], VTlo[64][40];
  __shared__ ushort Phi[128][40], Plo[128][40];

  short8 qhi[2][2], qlo[2][2];
#pragma unroll
  for (int mi = 0; mi < 2; ++mi) {
#pragma unroll
    for (int ks = 0; ks < 2; ++ks) {
      const int qr = 32 * wv + 16 * mi + l15;
      short8 th, tl;
#pragma unroll
      for (int j = 0; j < 8; ++j) {
        const int k = 32 * ks + 8 * l4 + j;
        float v = (qr < NQ && k < DHEAD)
                      ? rep[((size_t)bh * NQ + qr) * DHEAD + k] * SCALE : 0.f;
        ushort hh = f2bf(v);
        th[j] = (short)hh;
        tl[j] = (short)f2bf(v - bf2f(hh));
      }
      qhi[mi][ks] = th; qlo[mi][ks] = tl;
    }
  }

  f32x4 accO[2][4];
  float m_run[2][4], l_run[2][4];
#pragma unroll
  for (int mi = 0; mi < 2; ++mi) {
#pragma unroll
    for (int r = 0; r < 4; ++r) { m_run[mi][r] = NEGBIG; l_run[mi][r] = 0.f; }
#pragma unroll
    for (int di = 0; di < 4; ++di) accO[mi][di] = (f32x4){0.f, 0.f, 0.f, 0.f};
  }

  const int n0 = s * CHUNK;
  const int n1 = min(NTOK, n0 + CHUNK);

  for (int nt = n0; nt < n1; nt += 32) {
    __syncthreads();
#pragma unroll
    for (int i = 0; i < 4; ++i) {
      const int idx = t + i * 256;
      const int tr = idx >> 5;
      const int d = (idx & 31) * 2;
      const bool inb = (nt + tr < n1) && (d < DHEAD);
      uint hv = 0, lv = 0;
      if (inb) {
        const size_t g = ((size_t)b * NTOK + nt + tr) * INNERC + h * DHEAD + d;
        hv = *(const uint*)&wHi[g];
        lv = *(const uint*)&wLo[g];
      }
      *(uint*)&Khi[tr][d] = hv;
      *(uint*)&Klo[tr][d] = lv;
      const int ps = ((((tr >> 3) + (d >> 3)) & 3) << 3) + (tr & 7);
      VThi[d][ps] = (ushort)(hv & 0xffffu);
      VTlo[d][ps] = (ushort)(lv & 0xffffu);
      VThi[d + 1][ps] = (ushort)(hv >> 16);
      VTlo[d + 1][ps] = (ushort)(lv >> 16);
    }
    __syncthreads();

    f32x4 accS[2][2];
#pragma unroll
    for (int mi = 0; mi < 2; ++mi)
#pragma unroll
      for (int ni = 0; ni < 2; ++ni) accS[mi][ni] = (f32x4){0.f, 0.f, 0.f, 0.f};
#pragma unroll
    for (int ks = 0; ks < 2; ++ks) {
      short8 kh[2], kl[2];
#pragma unroll
      for (int ni = 0; ni < 2; ++ni) {
        kh[ni] = *(const short8*)&Khi[16 * ni + l15][32 * ks + 8 * l4];
        kl[ni] = *(const short8*)&Klo[16 * ni + l15][32 * ks + 8 * l4];
      }
#pragma unroll
      for (int mi = 0; mi < 2; ++mi)
#pragma unroll
        for (int ni = 0; ni < 2; ++ni) {
          accS[mi][ni] = __builtin_amdgcn_mfma_f32_16x16x32_bf16(qhi[mi][ks], kh[ni], accS[mi][ni], 0, 0, 0);
          accS[mi][ni] = __builtin_amdgcn_mfma_f32_16x16x32_bf16(qlo[mi][ks], kh[ni], accS[mi][ni], 0, 0, 0);
          accS[mi][ni] = __builtin_amdgcn_mfma_f32_16x16x32_bf16(qhi[mi][ks], kl[ni], accS[mi][ni], 0, 0, 0);
        }
    }

    bool cval[2];
#pragma unroll
    for (int ni = 0; ni < 2; ++ni) cval[ni] = (nt + 16 * ni + l15) < n1;
#pragma unroll
    for (int mi = 0; mi < 2; ++mi) {
#pragma unroll
      for (int ni = 0; ni < 2; ++ni)
        if (!cval[ni]) {
#pragma unroll
          for (int r = 0; r < 4; ++r) accS[mi][ni][r] = NEGBIG;
        }
#pragma unroll
      for (int r = 0; r < 4; ++r) {
        float mx = fmaxf(accS[mi][0][r], accS[mi][1][r]);
        mx = fmaxf(mx, __shfl_xor(mx, 1));
        mx = fmaxf(mx, __shfl_xor(mx, 2));
        mx = fmaxf(mx, __shfl_xor(mx, 4));
        mx = fmaxf(mx, __shfl_xor(mx, 8));
        const float m_new = fmaxf(m_run[mi][r], mx);
        const float sc = __expf(m_run[mi][r] - m_new);
        m_run[mi][r] = m_new;
        l_run[mi][r] *= sc;
#pragma unroll
        for (int di = 0; di < 4; ++di) accO[mi][di][r] *= sc;
        float ps = 0.f;
#pragma unroll
        for (int ni = 0; ni < 2; ++ni) {
          const float p = __expf(accS[mi][ni][r] - m_new);
          accS[mi][ni][r] = p;
          ps += p;
        }
        ps += __shfl_xor(ps, 1);
        ps += __shfl_xor(ps, 2);
        ps += __shfl_xor(ps, 4);
        ps += __shfl_xor(ps, 8);
        l_run[mi][r] += ps;
      }
#pragma unroll
      for (int ni = 0; ni < 2; ++ni)
#pragma unroll
        for (int r = 0; r < 4; ++r) {
          const int row = 32 * wv + 16 * mi + 4 * l4 + r;
          const int col = 16 * ni + l15;
          const float p = accS[mi][ni][r];
          const ushort ph = f2bf(p);
          Phi[row][col] = ph;
          Plo[row][col] = f2bf(p - bf2f(ph));
        }
    }

#pragma unroll
    for (int mi = 0; mi < 2; ++mi) {
      const short8 pah = *(const short8*)&Phi[32 * wv + 16 * mi + l15][8 * l4];
      const short8 pal = *(const short8*)&Plo[32 * wv + 16 * mi + l15][8 * l4];
#pragma unroll
      for (int di = 0; di < 4; ++di) {
        const int vs = (((l4 + 2 * di + (l15 >> 3)) & 3)) << 3;
        const short8 vbh = *(const short8*)&VThi[16 * di + l15][vs];
        const short8 vbl = *(const short8*)&VTlo[16 * di + l15][vs];
        accO[mi][di] = __builtin_amdgcn_mfma_f32_16x16x32_bf16(pah, vbh, accO[mi][di], 0, 0, 0);
        accO[mi][di] = __builtin_amdgcn_mfma_f32_16x16x32_bf16(pal, vbh, accO[mi][di], 0, 0, 0);
        accO[mi][di] = __builtin_amdgcn_mfma_f32_16x16x32_bf16(pah, vbl, accO[mi][di], 0, 0, 0);
      }
    }
  }

  const size_t base = ((size_t)bh * NSPLIT + s) * NQ;
#pragma unroll
  for (int mi = 0; mi < 2; ++mi)
#pragma unroll
    for (int r = 0; r < 4; ++r) {
      const int q = 32 * wv + 16 * mi + 4 * l4 + r;
      if (q < NQ && l15 == 0) {
        m_part[base + q] = m_run[mi][r];
        l_part[base + q] = l_run[mi][r];
      }
#pragma unroll
      for (int di = 0; di < 4; ++di) {
        const int d = 16 * di + l15;
        if (q < NQ && d < DHEAD)
          delta_part[(base + q) * DHEAD + d] = accO[mi][di][r];
      }
    }
}

// ---------------------------------------------------------------------------
// Combine split partials -> reph2, final m,l per (bh,q)
// ---------------------------------------------------------------------------
__global__ __launch_bounds__(256) void attn1_combine(
    const float* __restrict__ rep, const float* __restrict__ m_part,
    const float* __restrict__ l_part, const float* __restrict__ delta_part,
    const float* __restrict__ step_rep,
    float* __restrict__ reph2, float* __restrict__ m_fin, float* __restrict__ l_fin) {
  int bh = blockIdx.x;
  int h = bh % HEADS;
  int t = threadIdx.x;
  __shared__ float Mf[NQ], Lf[NQ];
  if (t < NQ) {
    int q = t;
    float M = -INFINITY;
#pragma unroll
    for (int s2 = 0; s2 < NSPLIT; ++s2)
      M = fmaxf(M, m_part[((size_t)bh * NSPLIT + s2) * NQ + q]);
    float L = 0.f;
#pragma unroll
    for (int s2 = 0; s2 < NSPLIT; ++s2)
      L += l_part[((size_t)bh * NSPLIT + s2) * NQ + q] *
           __expf(m_part[((size_t)bh * NSPLIT + s2) * NQ + q] - M);
    Mf[q] = M; Lf[q] = L;
    m_fin[(size_t)bh * NQ + q] = M;
    l_fin[(size_t)bh * NQ + q] = L;
  }
  __syncthreads();
  float sr = step_rep[h];
  for (int idx = t; idx < NQ * DHEAD; idx += 256) {
    int q = idx / DHEAD, d = idx % DHEAD;
    float sum = 0.f;
#pragma unroll
    for (int s2 = 0; s2 < NSPLIT; ++s2) {
      size_t pb = ((size_t)bh * NSPLIT + s2) * NQ + q;
      sum += __expf(m_part[pb] - Mf[q]) * delta_part[pb * DHEAD + d];
    }
    float rd = sum / Lf[q];
    reph2[(size_t)bh * NQ * DHEAD + idx] =
        rep[(size_t)bh * NQ * DHEAD + idx] + sr * rd;
  }
}

// ---------------------------------------------------------------------------
// Stage-2 self attention -> xqT planes [bh][64][128] (hi/lo), q-pads zeroed
// ---------------------------------------------------------------------------
__global__ __launch_bounds__(256) void attn2_kernel(
    const float* __restrict__ reph2, const float* __restrict__ step_x,
    ushort* __restrict__ xqTH, ushort* __restrict__ xqTL) {
  int bh = blockIdx.x;
  int h = bh % HEADS;
  int t = threadIdx.x;
  __shared__ float r2[NQ * DHEAD];
  __shared__ float att[NQ * NQ];

  for (int idx = t; idx < NQ * DHEAD; idx += 256)
    r2[idx] = reph2[(size_t)bh * NQ * DHEAD + idx];
  __syncthreads();

  for (int idx = t; idx < NQ * NQ; idx += 256) {
    int qq = idx / NQ, jj = idx % NQ;
    float s = 0.f;
#pragma unroll
    for (int k = 0; k < DHEAD; ++k) s += r2[qq * DHEAD + k] * r2[jj * DHEAD + k];
    att[idx] = s * SCALE;
  }
  __syncthreads();
  if (t < NQ) {
    float M = -INFINITY;
    for (int j = 0; j < NQ; ++j) M = fmaxf(M, att[t * NQ + j]);
    float L = 0.f;
    for (int j = 0; j < NQ; ++j) { float e = __expf(att[t * NQ + j] - M); att[t * NQ + j] = e; L += e; }
    float inv = 1.f / L;
    for (int j = 0; j < NQ; ++j) att[t * NQ + j] *= inv;
  }
  __syncthreads();
  float sx = step_x[h];
  for (int idx = t; idx < NQ * DHEAD; idx += 256) {
    int qd_q = idx / DHEAD, d = idx % DHEAD;
    float v = 0.f;
#pragma unroll
    for (int j = 0; j < NQ; ++j) v += att[qd_q * NQ + j] * r2[j * DHEAD + d];
    v *= sx;
    const size_t pg = ((size_t)bh * 64 + d) * 128 + qd_q;
    const ushort hh = f2bf(v);
    xqTH[pg] = hh;
    xqTL[pg] = f2bf(v - bf2f(hh));
  }
  // zero q-pad columns 100..127 for all 64 d-rows
  for (int idx = t; idx < 64 * 28; idx += 256) {
    int d = idx / 28, qq2 = NQ + (idx % 28);
    const size_t pg = ((size_t)bh * 64 + d) * 128 + qq2;
    xqTH[pg] = 0;
    xqTL[pg] = 0;
  }
}

// ---------------------------------------------------------------------------
// Pass 2 v4 (MFMA, barrier-free): direct global fragments from w planes
// (masked k>=50), rep planes and xqT planes; only P goes through LDS
// (wave-local rows).  LDS 18.4KB, launch_bounds(256,4) -> ~4 blk/CU.
// ---------------------------------------------------------------------------
#define TT3 64
__global__ __launch_bounds__(256, 4) void bcast4_kernel(
    const ushort* __restrict__ wHi, const ushort* __restrict__ wLo,
    const ushort* __restrict__ repPH, const ushort* __restrict__ repPL,
    const ushort* __restrict__ xqTH, const ushort* __restrict__ xqTL,
    const float* __restrict__ m_fin, const float* __restrict__ l_fin,
    ushort* __restrict__ xdHi, ushort* __restrict__ xdLo) {
  const int tile = blockIdx.x, bh = blockIdx.y;
  const int b = bh / HEADS, h = bh % HEADS;
  const int tok0 = tile * TT3;
  const int t = threadIdx.x;
  const int lane = t & 63, wv = t >> 6;
  const int l15 = lane & 15, l4 = lane >> 4;

  __shared__ ushort pH[64][72], pL[64][72];

  // ---- w A-fragments direct from global (4B-aligned uint loads, masked) ----
  const int tokA = tok0 + 16 * wv + l15;
  short8 awh[2], awl[2];
#pragma unroll
  for (int ks = 0; ks < 2; ++ks) {
    const int kbase = 32 * ks + 8 * l4;
    uint hv[4] = {0, 0, 0, 0}, lv[4] = {0, 0, 0, 0};
    if (tokA < NTOK && kbase < DHEAD) {
      const size_t g = ((size_t)b * NTOK + tokA) * INNERC + h * DHEAD + kbase;
#pragma unroll
      for (int c = 0; c < 4; ++c) {
        hv[c] = *(const uint*)&wHi[g + 2 * c];
        lv[c] = *(const uint*)&wLo[g + 2 * c];
      }
    }
    short8 th, tl;
#pragma unroll
    for (int j = 0; j < 8; ++j) {
      const bool ok = (kbase + j) < DHEAD;
      const ushort hsel = (j & 1) ? (ushort)(hv[j >> 1] >> 16) : (ushort)(hv[j >> 1] & 0xffffu);
      const ushort lsel = (j & 1) ? (ushort)(lv[j >> 1] >> 16) : (ushort)(lv[j >> 1] & 0xffffu);
      th[j] = ok ? (short)hsel : (short)0;
      tl[j] = ok ? (short)lsel : (short)0;
    }
    awh[ks] = th;
    awl[ks] = tl;
  }

  f32x4 accO[4];
#pragma unroll
  for (int di = 0; di < 4; ++di) accO[di] = (f32x4){0.f, 0.f, 0.f, 0.f};

#pragma unroll
  for (int qc = 0; qc < 2; ++qc) {
    const int q0 = qc * 64;

    // ---- S' = w . rep^T (B-frags direct from rep planes) ----
    f32x4 accS[4];
#pragma unroll
    for (int ni = 0; ni < 4; ++ni) accS[ni] = (f32x4){0.f, 0.f, 0.f, 0.f};
#pragma unroll
    for (int ks = 0; ks < 2; ++ks) {
#pragma unroll
      for (int ni = 0; ni < 4; ++ni) {
        const size_t rg = (((size_t)bh * 128) + (q0 + 16 * ni + l15)) * 64 + 32 * ks + 8 * l4;
        const short8 rbh = *(const short8*)&repPH[rg];
        const short8 rbl = *(const short8*)&repPL[rg];
        accS[ni] = __builtin_amdgcn_mfma_f32_16x16x32_bf16(awh[ks], rbh, accS[ni], 0, 0, 0);
        accS[ni] = __builtin_amdgcn_mfma_f32_16x16x32_bf16(awl[ks], rbh, accS[ni], 0, 0, 0);
        accS[ni] = __builtin_amdgcn_mfma_f32_16x16x32_bf16(awh[ks], rbl, accS[ni], 0, 0, 0);
      }
    }

    // ---- p = exp(S'-m[q])/l[q]; store P hi/lo (wave-local rows) ----
#pragma unroll
    for (int ni = 0; ni < 4; ++ni) {
      const int q = q0 + 16 * ni + l15;
      const bool valid = (q < NQ);
      float mq = 0.f, li = 0.f;
      if (valid) {
        mq = m_fin[(size_t)bh * NQ + q];
        li = 1.f / l_fin[(size_t)bh * NQ + q];
      }
#pragma unroll
      for (int r = 0; r < 4; ++r) {
        const float p = valid ? __expf(accS[ni][r] - mq) * li : 0.f;
        const int row = 16 * wv + 4 * l4 + r;
        const ushort ph = f2bf(p);
        pH[row][16 * ni + l15] = ph;
        pL[row][16 * ni + l15] = f2bf(p - bf2f(ph));
      }
    }
    // no barrier: PV reads only this wave's own 16 P-rows

    // ---- O += P . xqT^T (B-frags direct from xqT planes) ----
#pragma unroll
    for (int ks2 = 0; ks2 < 2; ++ks2) {
      const short8 pah = *(const short8*)&pH[16 * wv + l15][32 * ks2 + 8 * l4];
      const short8 pal = *(const short8*)&pL[16 * wv + l15][32 * ks2 + 8 * l4];
#pragma unroll
      for (int di = 0; di < 4; ++di) {
        const size_t xg = (((size_t)bh * 64) + (16 * di + l15)) * 128 + q0 + 32 * ks2 + 8 * l4;
        const short8 vbh = *(const short8*)&xqTH[xg];
        const short8 vbl = *(const short8*)&xqTL[xg];
        accO[di] = __builtin_amdgcn_mfma_f32_16x16x32_bf16(pah, vbh, accO[di], 0, 0, 0);
        accO[di] = __builtin_amdgcn_mfma_f32_16x16x32_bf16(pal, vbh, accO[di], 0, 0, 0);
        accO[di] = __builtin_amdgcn_mfma_f32_16x16x32_bf16(pah, vbl, accO[di], 0, 0, 0);
      }
    }
  }

  // ---- epilogue: write xd planes (stride XDK) ----
#pragma unroll
  for (int di = 0; di < 4; ++di) {
    const int d = di * 16 + l15;
    if (d >= DHEAD) continue;
#pragma unroll
    for (int r = 0; r < 4; ++r) {
      const int tok = tok0 + wv * 16 + 4 * l4 + r;
      if (tok < NTOK) {
        const float val = accO[di][r];
        const ushort hh = f2bf(val);
        const size_t g = ((size_t)b * NTOK + tok) * XDK + h * DHEAD + d;
        xdHi[g] = hh;
        xdLo[g] = f2bf(val - bf2f(hh));
      }
    }
  }
}

// ---------------------------------------------------------------------------
extern "C" void kernel_launch(void* const* d_in, const int* in_sizes, int n_in,
                              void* d_out, int out_size, void* d_ws, size_t ws_size,
                              hipStream_t stream) {
  const float* x        = (const float*)d_in[0];
  const float* proj_w   = (const float*)d_in[1];
  const float* step_x   = (const float*)d_in[2];
  const float* step_rep = (const float*)d_in[3];
  const float* out_w    = (const float*)d_in[4];
  const float* out_b    = (const float*)d_in[5];
  float* out = (float*)d_out;

  uint8_t* p8 = (uint8_t*)d_ws;
  ushort* wHi    = (ushort*)(p8);                  //  48,720,000 B
  ushort* wLo    = (ushort*)(p8 + 48720000);       //  48,720,000
  float*  rep    = (float*) (p8 + 97440000);       //     960,000
  float*  reph2  = (float*) (p8 + 98400000);       //     960,000
  // (960,000 B hole where fp32 xq used to live — unused)
  float*  m_part = (float*) (p8 + 100320000);      //     614,400 (48*32*100)
  float*  l_part = (float*) (p8 + 100934400);      //     614,400
  float*  m_fin  = (float*) (p8 + 101548800);      //      19,200
  float*  l_fin  = (float*) (p8 + 101568000);      //      19,200
  ushort* xdHi   = (ushort*)(p8 + 101587200);      //  51,968,000
  ushort* xdLo   = (ushort*)(p8 + 153555200);      //  51,968,000
  ushort* pwHi   = (ushort*)(p8 + 205523200);      //     491,520
  ushort* pwLo   = (ushort*)(p8 + 206014720);      //     491,520
  ushort* owHi   = (ushort*)(p8 + 206506240);      //     491,520
  ushort* owLo   = (ushort*)(p8 + 206997760);      //     491,520
  ushort* repPH  = (ushort*)(p8 + 207489280);      //     786,432 (48*128*64*2)
  ushort* repPL  = (ushort*)(p8 + 208275712);      //     786,432
  ushort* xqTH   = (ushort*)(p8 + 209062144);      //     786,432 (48*64*128*2)
  ushort* xqTL   = (ushort*)(p8 + 209848576);      //     786,432
  // end 210,635,008 B (~210.6 MB) < proven 213.8 MB.
  float* delta = (float*)xdHi;   // consumed by combine BEFORE pad-zero + bcast4

  // 0. pre-split weights
  split_pad<<<960, 256, 0, stream>>>(proj_w, pwHi, pwLo, INNERC, DIMC, 320, DIMC);
  split_pad<<<960, 256, 0, stream>>>(out_w, owHi, owLo, DIMC, INNERC, DIMC, XDK);
  // 1. w planes = x @ proj_w^T (single N pass)
  gemm1_xw<<<1269, 256, 0, stream>>>(x, pwHi, pwLo, wHi, wLo);
  // 2. pooling -> rep fp32 + rep*SCALE planes
  pool_kernel<<<dim3(NQ, BATCH), 320, 0, stream>>>(wHi, wLo, rep, repPH, repPL);
  // 3. stage-1 attention + combine (delta aliases xdHi!)
  attn1_mfma<<<dim3(NBH, NSPLIT), 256, 0, stream>>>(wHi, wLo, rep, m_part, l_part, delta);
  attn1_combine<<<NBH, 256, 0, stream>>>(rep, m_part, l_part, delta, step_rep,
                                         reph2, m_fin, l_fin);
  // 3b. zero xd pad columns AFTER delta is consumed, BEFORE bcast4/gemm2
  zero_xd_pad<<<2048, 256, 0, stream>>>(xdHi, xdLo);
  // 4. stage-2 self-attention -> xqT planes
  attn2_kernel<<<NBH, 256, 0, stream>>>(reph2, step_x, xqTH, xqTL);
  // 5. broadcast back -> xd planes (barrier-free MFMA)
  bcast4_kernel<<<dim3(159, NBH), 256, 0, stream>>>(
      wHi, wLo, repPH, repPL, xqTH, xqTL, m_fin, l_fin, xdHi, xdLo);
  // 6. out = xd @ out_w^T + bias (XCD-swizzled)
  gemm2_out<<<3807, 256, 0, stream>>>(xdHi, xdLo, owHi, owLo, out_b, out);
}

// Round 11
// 758.865 us; speedup vs baseline: 3.4437x; 1.1204x over previous
//
#include <hip/hip_runtime.h>
#include <math.h>

#define BATCH   8
#define NTOK    10150
#define DIMC    768
#define INNERC  300
#define HEADS   6
#define DHEAD   50
#define NQ      100
#define NBH     48          // BATCH*HEADS
#define NSPLIT  32
#define CHUNK   320         // 32*320 = 10240 >= 10150
#define SCALE   0.14142135623730951f   // 50^-0.5
#define MTOT    (BATCH*NTOK)           // 81200
#define XDK     320                    // padded K stride for xd planes
#define NEGBIG  -1.0e30f

typedef __attribute__((ext_vector_type(8))) short short8;
typedef __attribute__((ext_vector_type(4))) float f32x4;

__device__ __forceinline__ ushort f2bf(float x) {
  uint u = __float_as_uint(x);
  uint r = (u + 0x7fffu + ((u >> 16) & 1u)) >> 16;
  return (ushort)r;
}
__device__ __forceinline__ float bf2f(ushort h) {
  return __uint_as_float(((uint)h) << 16);
}

// ---------------------------------------------------------------------------
// Pre-split fp32 -> padded hi/lo bf16 planes.  dst is [Rp][Cp]; src [R][C].
// ---------------------------------------------------------------------------
__global__ void split_pad(const float* __restrict__ src, ushort* __restrict__ dHi,
                          ushort* __restrict__ dLo, int R, int C, int Rp, int Cp) {
  const int total = Rp * Cp;
  for (int i = blockIdx.x * blockDim.x + threadIdx.x; i < total;
       i += gridDim.x * blockDim.x) {
    const int r = i / Cp, c = i % Cp;
    const float v = (r < R && c < C) ? src[r * C + c] : 0.f;
    const ushort hh = f2bf(v);
    dHi[i] = hh;
    dLo[i] = f2bf(v - bf2f(hh));
  }
}

// Zero the k-pad columns (300..319) of the xd planes.
// MUST run AFTER attn1_combine (delta aliases xdHi) and BEFORE bcast/gemm2.
__global__ void zero_xd_pad(ushort* __restrict__ xdHi, ushort* __restrict__ xdLo) {
  const int total = MTOT * 20;
  for (int i = blockIdx.x * blockDim.x + threadIdx.x; i < total;
       i += gridDim.x * blockDim.x) {
    const size_t g = (size_t)(i / 20) * XDK + 300 + (i % 20);
    xdHi[g] = 0;
    xdLo[g] = 0;
  }
}

// ---------------------------------------------------------------------------
// GEMM 1: w(planes) = x @ proj_w^T.   BM=64, BN=320 (single N pass), BK=32.
// ---------------------------------------------------------------------------
__global__ __launch_bounds__(256, 2) void gemm1_xw(
    const float* __restrict__ x, const ushort* __restrict__ pwHi,
    const ushort* __restrict__ pwLo, ushort* __restrict__ wHi,
    ushort* __restrict__ wLo) {
  __shared__ ushort aH[64][40], aL[64][40];
  __shared__ ushort bH[320][40], bL[320][40];
  const int t = threadIdx.x;
  const int lane = t & 63, wv = t >> 6;
  const int l15 = lane & 15, l4 = lane >> 4;
  const int m0 = blockIdx.x * 64;
  const int arow = t >> 2, aslot = t & 3;

  f32x4 acc[4][5];
#pragma unroll
  for (int i = 0; i < 4; ++i)
#pragma unroll
    for (int j = 0; j < 5; ++j) acc[i][j] = (f32x4){0.f, 0.f, 0.f, 0.f};

  for (int k0 = 0; k0 < DIMC; k0 += 32) {
    __syncthreads();
    {
      float v[8];
      const int m = m0 + arow;
      if (m < MTOT) {
        const float* xp = &x[(size_t)m * DIMC + k0 + aslot * 8];
        const float4 u0 = *(const float4*)xp;
        const float4 u1 = *(const float4*)(xp + 4);
        v[0] = u0.x; v[1] = u0.y; v[2] = u0.z; v[3] = u0.w;
        v[4] = u1.x; v[5] = u1.y; v[6] = u1.z; v[7] = u1.w;
      } else {
#pragma unroll
        for (int j = 0; j < 8; ++j) v[j] = 0.f;
      }
      short8 th, tl;
#pragma unroll
      for (int j = 0; j < 8; ++j) {
        const ushort hh = f2bf(v[j]);
        th[j] = (short)hh;
        tl[j] = (short)f2bf(v[j] - bf2f(hh));
      }
      *(short8*)&aH[arow][aslot * 8] = th;
      *(short8*)&aL[arow][aslot * 8] = tl;
    }
#pragma unroll
    for (int i = 0; i < 5; ++i) {
      const int sid = t + i * 256;
      const int row = sid >> 2, slot = sid & 3;
      const size_t g = (size_t)row * DIMC + k0 + slot * 8;
      *(short8*)&bH[row][slot * 8] = *(const short8*)&pwHi[g];
      *(short8*)&bL[row][slot * 8] = *(const short8*)&pwLo[g];
    }
    __syncthreads();

    short8 ah[4], al[4];
#pragma unroll
    for (int i = 0; i < 4; ++i) {
      ah[i] = *(const short8*)&aH[i * 16 + l15][l4 * 8];
      al[i] = *(const short8*)&aL[i * 16 + l15][l4 * 8];
    }
#pragma unroll
    for (int j = 0; j < 5; ++j) {
      const int brow = wv * 80 + j * 16 + l15;
      const short8 bhf = *(const short8*)&bH[brow][l4 * 8];
      const short8 blf = *(const short8*)&bL[brow][l4 * 8];
#pragma unroll
      for (int i = 0; i < 4; ++i) {
        acc[i][j] = __builtin_amdgcn_mfma_f32_16x16x32_bf16(ah[i], bhf, acc[i][j], 0, 0, 0);
        acc[i][j] = __builtin_amdgcn_mfma_f32_16x16x32_bf16(al[i], bhf, acc[i][j], 0, 0, 0);
        acc[i][j] = __builtin_amdgcn_mfma_f32_16x16x32_bf16(ah[i], blf, acc[i][j], 0, 0, 0);
      }
    }
  }

#pragma unroll
  for (int j = 0; j < 5; ++j) {
    const int col = wv * 80 + j * 16 + l15;
    if (col >= INNERC) continue;
#pragma unroll
    for (int i = 0; i < 4; ++i)
#pragma unroll
      for (int r = 0; r < 4; ++r) {
        const int m = m0 + i * 16 + l4 * 4 + r;
        if (m < MTOT) {
          const float val = acc[i][j][r];
          const ushort hh = f2bf(val);
          const size_t g = (size_t)m * INNERC + col;
          wHi[g] = hh;
          wLo[g] = f2bf(val - bf2f(hh));
        }
      }
  }
}

// ---------------------------------------------------------------------------
// GEMM 2: out = xd(planes) @ out_w(planes)^T + bias.
// ---------------------------------------------------------------------------
__global__ __launch_bounds__(256, 2) void gemm2_out(
    const ushort* __restrict__ xdHi, const ushort* __restrict__ xdLo,
    const ushort* __restrict__ owHi, const ushort* __restrict__ owLo,
    const float* __restrict__ out_b, float* __restrict__ out) {
  __shared__ ushort aH[64][40], aL[64][40];
  __shared__ ushort bH[256][40], bL[256][40];
  const int t = threadIdx.x;
  const int lane = t & 63, wv = t >> 6;
  const int l15 = lane & 15, l4 = lane >> 4;
  const int nwg = gridDim.x;
  const int q = nwg >> 3, r = nwg & 7;
  const int xcd = blockIdx.x & 7, idx = blockIdx.x >> 3;
  const int wg = (xcd < r ? xcd * (q + 1) : r * (q + 1) + (xcd - r) * q) + idx;
  const int bn = wg % 3, bm = wg / 3;
  const int m0 = bm * 64, n0 = bn * 256;
  const int arow = t >> 2, aslot = t & 3;

  f32x4 acc[4][4];
#pragma unroll
  for (int i = 0; i < 4; ++i)
#pragma unroll
    for (int j = 0; j < 4; ++j) acc[i][j] = (f32x4){0.f, 0.f, 0.f, 0.f};

  for (int k0 = 0; k0 < XDK; k0 += 32) {
    __syncthreads();
    {
      const int m = m0 + arow;
      if (m < MTOT) {
        const size_t g = (size_t)m * XDK + k0 + aslot * 8;
        *(short8*)&aH[arow][aslot * 8] = *(const short8*)&xdHi[g];
        *(short8*)&aL[arow][aslot * 8] = *(const short8*)&xdLo[g];
      } else {
        const short8 z = {0, 0, 0, 0, 0, 0, 0, 0};
        *(short8*)&aH[arow][aslot * 8] = z;
        *(short8*)&aL[arow][aslot * 8] = z;
      }
    }
#pragma unroll
    for (int i = 0; i < 4; ++i) {
      const int sid = t + i * 256;
      const int row = sid >> 2, slot = sid & 3;
      const size_t g = (size_t)(n0 + row) * XDK + k0 + slot * 8;
      *(short8*)&bH[row][slot * 8] = *(const short8*)&owHi[g];
      *(short8*)&bL[row][slot * 8] = *(const short8*)&owLo[g];
    }
    __syncthreads();

    short8 ah[4], al[4];
#pragma unroll
    for (int i = 0; i < 4; ++i) {
      ah[i] = *(const short8*)&aH[i * 16 + l15][l4 * 8];
      al[i] = *(const short8*)&aL[i * 16 + l15][l4 * 8];
    }
#pragma unroll
    for (int j = 0; j < 4; ++j) {
      const int brow = wv * 64 + j * 16 + l15;
      const short8 bhf = *(const short8*)&bH[brow][l4 * 8];
      const short8 blf = *(const short8*)&bL[brow][l4 * 8];
#pragma unroll
      for (int i = 0; i < 4; ++i) {
        acc[i][j] = __builtin_amdgcn_mfma_f32_16x16x32_bf16(ah[i], bhf, acc[i][j], 0, 0, 0);
        acc[i][j] = __builtin_amdgcn_mfma_f32_16x16x32_bf16(al[i], bhf, acc[i][j], 0, 0, 0);
        acc[i][j] = __builtin_amdgcn_mfma_f32_16x16x32_bf16(ah[i], blf, acc[i][j], 0, 0, 0);
      }
    }
  }

#pragma unroll
  for (int j = 0; j < 4; ++j) {
    const int col = n0 + wv * 64 + j * 16 + l15;
    const float bv = out_b[col];
#pragma unroll
    for (int i = 0; i < 4; ++i)
#pragma unroll
      for (int r = 0; r < 4; ++r) {
        const int m = m0 + i * 16 + l4 * 4 + r;
        if (m < MTOT) out[(size_t)m * DIMC + col] = acc[i][j][r] + bv;
      }
  }
}

// ---------------------------------------------------------------------------
// Adaptive avg-pool -> rep fp32 AND padded rep*SCALE hi/lo planes [bh][128][64]
// ---------------------------------------------------------------------------
__global__ void pool_kernel(const ushort* __restrict__ wHi,
                            const ushort* __restrict__ wLo,
                            float* __restrict__ rep,
                            ushort* __restrict__ repPH, ushort* __restrict__ repPL) {
  int q = blockIdx.x, b = blockIdx.y;
  int i = threadIdx.x;
  if (i < INNERC) {
    int pr = q / 10, pc = q % 10;
    float s = 0.f;
    for (int kr = 0; kr < 10; ++kr)
      for (int kc = 0; kc < 10; ++kc) {
        int tok = (pr * 10 + kr) * 100 + (pc * 10 + kc);
        const size_t g = ((size_t)b * NTOK + tok) * INNERC + i;
        s += bf2f(wHi[g]) + bf2f(wLo[g]);
      }
    s *= 0.01f;
    int h = i / DHEAD, d = i % DHEAD;
    rep[(((size_t)b * HEADS + h) * NQ + q) * DHEAD + d] = s;
    const float sv = s * SCALE;
    const ushort hh = f2bf(sv);
    const size_t pg = (((size_t)b * HEADS + h) * 128 + q) * 64 + d;
    repPH[pg] = hh;
    repPL[pg] = f2bf(sv - bf2f(hh));
  }
  // zero d-pad columns 50..63 for this (b,q) across all heads
  for (int j = threadIdx.x; j < HEADS * 14; j += 320) {
    int h2 = j / 14, d2 = DHEAD + (j % 14);
    const size_t pg = (((size_t)b * HEADS + h2) * 128 + q) * 64 + d2;
    repPH[pg] = 0;
    repPL[pg] = 0;
  }
}

// ---------------------------------------------------------------------------
// Stage-1 attention, MFMA split-flash (unchanged — verified)
// ---------------------------------------------------------------------------
__global__ __launch_bounds__(256, 3) void attn1_mfma(
    const ushort* __restrict__ wHi, const ushort* __restrict__ wLo,
    const float* __restrict__ rep,
    float* __restrict__ m_part, float* __restrict__ l_part,
    float* __restrict__ delta_part) {
  const int bh = blockIdx.x, s = blockIdx.y;
  const int b = bh / HEADS, h = bh % HEADS;
  const int t = threadIdx.x;
  const int lane = t & 63, wv = t >> 6;
  const int l15 = lane & 15, l4 = lane >> 4;

  __shared__ ushort Khi[32][72], Klo[32][72];
  __shared__ ushort VThi[64][40], VTlo[64][40];
  __shared__ ushort Phi[128][40], Plo[128][40];

  short8 qhi[2][2], qlo[2][2];
#pragma unroll
  for (int mi = 0; mi < 2; ++mi) {
#pragma unroll
    for (int ks = 0; ks < 2; ++ks) {
      const int qr = 32 * wv + 16 * mi + l15;
      short8 th, tl;
#pragma unroll
      for (int j = 0; j < 8; ++j) {
        const int k = 32 * ks + 8 * l4 + j;
        float v = (qr < NQ && k < DHEAD)
                      ? rep[((size_t)bh * NQ + qr) * DHEAD + k] * SCALE : 0.f;
        ushort hh = f2bf(v);
        th[j] = (short)hh;
        tl[j] = (short)f2bf(v - bf2f(hh));
      }
      qhi[mi][ks] = th; qlo[mi][ks] = tl;
    }
  }

  f32x4 accO[2][4];
  float m_run[2][4], l_run[2][4];
#pragma unroll
  for (int mi = 0; mi < 2; ++mi) {
#pragma unroll
    for (int r = 0; r < 4; ++r) { m_run[mi][r] = NEGBIG; l_run[mi][r] = 0.f; }
#pragma unroll
    for (int di = 0; di < 4; ++di) accO[mi][di] = (f32x4){0.f, 0.f, 0.f, 0.f};
  }

  const int n0 = s * CHUNK;
  const int n1 = min(NTOK, n0 + CHUNK);

  for (int nt = n0; nt < n1; nt += 32) {
    __syncthreads();
#pragma unroll
    for (int i = 0; i < 4; ++i) {
      const int idx = t + i * 256;
      const int tr = idx >> 5;
      const int d = (idx & 31) * 2;
      const bool inb = (nt + tr < n1) && (d < DHEAD);
      uint hv = 0, lv = 0;
      if (inb) {
        const size_t g = ((size_t)b * NTOK + nt + tr) * INNERC + h * DHEAD + d;
        hv = *(const uint*)&wHi[g];
        lv = *(const uint*)&wLo[g];
      }
      *(uint*)&Khi[tr][d] = hv;
      *(uint*)&Klo[tr][d] = lv;
      const int ps = ((((tr >> 3) + (d >> 3)) & 3) << 3) + (tr & 7);
      VThi[d][ps] = (ushort)(hv & 0xffffu);
      VTlo[d][ps] = (ushort)(lv & 0xffffu);
      VThi[d + 1][ps] = (ushort)(hv >> 16);
      VTlo[d + 1][ps] = (ushort)(lv >> 16);
    }
    __syncthreads();

    f32x4 accS[2][2];
#pragma unroll
    for (int mi = 0; mi < 2; ++mi)
#pragma unroll
      for (int ni = 0; ni < 2; ++ni) accS[mi][ni] = (f32x4){0.f, 0.f, 0.f, 0.f};
#pragma unroll
    for (int ks = 0; ks < 2; ++ks) {
      short8 kh[2], kl[2];
#pragma unroll
      for (int ni = 0; ni < 2; ++ni) {
        kh[ni] = *(const short8*)&Khi[16 * ni + l15][32 * ks + 8 * l4];
        kl[ni] = *(const short8*)&Klo[16 * ni + l15][32 * ks + 8 * l4];
      }
#pragma unroll
      for (int mi = 0; mi < 2; ++mi)
#pragma unroll
        for (int ni = 0; ni < 2; ++ni) {
          accS[mi][ni] = __builtin_amdgcn_mfma_f32_16x16x32_bf16(qhi[mi][ks], kh[ni], accS[mi][ni], 0, 0, 0);
          accS[mi][ni] = __builtin_amdgcn_mfma_f32_16x16x32_bf16(qlo[mi][ks], kh[ni], accS[mi][ni], 0, 0, 0);
          accS[mi][ni] = __builtin_amdgcn_mfma_f32_16x16x32_bf16(qhi[mi][ks], kl[ni], accS[mi][ni], 0, 0, 0);
        }
    }

    bool cval[2];
#pragma unroll
    for (int ni = 0; ni < 2; ++ni) cval[ni] = (nt + 16 * ni + l15) < n1;
#pragma unroll
    for (int mi = 0; mi < 2; ++mi) {
#pragma unroll
      for (int ni = 0; ni < 2; ++ni)
        if (!cval[ni]) {
#pragma unroll
          for (int r = 0; r < 4; ++r) accS[mi][ni][r] = NEGBIG;
        }
#pragma unroll
      for (int r = 0; r < 4; ++r) {
        float mx = fmaxf(accS[mi][0][r], accS[mi][1][r]);
        mx = fmaxf(mx, __shfl_xor(mx, 1));
        mx = fmaxf(mx, __shfl_xor(mx, 2));
        mx = fmaxf(mx, __shfl_xor(mx, 4));
        mx = fmaxf(mx, __shfl_xor(mx, 8));
        const float m_new = fmaxf(m_run[mi][r], mx);
        const float sc = __expf(m_run[mi][r] - m_new);
        m_run[mi][r] = m_new;
        l_run[mi][r] *= sc;
#pragma unroll
        for (int di = 0; di < 4; ++di) accO[mi][di][r] *= sc;
        float ps = 0.f;
#pragma unroll
        for (int ni = 0; ni < 2; ++ni) {
          const float p = __expf(accS[mi][ni][r] - m_new);
          accS[mi][ni][r] = p;
          ps += p;
        }
        ps += __shfl_xor(ps, 1);
        ps += __shfl_xor(ps, 2);
        ps += __shfl_xor(ps, 4);
        ps += __shfl_xor(ps, 8);
        l_run[mi][r] += ps;
      }
#pragma unroll
      for (int ni = 0; ni < 2; ++ni)
#pragma unroll
        for (int r = 0; r < 4; ++r) {
          const int row = 32 * wv + 16 * mi + 4 * l4 + r;
          const int col = 16 * ni + l15;
          const float p = accS[mi][ni][r];
          const ushort ph = f2bf(p);
          Phi[row][col] = ph;
          Plo[row][col] = f2bf(p - bf2f(ph));
        }
    }

#pragma unroll
    for (int mi = 0; mi < 2; ++mi) {
      const short8 pah = *(const short8*)&Phi[32 * wv + 16 * mi + l15][8 * l4];
      const short8 pal = *(const short8*)&Plo[32 * wv + 16 * mi + l15][8 * l4];
#pragma unroll
      for (int di = 0; di < 4; ++di) {
        const int vs = (((l4 + 2 * di + (l15 >> 3)) & 3)) << 3;
        const short8 vbh = *(const short8*)&VThi[16 * di + l15][vs];
        const short8 vbl = *(const short8*)&VTlo[16 * di + l15][vs];
        accO[mi][di] = __builtin_amdgcn_mfma_f32_16x16x32_bf16(pah, vbh, accO[mi][di], 0, 0, 0);
        accO[mi][di] = __builtin_amdgcn_mfma_f32_16x16x32_bf16(pal, vbh, accO[mi][di], 0, 0, 0);
        accO[mi][di] = __builtin_amdgcn_mfma_f32_16x16x32_bf16(pah, vbl, accO[mi][di], 0, 0, 0);
      }
    }
  }

  const size_t base = ((size_t)bh * NSPLIT + s) * NQ;
#pragma unroll
  for (int mi = 0; mi < 2; ++mi)
#pragma unroll
    for (int r = 0; r < 4; ++r) {
      const int q = 32 * wv + 16 * mi + 4 * l4 + r;
      if (q < NQ && l15 == 0) {
        m_part[base + q] = m_run[mi][r];
        l_part[base + q] = l_run[mi][r];
      }
#pragma unroll
      for (int di = 0; di < 4; ++di) {
        const int d = 16 * di + l15;
        if (q < NQ && d < DHEAD)
          delta_part[(base + q) * DHEAD + d] = accO[mi][di][r];
      }
    }
}

// ---------------------------------------------------------------------------
// Combine split partials -> reph2, final m,l per (bh,q)
// ---------------------------------------------------------------------------
__global__ __launch_bounds__(256) void attn1_combine(
    const float* __restrict__ rep, const float* __restrict__ m_part,
    const float* __restrict__ l_part, const float* __restrict__ delta_part,
    const float* __restrict__ step_rep,
    float* __restrict__ reph2, float* __restrict__ m_fin, float* __restrict__ l_fin) {
  int bh = blockIdx.x;
  int h = bh % HEADS;
  int t = threadIdx.x;
  __shared__ float Mf[NQ], Lf[NQ];
  if (t < NQ) {
    int q = t;
    float M = -INFINITY;
#pragma unroll
    for (int s2 = 0; s2 < NSPLIT; ++s2)
      M = fmaxf(M, m_part[((size_t)bh * NSPLIT + s2) * NQ + q]);
    float L = 0.f;
#pragma unroll
    for (int s2 = 0; s2 < NSPLIT; ++s2)
      L += l_part[((size_t)bh * NSPLIT + s2) * NQ + q] *
           __expf(m_part[((size_t)bh * NSPLIT + s2) * NQ + q] - M);
    Mf[q] = M; Lf[q] = L;
    m_fin[(size_t)bh * NQ + q] = M;
    l_fin[(size_t)bh * NQ + q] = L;
  }
  __syncthreads();
  float sr = step_rep[h];
  for (int idx = t; idx < NQ * DHEAD; idx += 256) {
    int q = idx / DHEAD, d = idx % DHEAD;
    float sum = 0.f;
#pragma unroll
    for (int s2 = 0; s2 < NSPLIT; ++s2) {
      size_t pb = ((size_t)bh * NSPLIT + s2) * NQ + q;
      sum += __expf(m_part[pb] - Mf[q]) * delta_part[pb * DHEAD + d];
    }
    float rd = sum / Lf[q];
    reph2[(size_t)bh * NQ * DHEAD + idx] =
        rep[(size_t)bh * NQ * DHEAD + idx] + sr * rd;
  }
}

// ---------------------------------------------------------------------------
// Stage-2 self attention -> xqT planes [bh][64][128] (hi/lo), q-pads zeroed
// ---------------------------------------------------------------------------
__global__ __launch_bounds__(256) void attn2_kernel(
    const float* __restrict__ reph2, const float* __restrict__ step_x,
    ushort* __restrict__ xqTH, ushort* __restrict__ xqTL) {
  int bh = blockIdx.x;
  int h = bh % HEADS;
  int t = threadIdx.x;
  __shared__ float r2[NQ * DHEAD];
  __shared__ float att[NQ * NQ];

  for (int idx = t; idx < NQ * DHEAD; idx += 256)
    r2[idx] = reph2[(size_t)bh * NQ * DHEAD + idx];
  __syncthreads();

  for (int idx = t; idx < NQ * NQ; idx += 256) {
    int qq = idx / NQ, jj = idx % NQ;
    float s = 0.f;
#pragma unroll
    for (int k = 0; k < DHEAD; ++k) s += r2[qq * DHEAD + k] * r2[jj * DHEAD + k];
    att[idx] = s * SCALE;
  }
  __syncthreads();
  if (t < NQ) {
    float M = -INFINITY;
    for (int j = 0; j < NQ; ++j) M = fmaxf(M, att[t * NQ + j]);
    float L = 0.f;
    for (int j = 0; j < NQ; ++j) { float e = __expf(att[t * NQ + j] - M); att[t * NQ + j] = e; L += e; }
    float inv = 1.f / L;
    for (int j = 0; j < NQ; ++j) att[t * NQ + j] *= inv;
  }
  __syncthreads();
  float sx = step_x[h];
  for (int idx = t; idx < NQ * DHEAD; idx += 256) {
    int qd_q = idx / DHEAD, d = idx % DHEAD;
    float v = 0.f;
#pragma unroll
    for (int j = 0; j < NQ; ++j) v += att[qd_q * NQ + j] * r2[j * DHEAD + d];
    v *= sx;
    const size_t pg = ((size_t)bh * 64 + d) * 128 + qd_q;
    const ushort hh = f2bf(v);
    xqTH[pg] = hh;
    xqTL[pg] = f2bf(v - bf2f(hh));
  }
  // zero q-pad columns 100..127 for all 64 d-rows
  for (int idx = t; idx < 64 * 28; idx += 256) {
    int d = idx / 28, qq2 = NQ + (idx % 28);
    const size_t pg = ((size_t)bh * 64 + d) * 128 + qq2;
    xqTH[pg] = 0;
    xqTL[pg] = 0;
  }
}

// ---------------------------------------------------------------------------
// Pass 2 v5: TT=128 (2 sub-tiles/wave), B-frags BATCH-loaded into registers
// per q-chunk and reused across sub-tiles; P via wave-local LDS (no barrier).
// launch_bounds(256,2) so the allocator keeps frags live (R10's VGPR=48
// starved the loads into serial L2 round-trips).
// ---------------------------------------------------------------------------
#define TT5 128
__global__ __launch_bounds__(256, 2) void bcast5_kernel(
    const ushort* __restrict__ wHi, const ushort* __restrict__ wLo,
    const ushort* __restrict__ repPH, const ushort* __restrict__ repPL,
    const ushort* __restrict__ xqTH, const ushort* __restrict__ xqTL,
    const float* __restrict__ m_fin, const float* __restrict__ l_fin,
    ushort* __restrict__ xdHi, ushort* __restrict__ xdLo) {
  const int tile = blockIdx.x, bh = blockIdx.y;
  const int b = bh / HEADS, h = bh % HEADS;
  const int tok0 = tile * TT5;
  const int t = threadIdx.x;
  const int lane = t & 63, wv = t >> 6;
  const int l15 = lane & 15, l4 = lane >> 4;

  __shared__ ushort pH[128][72], pL[128][72];

  // ---- w A-fragments for both sub-tiles (uint loads, masked k>=50) ----
  short8 awh[2][2], awl[2][2];
#pragma unroll
  for (int st = 0; st < 2; ++st) {
    const int tokA = tok0 + st * 64 + 16 * wv + l15;
#pragma unroll
    for (int ks = 0; ks < 2; ++ks) {
      const int kbase = 32 * ks + 8 * l4;
      uint hv[4] = {0, 0, 0, 0}, lv[4] = {0, 0, 0, 0};
      if (tokA < NTOK && kbase < DHEAD) {
        const size_t g = ((size_t)b * NTOK + tokA) * INNERC + h * DHEAD + kbase;
#pragma unroll
        for (int c = 0; c < 4; ++c) {
          hv[c] = *(const uint*)&wHi[g + 2 * c];
          lv[c] = *(const uint*)&wLo[g + 2 * c];
        }
      }
      short8 th, tl;
#pragma unroll
      for (int j = 0; j < 8; ++j) {
        const bool ok = (kbase + j) < DHEAD;
        const ushort hsel = (j & 1) ? (ushort)(hv[j >> 1] >> 16) : (ushort)(hv[j >> 1] & 0xffffu);
        const ushort lsel = (j & 1) ? (ushort)(lv[j >> 1] >> 16) : (ushort)(lv[j >> 1] & 0xffffu);
        th[j] = ok ? (short)hsel : (short)0;
        tl[j] = ok ? (short)lsel : (short)0;
      }
      awh[st][ks] = th;
      awl[st][ks] = tl;
    }
  }

  f32x4 accO[2][4];
#pragma unroll
  for (int st = 0; st < 2; ++st)
#pragma unroll
    for (int di = 0; di < 4; ++di) accO[st][di] = (f32x4){0.f, 0.f, 0.f, 0.f};

#pragma unroll
  for (int qc = 0; qc < 2; ++qc) {
    const int q0 = qc * 64;

    // ---- BATCH-load all rep B-frags into registers (16 independent loads) ----
    short8 rbh[4][2], rbl[4][2];
#pragma unroll
    for (int ni = 0; ni < 4; ++ni)
#pragma unroll
      for (int ks = 0; ks < 2; ++ks) {
        const size_t rg = (((size_t)bh * 128) + (q0 + 16 * ni + l15)) * 64 + 32 * ks + 8 * l4;
        rbh[ni][ks] = *(const short8*)&repPH[rg];
        rbl[ni][ks] = *(const short8*)&repPL[rg];
      }
    // m, 1/l per ni column
    float mq[4], li[4];
    bool vq[4];
#pragma unroll
    for (int ni = 0; ni < 4; ++ni) {
      const int q = q0 + 16 * ni + l15;
      vq[ni] = (q < NQ);
      mq[ni] = vq[ni] ? m_fin[(size_t)bh * NQ + q] : 0.f;
      li[ni] = vq[ni] ? 1.f / l_fin[(size_t)bh * NQ + q] : 0.f;
    }

    // ---- phase 1: S' + softmax + P->LDS for both sub-tiles ----
#pragma unroll
    for (int st = 0; st < 2; ++st) {
      f32x4 accS[4];
#pragma unroll
      for (int ni = 0; ni < 4; ++ni) accS[ni] = (f32x4){0.f, 0.f, 0.f, 0.f};
#pragma unroll
      for (int ks = 0; ks < 2; ++ks)
#pragma unroll
        for (int ni = 0; ni < 4; ++ni) {
          accS[ni] = __builtin_amdgcn_mfma_f32_16x16x32_bf16(awh[st][ks], rbh[ni][ks], accS[ni], 0, 0, 0);
          accS[ni] = __builtin_amdgcn_mfma_f32_16x16x32_bf16(awl[st][ks], rbh[ni][ks], accS[ni], 0, 0, 0);
          accS[ni] = __builtin_amdgcn_mfma_f32_16x16x32_bf16(awh[st][ks], rbl[ni][ks], accS[ni], 0, 0, 0);
        }
#pragma unroll
      for (int ni = 0; ni < 4; ++ni) {
#pragma unroll
        for (int r = 0; r < 4; ++r) {
          const float p = vq[ni] ? __expf(accS[ni][r] - mq[ni]) * li[ni] : 0.f;
          const int row = st * 64 + 16 * wv + 4 * l4 + r;
          const ushort ph = f2bf(p);
          pH[row][16 * ni + l15] = ph;
          pL[row][16 * ni + l15] = f2bf(p - bf2f(ph));
        }
      }
    }

    // ---- BATCH-load all xqT B-frags into registers ----
    short8 xbh[4][2], xbl[4][2];
#pragma unroll
    for (int di = 0; di < 4; ++di)
#pragma unroll
      for (int ks2 = 0; ks2 < 2; ++ks2) {
        const size_t xg = (((size_t)bh * 64) + (16 * di + l15)) * 128 + q0 + 32 * ks2 + 8 * l4;
        xbh[di][ks2] = *(const short8*)&xqTH[xg];
        xbl[di][ks2] = *(const short8*)&xqTL[xg];
      }

    // ---- phase 2: PV for both sub-tiles (P from wave-local LDS rows) ----
#pragma unroll
    for (int st = 0; st < 2; ++st) {
#pragma unroll
      for (int ks2 = 0; ks2 < 2; ++ks2) {
        const short8 pah = *(const short8*)&pH[st * 64 + 16 * wv + l15][32 * ks2 + 8 * l4];
        const short8 pal = *(const short8*)&pL[st * 64 + 16 * wv + l15][32 * ks2 + 8 * l4];
#pragma unroll
        for (int di = 0; di < 4; ++di) {
          accO[st][di] = __builtin_amdgcn_mfma_f32_16x16x32_bf16(pah, xbh[di][ks2], accO[st][di], 0, 0, 0);
          accO[st][di] = __builtin_amdgcn_mfma_f32_16x16x32_bf16(pal, xbh[di][ks2], accO[st][di], 0, 0, 0);
          accO[st][di] = __builtin_amdgcn_mfma_f32_16x16x32_bf16(pah, xbl[di][ks2], accO[st][di], 0, 0, 0);
        }
      }
    }
  }

  // ---- epilogue: write xd planes (stride XDK) ----
#pragma unroll
  for (int st = 0; st < 2; ++st)
#pragma unroll
    for (int di = 0; di < 4; ++di) {
      const int d = di * 16 + l15;
      if (d >= DHEAD) continue;
#pragma unroll
      for (int r = 0; r < 4; ++r) {
        const int tok = tok0 + st * 64 + wv * 16 + 4 * l4 + r;
        if (tok < NTOK) {
          const float val = accO[st][di][r];
          const ushort hh = f2bf(val);
          const size_t g = ((size_t)b * NTOK + tok) * XDK + h * DHEAD + d;
          xdHi[g] = hh;
          xdLo[g] = f2bf(val - bf2f(hh));
        }
      }
    }
}

// ---------------------------------------------------------------------------
extern "C" void kernel_launch(void* const* d_in, const int* in_sizes, int n_in,
                              void* d_out, int out_size, void* d_ws, size_t ws_size,
                              hipStream_t stream) {
  const float* x        = (const float*)d_in[0];
  const float* proj_w   = (const float*)d_in[1];
  const float* step_x   = (const float*)d_in[2];
  const float* step_rep = (const float*)d_in[3];
  const float* out_w    = (const float*)d_in[4];
  const float* out_b    = (const float*)d_in[5];
  float* out = (float*)d_out;

  uint8_t* p8 = (uint8_t*)d_ws;
  ushort* wHi    = (ushort*)(p8);                  //  48,720,000 B
  ushort* wLo    = (ushort*)(p8 + 48720000);       //  48,720,000
  float*  rep    = (float*) (p8 + 97440000);       //     960,000
  float*  reph2  = (float*) (p8 + 98400000);       //     960,000
  float*  m_part = (float*) (p8 + 100320000);      //     614,400 (48*32*100)
  float*  l_part = (float*) (p8 + 100934400);      //     614,400
  float*  m_fin  = (float*) (p8 + 101548800);      //      19,200
  float*  l_fin  = (float*) (p8 + 101568000);      //      19,200
  ushort* xdHi   = (ushort*)(p8 + 101587200);      //  51,968,000
  ushort* xdLo   = (ushort*)(p8 + 153555200);      //  51,968,000
  ushort* pwHi   = (ushort*)(p8 + 205523200);      //     491,520
  ushort* pwLo   = (ushort*)(p8 + 206014720);      //     491,520
  ushort* owHi   = (ushort*)(p8 + 206506240);      //     491,520
  ushort* owLo   = (ushort*)(p8 + 206997760);      //     491,520
  ushort* repPH  = (ushort*)(p8 + 207489280);      //     786,432 (48*128*64*2)
  ushort* repPL  = (ushort*)(p8 + 208275712);      //     786,432
  ushort* xqTH   = (ushort*)(p8 + 209062144);      //     786,432 (48*64*128*2)
  ushort* xqTL   = (ushort*)(p8 + 209848576);      //     786,432
  // end 210,635,008 B (~210.6 MB) < proven 213.8 MB.
  float* delta = (float*)xdHi;   // consumed by combine BEFORE pad-zero + bcast5

  // 0. pre-split weights
  split_pad<<<960, 256, 0, stream>>>(proj_w, pwHi, pwLo, INNERC, DIMC, 320, DIMC);
  split_pad<<<960, 256, 0, stream>>>(out_w, owHi, owLo, DIMC, INNERC, DIMC, XDK);
  // 1. w planes = x @ proj_w^T (single N pass)
  gemm1_xw<<<1269, 256, 0, stream>>>(x, pwHi, pwLo, wHi, wLo);
  // 2. pooling -> rep fp32 + rep*SCALE planes
  pool_kernel<<<dim3(NQ, BATCH), 320, 0, stream>>>(wHi, wLo, rep, repPH, repPL);
  // 3. stage-1 attention + combine (delta aliases xdHi!)
  attn1_mfma<<<dim3(NBH, NSPLIT), 256, 0, stream>>>(wHi, wLo, rep, m_part, l_part, delta);
  attn1_combine<<<NBH, 256, 0, stream>>>(rep, m_part, l_part, delta, step_rep,
                                         reph2, m_fin, l_fin);
  // 3b. zero xd pad columns AFTER delta is consumed, BEFORE bcast5/gemm2
  zero_xd_pad<<<2048, 256, 0, stream>>>(xdHi, xdLo);
  // 4. stage-2 self-attention -> xqT planes
  attn2_kernel<<<NBH, 256, 0, stream>>>(reph2, step_x, xqTH, xqTL);
  // 5. broadcast back -> xd planes (register-batched MFMA)
  bcast5_kernel<<<dim3(80, NBH), 256, 0, stream>>>(
      wHi, wLo, repPH, repPL, xqTH, xqTL, m_fin, l_fin, xdHi, xdLo);
  // 6. out = xd @ out_w^T + bias (XCD-swizzled)
  gemm2_out<<<3807, 256, 0, stream>>>(xdHi, xdLo, owHi, owLo, out_b, out);
}